// Round 10
// baseline (698.493 us; speedup 1.0000x reference)
//
#include <hip/hip_runtime.h>

// MANNet forward, MI355X gfx950. Inputs fp32 (+int32 ids), output fp32.
// R19: (1) k_gru deferred stores — per-step global output stores (plus their
// address math) moved out of the pre-barrier window into the NEXT step's
// ds_read-stall shadow (values kept in registers, flushed at step top; final
// flush after loop). Barrier arrival earlier; stores execute for free.
// (2) k_fuse — gbB projection GEMMs and k_scmm are independent (scmm reads only
// hl_hi/hr_hi) but were serialized on the stream; merged into one dispatch
// (blockIdx.y<6 gemm / >=6 scmm) so the GEMM hides under scmm.

#define DEV static __device__ __forceinline__
#define BAR_LGKM() __asm__ volatile("s_waitcnt lgkmcnt(0)\ns_barrier" ::: "memory")

typedef __attribute__((ext_vector_type(4))) float f32x4;
typedef __attribute__((ext_vector_type(8))) short s16x8;
typedef __attribute__((ext_vector_type(4))) unsigned int u32x4;
typedef __attribute__((ext_vector_type(2))) unsigned int u32x2;

constexpr int T = 256, E = 300, EP = 320, H = 128, H2 = 256, H3 = 384, H12 = 1536;
constexpr int M = 1024;            // B*T
constexpr int STY = 262144;        // 4*T*T elements per score type

DEV float b2f(unsigned short h) { return __uint_as_float(((unsigned)h) << 16); }
DEV unsigned short f2b(float f) {
  unsigned u = __float_as_uint(f);
  u += 0x7fff + ((u >> 16) & 1);            // RNE
  return (unsigned short)(u >> 16);
}
DEV unsigned cvt_pk_bf16(float lo, float hi) {   // dst = {bf16(lo), bf16(hi)} RNE
  unsigned r;
  __asm__("v_cvt_pk_bf16_f32 %0, %1, %2" : "=v"(r) : "v"(lo), "v"(hi));
  return r;
}
DEV float rcp_f(float x) {                       // v_rcp_f32: 1 ulp, 1 trans op
  float r;
  __asm__("v_rcp_f32 %0, %1" : "=v"(r) : "v"(x));
  return r;
}
DEV float sigm(float x) { return rcp_f(1.f + __expf(-x)); }
DEV float tanh_f(float x) {
  float e = __expf(2.f * x);
  return __builtin_fmaf(-2.f, rcp_f(e + 1.f), 1.f);
}
// lanes 0-31 <- x0, lanes 32-63 <- x1's lanes 0-31 (one v_permlane32_swap_b32)
DEV float plsel(float x0, float x1) {
  u32x2 r = __builtin_amdgcn_permlane32_swap(
      __float_as_uint(x0), __float_as_uint(x1), false, false);
  return __uint_as_float(r[0]);
}

DEV s16x8 ldfrag(const unsigned short* p) {
  u32x4 v = *(const u32x4*)p;
  return __builtin_bit_cast(s16x8, v);
}
DEV f32x4 mfma16(s16x8 a, s16x8 b, f32x4 c) {
  return __builtin_amdgcn_mfma_f32_16x16x32_bf16(a, b, c, 0, 0, 0);
}

// ---------------- fused staging: 9x cvt + embed + padw (flattened grid) -------

struct StageArgs {
  const float* cs[9]; unsigned short* cd[9]; int cn[9];
  const int* idx; const float* emb; unsigned short* xhi; unsigned short* xlo;
  const float* lW; const float* rW; unsigned short* wpad;
  int bo[12];                      // per-seg block offsets; bo[11] = total
};

__global__ void k_stage(StageArgs sa) {
  int blk = blockIdx.x;
  int seg = 0;
  #pragma unroll
  for (int s2 = 1; s2 < 11; ++s2) seg = (blk >= sa.bo[s2]) ? s2 : seg;
  int i = (blk - sa.bo[seg]) * 256 + threadIdx.x;
  if (seg < 9) {
    if (i < sa.cn[seg]) sa.cd[seg][i] = f2b(sa.cs[seg][i]);
    return;
  }
  if (seg == 9) {
    if (i >= M * EP) return;
    int m = i / EP, e = i - m * EP;
    int r = sa.idx[m];
    float v = (e < E) ? sa.emb[(size_t)r * E + e] : 0.f;
    unsigned short hi = f2b(v);
    sa.xhi[i] = hi;
    sa.xlo[i] = f2b(v - b2f(hi));
    return;
  }
  if (i >= 4 * H3 * EP) return;
  int e = i % EP, n = (i / EP) % H3, uu = i / (EP * H3);
  const float* src = (uu < 2 ? sa.lW : sa.rW) + (size_t)((uu & 1) * H3 + n) * E;
  sa.wpad[i] = (e < E) ? f2b(src[e]) : (unsigned short)0;
}

// ---------------- generic GEMM: C = (Ahi+Alo) @ W^T (+bias), fp32 out ----------
// tr=1: write transposed C_t[n*M + m] (for j-streamed consumers).

struct GemmDesc {
  const unsigned short* Ahi; const unsigned short* Alo; const unsigned short* W;
  const float* bias; float* Cf; int N; int K; int tr;
};
struct GemmBatch { GemmDesc d[8]; };

DEV void gemm_body(const GemmDesc& g, int mb, int nb, int tid) {
  int lane = tid & 63, w = tid >> 6, quad = lane >> 4, l16 = lane & 15;
  int K = g.K;
  const unsigned short* Ahp = g.Ahi + (size_t)(mb + w * 16 + l16) * K + quad * 8;
  const unsigned short* Alp = g.Alo + (size_t)(mb + w * 16 + l16) * K + quad * 8;
  const unsigned short* Wp = g.W + (size_t)(nb + l16) * K + quad * 8;
  f32x4 acc[4];
  #pragma unroll
  for (int nt = 0; nt < 4; ++nt) acc[nt] = f32x4{0.f, 0.f, 0.f, 0.f};
  for (int k = 0; k < K; k += 32) {
    s16x8 ah = ldfrag(Ahp + k);
    s16x8 al = ldfrag(Alp + k);
    #pragma unroll
    for (int nt = 0; nt < 4; ++nt) {
      s16x8 b = ldfrag(Wp + (size_t)nt * 16 * K + k);
      acc[nt] = mfma16(ah, b, acc[nt]);
      acc[nt] = mfma16(al, b, acc[nt]);
    }
  }
  int mr0 = mb + w * 16 + quad * 4;
  #pragma unroll
  for (int nt = 0; nt < 4; ++nt) {
    int col = nb + nt * 16 + l16;
    float bv = g.bias ? g.bias[col] : 0.f;
    #pragma unroll
    for (int r = 0; r < 4; ++r) {
      if (g.tr)
        g.Cf[(size_t)col * M + (mr0 + r)] = acc[nt][r] + bv;
      else
        g.Cf[(size_t)(mr0 + r) * g.N + col] = acc[nt][r] + bv;
    }
  }
}

__global__ __launch_bounds__(256) void k_gemm(GemmBatch gb) {
  GemmDesc g = gb.d[blockIdx.z];
  int nb = blockIdx.y * 64;
  if (nb >= g.N) return;
  gemm_body(g, blockIdx.x * 64, nb, threadIdx.x);
}

// ---------------- GRU recurrence v8 (deferred stores) ----------------

struct RecArgs {
  const unsigned short* whh[4];
  const float* pre[4];
  float* outf[4];
  unsigned short* outhi[4];
  unsigned short* outlo[4];
  unsigned short* agghi[4];      // null -> no agg copy
  unsigned short* agglo[4];
  const float* bhh[4];
  int colOff[4];
  int dir[4];
};

// One recurrence step. pr_/pz_/pn_ are this step's pre-activations (bh_r/bh_z
// pre-added), refreshed from pq_ (advanced 2 steps) for step s+2. Outputs of
// step s-1 (p_*) flush at step-s top, inside the ds_read stall shadow.
#define GRU_STEP(pr_, pz_, pn_, pq_, hcur_, hnxt_, s_)                         \
  {                                                                            \
    const unsigned short* hb_ = hcur_ + l16 * 136 + quad * 8;                  \
    s16x8 ah0 = ldfrag(hb_);                                                   \
    s16x8 ah1 = ldfrag(hb_ + 32);                                              \
    s16x8 ah2 = ldfrag(hb_ + 64);                                              \
    s16x8 ah3 = ldfrag(hb_ + 96);                                              \
    if (s_) {                                                                  \
      outf[p_o] = p_hf; outhi[p_o] = p_hi; outlo[p_o] = p_lo;                  \
      if (agghi) { agghi[p_a] = p_hi; agglo[p_a] = p_lo; }                     \
    }                                                                          \
    float pr = pr_, pz = pz_, pn = pn_;                                        \
    pq_ += pst2;                                                               \
    pr_ = pq_[0] + bh_r; pz_ = pq_[128] + bh_z; pn_ = pq_[256];                \
    f32x4 z4 = f32x4{0.f, 0.f, 0.f, 0.f};                                      \
    f32x4 aR0 = mfma16(ah0, bq[0][0], z4);                                     \
    f32x4 aR1 = mfma16(ah2, bq[0][2], z4);                                     \
    aR0 = mfma16(ah1, bq[0][1], aR0);                                          \
    aR1 = mfma16(ah3, bq[0][3], aR1);                                          \
    f32x4 aZ0 = mfma16(ah0, bq[1][0], z4);                                     \
    f32x4 aZ1 = mfma16(ah2, bq[1][2], z4);                                     \
    aZ0 = mfma16(ah1, bq[1][1], aZ0);                                          \
    aZ1 = mfma16(ah3, bq[1][3], aZ1);                                          \
    float r0 = (aR0[0] + aR1[0]) + (aR0[1] + aR1[1]);                          \
    float r1v = (aR0[2] + aR1[2]) + (aR0[3] + aR1[3]);                         \
    float rg = sigm(pr + plsel(r0, r1v));                                      \
    f32x4 aN0 = mfma16(ah0, bq[2][0], z4);                                     \
    f32x4 aN1 = mfma16(ah2, bq[2][2], z4);                                     \
    aN0 = mfma16(ah1, bq[2][1], aN0);                                          \
    aN1 = mfma16(ah3, bq[2][3], aN1);                                          \
    float z0 = (aZ0[0] + aZ1[0]) + (aZ0[1] + aZ1[1]);                          \
    float z1 = (aZ0[2] + aZ1[2]) + (aZ0[3] + aZ1[3]);                          \
    float zg = sigm(pz + plsel(z0, z1));                                       \
    float n0 = (aN0[0] + aN1[0]) + (aN0[1] + aN1[1]);                          \
    float n1 = (aN0[2] + aN1[2]) + (aN0[3] + aN1[3]);                          \
    float ng = tanh_f(pn + rg * (plsel(n0, n1) + bh_n));                       \
    hf = __builtin_fmaf(zg, hf - ng, ng);                                      \
    unsigned hp32 = cvt_pk_bf16(hf, hf);                                       \
    float rem = hf - __uint_as_float(hp32 << 16);                              \
    unsigned lp32 = cvt_pk_bf16(rem, rem);                                     \
    unsigned short hi = (unsigned short)hp32;                                  \
    unsigned short lo = (unsigned short)lp32;                                  \
    hnxt_[(2 * b) * 136 + d] = hi;                                             \
    hnxt_[(2 * b + 1) * 136 + d] = lo;                                         \
    int tq = dir ? (T - 1 - (s_)) : (s_);                                      \
    p_hf = hf; p_hi = hi; p_lo = lo;                                           \
    p_o = (size_t)(b * T + tq) * H2 + colOff + d;                              \
    p_a = (size_t)(b * T + tq) * H12 + colOff + d;                             \
    BAR_LGKM();                                                                \
  }

__global__ __launch_bounds__(512) void k_gru(RecArgs ra) {
  int u = blockIdx.x;
  __shared__ __align__(16) unsigned short hs[2][16 * 136];
  int tid = threadIdx.x, lane = tid & 63, w8 = tid >> 6;
  int quad = lane >> 4, l16 = lane & 15;
  for (int i = tid; i < 2 * 16 * 136; i += 512) ((unsigned short*)hs)[i] = 0;
  const unsigned short* whh = ra.whh[u];
  s16x8 bq[3][4];
  #pragma unroll
  for (int g = 0; g < 3; ++g) {
    int row = g * 128 + w8 * 16 + l16;
    #pragma unroll
    for (int kc = 0; kc < 4; ++kc)
      bq[g][kc] = ldfrag(whh + (size_t)row * H + kc * 32 + quad * 8);
  }
  const float* bhh = ra.bhh[u];
  const float* pre = ra.pre[u];
  float* outf = ra.outf[u];
  unsigned short* outhi = ra.outhi[u];
  unsigned short* outlo = ra.outlo[u];
  unsigned short* agghi = ra.agghi[u];
  unsigned short* agglo = ra.agglo[u];
  int colOff = ra.colOff[u], dir = ra.dir[u];
  int b = ((quad & 1) << 1) | (quad >> 1);
  int d = w8 * 16 + l16;
  float bh_r = bhh[d], bh_z = bhh[d + 128], bh_n = bhh[d + 256];
  float hf = 0.f;
  // deferred-store state (step s-1 outputs, flushed at step-s top)
  float p_hf = 0.f;
  unsigned short p_hi = 0, p_lo = 0;
  size_t p_o = 0, p_a = 0;
  int t0 = dir ? (T - 1) : 0;
  long pst = dir ? -(long)H3 : (long)H3;
  long pst2 = 2 * pst;
  // depth-2 prefetch: even/odd register pairs. Final iterations overrun the
  // unit's pre slab by <=2 rows (3KB) — lands in adjacent ws regions, unused.
  const float* pqE = pre + (size_t)(b * T + t0) * H3 + d;
  const float* pqO = pqE + pst;
  float e_pr = pqE[0] + bh_r, e_pz = pqE[128] + bh_z, e_pn = pqE[256];
  float o_pr = pqO[0] + bh_r, o_pz = pqO[128] + bh_z, o_pn = pqO[256];
  __syncthreads();
  for (int s = 0; s < T; s += 2) {
    GRU_STEP(e_pr, e_pz, e_pn, pqE, hs[0], hs[1], s);
    GRU_STEP(o_pr, o_pz, o_pn, pqO, hs[1], hs[0], s + 1);
  }
  // flush final step's outputs
  outf[p_o] = p_hf; outhi[p_o] = p_hi; outlo[p_o] = p_lo;
  if (agghi) { agghi[p_a] = p_hi; agglo[p_a] = p_lo; }
}

// ---------------- fused: projection GEMMs (y<6) + MFMA scores (y>=6) ----------
// gemm and scmm are independent (scmm reads only hl_hi/hr_hi) — one dispatch
// lets them co-execute instead of serializing on the stream.

struct ScMMArgs {
  const unsigned short* Xhi[2];
  const float* Rf; const float* Wt[2]; const float* vt[2];
  float* So[2]; float* So2[2];
};
struct FuseArgs { GemmDesc d[6]; ScMMArgs sm; };

__global__ __launch_bounds__(256, 2) void k_fuse(FuseArgs fa) {
  __shared__ __align__(16) unsigned short w_lds[64 * 256];   // 32KB (scmm path)
  int y = blockIdx.y;
  int tid = threadIdx.x;
  if (y < 6) {
    int xx = blockIdx.x;
    if (xx >= 64) return;
    GemmDesc g = fa.d[y];
    int nb = (xx >> 4) * 64;
    if (nb >= g.N) return;
    gemm_body(g, (xx & 15) * 64, nb, tid);
    return;
  }
  const ScMMArgs& a = fa.sm;
  int which = y - 6;
  int bi = blockIdx.x, b = bi >> 8;
  int type = which >> 1, khb = which & 1;
  const unsigned short* Xhi = a.Xhi[type];
  const float* W = a.Wt[type] + (size_t)khb * 64 * 256;
  const float* v = a.vt[type] + khb * 64;
  float* Sout = khb ? a.So2[type] : a.So[type];
  int lane = tid & 63, w = tid >> 6, quad = lane >> 4, l16 = lane & 15;
  int d4 = tid & 63, rhi = tid >> 6;
  float4 h4 = ((const float4*)(a.Rf + (size_t)bi * 256))[d4];
  #pragma unroll
  for (int it = 0; it < 16; ++it) {
    int kl = it * 4 + rhi;                            // local row 0..63
    float4 w4 = ((const float4*)(W + (size_t)kl * 256))[d4];
    unsigned lo32 = cvt_pk_bf16(w4.x * h4.x, w4.y * h4.y);
    unsigned hi32 = cvt_pk_bf16(w4.z * h4.z, w4.w * h4.w);
    unsigned long long pk = (unsigned long long)lo32 | ((unsigned long long)hi32 << 32);
    int gphys = ((d4 >> 1) + kl) & 31;
    *(unsigned long long*)(w_lds + (size_t)kl * 256 + gphys * 8 + (d4 & 1) * 4) = pk;
  }
  BAR_LGKM();
  f32x4 acc[4][4];
  #pragma unroll
  for (int jj = 0; jj < 4; ++jj)
    #pragma unroll
    for (int c = 0; c < 4; ++c) acc[jj][c] = f32x4{0.f, 0.f, 0.f, 0.f};
  const unsigned short* Xp0 =
      Xhi + (size_t)(b * 256 + w * 4 * 16 + l16) * 256 + quad * 8;
  #pragma unroll 2
  for (int kc = 0; kc < 8; ++kc) {
    s16x8 af[4];
    #pragma unroll
    for (int c = 0; c < 4; ++c) {
      int krow = c * 16 + l16;
      int gp = (kc * 4 + quad + krow) & 31;
      af[c] = ldfrag(w_lds + (size_t)krow * 256 + gp * 8);
    }
    s16x8 bf[4];
    #pragma unroll
    for (int jj = 0; jj < 4; ++jj)
      bf[jj] = ldfrag(Xp0 + (size_t)jj * 16 * 256 + kc * 32);
    #pragma unroll
    for (int jj = 0; jj < 4; ++jj)
      #pragma unroll
      for (int c = 0; c < 4; ++c)
        acc[jj][c] = mfma16(af[c], bf[jj], acc[jj][c]);
  }
  float vv[4][4];
  #pragma unroll
  for (int c = 0; c < 4; ++c)
    #pragma unroll
    for (int r = 0; r < 4; ++r) vv[c][r] = v[c * 16 + quad * 4 + r];
  #pragma unroll
  for (int jj = 0; jj < 4; ++jj) {
    float s = 0.f;
    #pragma unroll
    for (int c = 0; c < 4; ++c)
      #pragma unroll
      for (int r = 0; r < 4; ++r) s += tanh_f(acc[jj][c][r]) * vv[c][r];
    s += __shfl_xor(s, 16);
    s += __shfl_xor(s, 32);
    int jt = w * 4 + jj;
    if (lane < 16) Sout[(size_t)bi * 256 + jt * 16 + l16] = s;
  }
}

// ---------------- scores cmb path (grid 256, 4 i-rows/block) ------------------

struct ScCmbArgs {
  const float *Hc, *Rc, *Hm, *Rm, *HB, *hrf, *vcf, *vmf; float* S;
};

__global__ __launch_bounds__(256, 2) void k_sccmb(ScCmbArgs a) {
  int bi = blockIdx.x;
  int tid = threadIdx.x;
  __shared__ float rc_l[4 * 128];
  __shared__ float rm_l[4 * 128];
  __shared__ float hr_l[4 * 256];
  __shared__ float vc_l[128], vm_l[128];
  int b = bi >> 6, i0 = (bi & 63) << 2;       // 4 i-rows: gi0..gi0+3
  int gi0 = b * 256 + i0;
  {
    const float4* hr4 = (const float4*)(a.hrf + (size_t)gi0 * 256);
    ((float4*)hr_l)[tid] = hr4[tid];
    if (tid < 128) {
      const float4* rc4 = (const float4*)(a.Rc + (size_t)gi0 * 128);
      const float4* rm4 = (const float4*)(a.Rm + (size_t)gi0 * 128);
      ((float4*)rc_l)[tid] = rc4[tid];
      ((float4*)rm_l)[tid] = rm4[tid];
      vc_l[tid] = a.vcf[tid]; vm_l[tid] = a.vmf[tid];
    }
  }
  __syncthreads();
  int j = tid;
  size_t cb = (size_t)(b * 256 + j);
  float scq[4], smq[4], sbq[4];
  #pragma unroll
  for (int q = 0; q < 4; ++q) { scq[q] = 0.f; smq[q] = 0.f; sbq[q] = 0.f; }
  for (int k = 0; k < 128; ++k) {
    float hc = a.Hc[(size_t)k * M + cb];      // transposed: lane-consecutive
    float hm = a.Hm[(size_t)k * M + cb];
    float vck = vc_l[k], vmk = vm_l[k];
    #pragma unroll
    for (int q = 0; q < 4; ++q) {
      scq[q] += vck * tanh_f(hc + rc_l[q * 128 + k]);
      smq[q] += vmk * tanh_f(hm - rm_l[q * 128 + k]);
    }
  }
  for (int k = 0; k < 256; ++k) {
    float hb = a.HB[(size_t)k * M + cb];      // transposed
    #pragma unroll
    for (int q = 0; q < 4; ++q) sbq[q] += hb * hr_l[q * 256 + k];
  }
  #pragma unroll
  for (int q = 0; q < 4; ++q) {
    size_t o = (size_t)(gi0 + q) * 256 + j;
    a.S[(size_t)STY * 1 + o] = scq[q];
    a.S[(size_t)STY * 3 + o] = sbq[q];
    a.S[(size_t)STY * 4 + o] = smq[q];
  }
}

// ---------------- wsum with inline softmax (adds kh-half partials) ------------

__global__ __launch_bounds__(256) void k_wsum(const float* __restrict__ S,
    const float* __restrict__ S2,
    const float* __restrict__ hl_f, const float* __restrict__ hr_f,
    unsigned short* __restrict__ ahi, unsigned short* __restrict__ alo) {
  int it = blockIdx.x, type = blockIdx.y, b = blockIdx.z;
  __shared__ float p_l[8][256];
  __shared__ float red[4];
  int tid = threadIdx.x;
  for (int ii = 0; ii < 8; ++ii) {
    size_t idx = ((size_t)(b * 256 + it * 8 + ii)) * 256 + tid;
    float x = S[(size_t)type * STY + idx];
    if (type == 0) x += S2[idx];                        // pts partial (kh1)
    else if (type == 2) x += S2[(size_t)STY + idx];     // ptd partial (kh1)
    float m = x;
    for (int dl = 32; dl; dl >>= 1) m = fmaxf(m, __shfl_xor(m, dl));
    if ((tid & 63) == 0) red[tid >> 6] = m;
    __syncthreads();
    m = fmaxf(fmaxf(red[0], red[1]), fmaxf(red[2], red[3]));
    __syncthreads();
    float e = __expf(x - m);
    float sum = e;
    for (int dl = 32; dl; dl >>= 1) sum += __shfl_xor(sum, dl);
    if ((tid & 63) == 0) red[tid >> 6] = sum;
    __syncthreads();
    sum = red[0] + red[1] + red[2] + red[3];
    p_l[ii][tid] = e * rcp_f(sum);
    __syncthreads();
  }
  const float* src = (type == 0 ? hr_f : hl_f) + (size_t)b * 256 * 256;
  float acc[8] = {0.f, 0.f, 0.f, 0.f, 0.f, 0.f, 0.f, 0.f};
  for (int j = 0; j < 256; ++j) {
    float hv = src[(size_t)j * 256 + tid];
    #pragma unroll
    for (int ii = 0; ii < 8; ++ii) acc[ii] += p_l[ii][j] * hv;
  }
  int off = 256 * (1 + type);      // agg: [hr | pts | ptc | ptd | ptb | ptm]
  #pragma unroll
  for (int ii = 0; ii < 8; ++ii) {
    float vv = acc[ii];
    unsigned short hi = f2b(vv);
    size_t o = (size_t)(b * 256 + it * 8 + ii) * H12 + off + tid;
    ahi[o] = hi;
    alo[o] = f2b(vv - b2f(hi));
  }
}

// ---------------- fused tail ----------------

__global__ __launch_bounds__(256) void k_tail(const float* __restrict__ Hp,
    const float* __restrict__ hl_f, const float* __restrict__ vpf,
    const float* __restrict__ Wc2f, const float* __restrict__ Arc,
    const float* __restrict__ ar_f, const float* __restrict__ vcf,
    const float* __restrict__ Wpredf, float* __restrict__ out) {
  int b = blockIdx.x, tid = threadIdx.x;
  __shared__ float vl[128], wl[256], rvec[256], rlcl[128], red[4];
  if (tid < 128) vl[tid] = vpf[tid];
  __syncthreads();
  const float* hp = Hp + (size_t)(b * 256 + tid) * 128;
  float s = 0.f;
  for (int k = 0; k < 128; ++k) s += vl[k] * tanh_f(hp[k]);
  float m = s;
  for (int dl = 32; dl; dl >>= 1) m = fmaxf(m, __shfl_xor(m, dl));
  if ((tid & 63) == 0) red[tid >> 6] = m;
  __syncthreads();
  m = fmaxf(fmaxf(red[0], red[1]), fmaxf(red[2], red[3]));
  __syncthreads();
  float e = __expf(s - m);
  float sum = e;
  for (int dl = 32; dl; dl >>= 1) sum += __shfl_xor(sum, dl);
  if ((tid & 63) == 0) red[tid >> 6] = sum;
  __syncthreads();
  sum = red[0] + red[1] + red[2] + red[3];
  wl[tid] = e * rcp_f(sum);
  __syncthreads();
  float acc = 0.f;
  for (int t = 0; t < 256; ++t) acc += wl[t] * hl_f[(size_t)(b * 256 + t) * 256 + tid];
  rvec[tid] = acc;
  __syncthreads();
  if (tid < 128) {
    float a2 = 0.f;
    const float* wr = Wc2f + (size_t)tid * 256;
    for (int dk = 0; dk < 256; ++dk) a2 += rvec[dk] * wr[dk];
    rlcl[tid] = a2;
    vl[tid] = vcf[tid];
  }
  __syncthreads();
  const float* ap = Arc + (size_t)(b * 256 + tid) * 128;
  float s2 = 0.f;
  for (int k = 0; k < 128; ++k) s2 += vl[k] * (ap[k] + rlcl[k]);
  m = s2;
  for (int dl = 32; dl; dl >>= 1) m = fmaxf(m, __shfl_xor(m, dl));
  if ((tid & 63) == 0) red[tid >> 6] = m;
  __syncthreads();
  m = fmaxf(fmaxf(red[0], red[1]), fmaxf(red[2], red[3]));
  __syncthreads();
  float e2 = __expf(s2 - m);
  float sum2 = e2;
  for (int dl = 32; dl; dl >>= 1) sum2 += __shfl_xor(sum2, dl);
  if ((tid & 63) == 0) red[tid >> 6] = sum2;
  __syncthreads();
  sum2 = red[0] + red[1] + red[2] + red[3];
  wl[tid] = e2 * rcp_f(sum2);
  __syncthreads();
  float acc2 = 0.f;
  for (int t = 0; t < 256; ++t) acc2 += wl[t] * ar_f[(size_t)(b * 256 + t) * 256 + tid];
  rvec[tid] = acc2;
  __syncthreads();
  if (tid < 2) {
    float o = 0.f;
    const float* wp = Wpredf + (size_t)tid * 256;
    for (int dk = 0; dk < 256; ++dk) o += rvec[dk] * wp[dk];
    out[b * 2 + tid] = sigm(o);
  }
}

// ---------------- host ----------------

extern "C" void kernel_launch(void* const* d_in, const int* in_sizes, int n_in,
                              void* d_out, int out_size, void* d_ws, size_t ws_size,
                              hipStream_t stream) {
  (void)in_sizes; (void)n_in; (void)out_size; (void)ws_size;
  const int* inputs = (const int*)d_in[0];
  const float* embed = (const float*)d_in[1];
  const float* lWih = (const float*)d_in[2];
  const float* lWhh = (const float*)d_in[3];
  const float* lbih = (const float*)d_in[4];
  const float* lbhh = (const float*)d_in[5];
  const float* rWih = (const float*)d_in[6];
  const float* rWhh = (const float*)d_in[7];
  const float* rbih = (const float*)d_in[8];
  const float* rbhh = (const float*)d_in[9];
  const float* aWih = (const float*)d_in[10];
  const float* aWhh = (const float*)d_in[11];
  const float* abih = (const float*)d_in[12];
  const float* abhh = (const float*)d_in[13];
  const float* Wc1 = (const float*)d_in[14];
  const float* Wc2 = (const float*)d_in[15];
  const float* vc  = (const float*)d_in[16];
  const float* Wb  = (const float*)d_in[17];
  const float* Wd  = (const float*)d_in[18];
  const float* vd  = (const float*)d_in[19];
  const float* Wm  = (const float*)d_in[20];
  const float* vmv = (const float*)d_in[21];
  const float* Wsw = (const float*)d_in[22];
  const float* vsv = (const float*)d_in[23];
  const float* Wp  = (const float*)d_in[24];
  const float* vp  = (const float*)d_in[25];
  const float* Wpred = (const float*)d_in[26];

  char* ws = (char*)d_ws;
  size_t off = 0;
  auto alloc = [&](size_t bytes) -> void* {
    void* p = ws + off;
    off += (bytes + 255) & ~(size_t)255;
    return p;
  };
  unsigned short* xhi = (unsigned short*)alloc((size_t)M * EP * 2);
  unsigned short* xlo = (unsigned short*)alloc((size_t)M * EP * 2);
  unsigned short* wpad = (unsigned short*)alloc((size_t)4 * H3 * EP * 2);
  unsigned short* Whh_b = (unsigned short*)alloc((size_t)6 * H3 * H * 2);
  unsigned short* aWih_b = (unsigned short*)alloc((size_t)2 * H3 * H12 * 2);
  unsigned short* Wc1_b = (unsigned short*)alloc((size_t)H * H2 * 2);
  unsigned short* Wc2_b = (unsigned short*)alloc((size_t)H * H2 * 2);
  unsigned short* Wm_b  = (unsigned short*)alloc((size_t)H * H2 * 2);
  unsigned short* Wp_b  = (unsigned short*)alloc((size_t)H * H2 * 2);
  unsigned short* Wb_b  = (unsigned short*)alloc((size_t)H2 * H2 * 2);
  char* region1 = (char*)alloc((size_t)4 * M * H3 * 4);
  float* pre_lr = (float*)region1;
  float* S      = (float*)region1;
  float* pre_a  = (float*)region1;
  float* S2 = (float*)alloc((size_t)2 * STY * 4);   // kh1 partials: [pts | ptd]
  float* hl_f = (float*)alloc((size_t)M * H2 * 4);
  float* hr_f = (float*)alloc((size_t)M * H2 * 4);
  unsigned short* hl_hi = (unsigned short*)alloc((size_t)M * H2 * 2);
  unsigned short* hl_lo = (unsigned short*)alloc((size_t)M * H2 * 2);
  unsigned short* hr_hi = (unsigned short*)alloc((size_t)M * H2 * 2);
  unsigned short* hr_lo = (unsigned short*)alloc((size_t)M * H2 * 2);
  float* Hc = (float*)alloc((size_t)M * H * 4);     // transposed [H][M]
  float* Rc = (float*)alloc((size_t)M * H * 4);
  float* Hm = (float*)alloc((size_t)M * H * 4);     // transposed [H][M]
  float* Rm = (float*)alloc((size_t)M * H * 4);
  float* Hp = (float*)alloc((size_t)M * H * 4);
  float* HB = (float*)alloc((size_t)M * H2 * 4);    // transposed [H2][M]
  unsigned short* agg_hi = (unsigned short*)alloc((size_t)M * H12 * 2);
  unsigned short* agg_lo = (unsigned short*)alloc((size_t)M * H12 * 2);
  float* ar_f = (float*)alloc((size_t)M * H2 * 4);
  unsigned short* ar_hi = (unsigned short*)alloc((size_t)M * H2 * 2);
  unsigned short* ar_lo = (unsigned short*)alloc((size_t)M * H2 * 2);
  float* Arc = (float*)alloc((size_t)M * H * 4);

  // 1. staging (flattened grid)
  StageArgs sa{};
  sa.cs[0] = lWhh;  sa.cd[0] = Whh_b;                 sa.cn[0] = 2 * H3 * H;
  sa.cs[1] = rWhh;  sa.cd[1] = Whh_b + 2 * H3 * H;    sa.cn[1] = 2 * H3 * H;
  sa.cs[2] = aWhh;  sa.cd[2] = Whh_b + 4 * H3 * H;    sa.cn[2] = 2 * H3 * H;
  sa.cs[3] = aWih;  sa.cd[3] = aWih_b;                sa.cn[3] = 2 * H3 * H12;
  sa.cs[4] = Wc1;   sa.cd[4] = Wc1_b;                 sa.cn[4] = H * H2;
  sa.cs[5] = Wc2;   sa.cd[5] = Wc2_b;                 sa.cn[5] = H * H2;
  sa.cs[6] = Wm;    sa.cd[6] = Wm_b;                  sa.cn[6] = H * H2;
  sa.cs[7] = Wp;    sa.cd[7] = Wp_b;                  sa.cn[7] = H * H2;
  sa.cs[8] = Wb;    sa.cd[8] = Wb_b;                  sa.cn[8] = H2 * H2;
  sa.idx = inputs; sa.emb = embed; sa.xhi = xhi; sa.xlo = xlo;
  sa.lW = lWih; sa.rW = rWih; sa.wpad = wpad;
  {
    int acc0 = 0;
    sa.bo[0] = 0;
    for (int s = 0; s < 9; ++s) { acc0 += (sa.cn[s] + 255) / 256; sa.bo[s + 1] = acc0; }
    acc0 += (M * EP + 255) / 256;       sa.bo[10] = acc0;
    acc0 += (4 * H3 * EP + 255) / 256;  sa.bo[11] = acc0;
  }
  k_stage<<<dim3(sa.bo[11]), dim3(256), 0, stream>>>(sa);

  // 2. input projections for l/r GRUs
  GemmBatch ga{};
  const float* biases[4] = { lbih, lbih + H3, rbih, rbih + H3 };
  for (int u = 0; u < 4; ++u)
    ga.d[u] = GemmDesc{ xhi, xlo, wpad + (size_t)u * H3 * EP, biases[u],
                        pre_lr + (size_t)u * M * H3, H3, EP, 0 };
  k_gemm<<<dim3(16, 6, 4), dim3(256), 0, stream>>>(ga);

  // 3. l/r recurrences (writes fp32 + hi/lo + agg hr-copy); 1 unit per block
  RecArgs r1{};
  r1.whh[0] = Whh_b;               r1.whh[1] = Whh_b + H3 * H;
  r1.whh[2] = Whh_b + 2 * H3 * H;  r1.whh[3] = Whh_b + 3 * H3 * H;
  for (int u = 0; u < 4; ++u) r1.pre[u] = pre_lr + (size_t)u * M * H3;
  r1.outf[0] = r1.outf[1] = hl_f; r1.outf[2] = r1.outf[3] = hr_f;
  r1.outhi[0] = r1.outhi[1] = hl_hi; r1.outhi[2] = r1.outhi[3] = hr_hi;
  r1.outlo[0] = r1.outlo[1] = hl_lo; r1.outlo[2] = r1.outlo[3] = hr_lo;
  r1.agghi[0] = r1.agghi[1] = nullptr; r1.agghi[2] = r1.agghi[3] = agg_hi;
  r1.agglo[0] = r1.agglo[1] = nullptr; r1.agglo[2] = r1.agglo[3] = agg_lo;
  r1.bhh[0] = lbhh; r1.bhh[1] = lbhh + H3; r1.bhh[2] = rbhh; r1.bhh[3] = rbhh + H3;
  r1.colOff[0] = 0; r1.colOff[1] = H; r1.colOff[2] = 0; r1.colOff[3] = H;
  r1.dir[0] = 0; r1.dir[1] = 1; r1.dir[2] = 0; r1.dir[3] = 1;
  k_gru<<<dim3(4), dim3(512), 0, stream>>>(r1);

  // 4+5a. fused projection GEMMs + MFMA scores (independent; co-execute)
  FuseArgs fu{};
  fu.d[0] = GemmDesc{ hl_hi, hl_lo, Wc1_b, nullptr, Hc, H, H2, 1 };
  fu.d[1] = GemmDesc{ hr_hi, hr_lo, Wc2_b, nullptr, Rc, H, H2, 0 };
  fu.d[2] = GemmDesc{ hl_hi, hl_lo, Wm_b, nullptr, Hm, H, H2, 1 };
  fu.d[3] = GemmDesc{ hr_hi, hr_lo, Wm_b, nullptr, Rm, H, H2, 0 };
  fu.d[4] = GemmDesc{ hl_hi, hl_lo, Wb_b, nullptr, HB, H2, H2, 1 };
  fu.d[5] = GemmDesc{ hl_hi, hl_lo, Wp_b, nullptr, Hp, H, H2, 0 };
  fu.sm.Xhi[0] = hl_hi; fu.sm.Wt[0] = Wd;  fu.sm.vt[0] = vd;
  fu.sm.So[0] = S + (size_t)2 * STY;
  fu.sm.Xhi[1] = hr_hi; fu.sm.Wt[1] = Wsw; fu.sm.vt[1] = vsv;
  fu.sm.So[1] = S + (size_t)0 * STY;
  fu.sm.So2[0] = S2 + (size_t)STY;   // ptd kh1 partial
  fu.sm.So2[1] = S2;                 // pts kh1 partial
  fu.sm.Rf = hr_f;
  k_fuse<<<dim3(M, 10), dim3(256), 0, stream>>>(fu);

  // 5b. combined ptc/ptb/ptm scores (4 i-rows/block)
  ScCmbArgs scb{};
  scb.Hc = Hc; scb.Rc = Rc; scb.Hm = Hm; scb.Rm = Rm; scb.HB = HB;
  scb.hrf = hr_f; scb.vcf = vc; scb.vmf = vmv; scb.S = S;
  k_sccmb<<<dim3(256), dim3(256), 0, stream>>>(scb);

  // 6. softmax + weighted sums into agg
  k_wsum<<<dim3(32, 5, 4), dim3(256), 0, stream>>>(S, S2, hl_f, hr_f, agg_hi, agg_lo);

  // 7. agg GRU input projection
  GemmBatch gc{};
  gc.d[0] = GemmDesc{ agg_hi, agg_lo, aWih_b, abih, pre_a, H3, H12, 0 };
  gc.d[1] = GemmDesc{ agg_hi, agg_lo, aWih_b + (size_t)H3 * H12, abih + H3,
                      pre_a + (size_t)M * H3, H3, H12, 0 };
  k_gemm<<<dim3(16, 6, 2), dim3(256), 0, stream>>>(gc);

  // 8. agg recurrence (writes ar fp32 + hi/lo); 1 unit per block
  RecArgs r2{};
  r2.whh[0] = Whh_b + 4 * H3 * H; r2.whh[1] = Whh_b + 5 * H3 * H;
  r2.whh[2] = r2.whh[3] = Whh_b + 4 * H3 * H;
  r2.pre[0] = pre_a; r2.pre[1] = pre_a + (size_t)M * H3;
  r2.pre[2] = r2.pre[3] = pre_a;
  r2.outf[0] = r2.outf[1] = r2.outf[2] = r2.outf[3] = ar_f;
  r2.outhi[0] = r2.outhi[1] = r2.outhi[2] = r2.outhi[3] = ar_hi;
  r2.outlo[0] = r2.outlo[1] = r2.outlo[2] = r2.outlo[3] = ar_lo;
  for (int u = 0; u < 4; ++u) { r2.agghi[u] = nullptr; r2.agglo[u] = nullptr; }
  r2.bhh[0] = abhh; r2.bhh[1] = abhh + H3; r2.bhh[2] = r2.bhh[3] = abhh;
  r2.colOff[0] = 0; r2.colOff[1] = H; r2.colOff[2] = r2.colOff[3] = 0;
  r2.dir[0] = 0; r2.dir[1] = 1; r2.dir[2] = r2.dir[3] = 0;
  k_gru<<<dim3(2), dim3(512), 0, stream>>>(r2);

  // 9. Arc GEMM
  GemmBatch gd{};
  gd.d[0] = GemmDesc{ ar_hi, ar_lo, Wc1_b, nullptr, Arc, H, H2, 0 };
  k_gemm<<<dim3(16, 2, 1), dim3(256), 0, stream>>>(gd);

  // 10. fused tail
  k_tail<<<dim3(4), dim3(256), 0, stream>>>(Hp, hl_f, vp, Wc2, Arc, ar_f, vc, Wpred,
                                            (float*)d_out);
}

// Round 11
// 676.009 us; speedup vs baseline: 1.0333x; 1.0333x over previous
//
#include <hip/hip_runtime.h>

// MANNet forward, MI355X gfx950. Inputs fp32 (+int32 ids), output fp32.
// R20: revert R19's deferred stores (measured +9us/dispatch: flush extended
// register lifetimes + added a branch; stores did NOT land in the lgkm stall
// window). Back to R18's store-after-gates placement, PLUS incremental output
// pointers (addresses advance by +-H2/+-H12 per step -> pointer bumps instead
// of per-step 64-bit mul/add chains). k_fuse (gemm || scmm merge, -7us) kept.

#define DEV static __device__ __forceinline__
#define BAR_LGKM() __asm__ volatile("s_waitcnt lgkmcnt(0)\ns_barrier" ::: "memory")

typedef __attribute__((ext_vector_type(4))) float f32x4;
typedef __attribute__((ext_vector_type(8))) short s16x8;
typedef __attribute__((ext_vector_type(4))) unsigned int u32x4;
typedef __attribute__((ext_vector_type(2))) unsigned int u32x2;

constexpr int T = 256, E = 300, EP = 320, H = 128, H2 = 256, H3 = 384, H12 = 1536;
constexpr int M = 1024;            // B*T
constexpr int STY = 262144;        // 4*T*T elements per score type

DEV float b2f(unsigned short h) { return __uint_as_float(((unsigned)h) << 16); }
DEV unsigned short f2b(float f) {
  unsigned u = __float_as_uint(f);
  u += 0x7fff + ((u >> 16) & 1);            // RNE
  return (unsigned short)(u >> 16);
}
DEV unsigned cvt_pk_bf16(float lo, float hi) {   // dst = {bf16(lo), bf16(hi)} RNE
  unsigned r;
  __asm__("v_cvt_pk_bf16_f32 %0, %1, %2" : "=v"(r) : "v"(lo), "v"(hi));
  return r;
}
DEV float rcp_f(float x) {                       // v_rcp_f32: 1 ulp, 1 trans op
  float r;
  __asm__("v_rcp_f32 %0, %1" : "=v"(r) : "v"(x));
  return r;
}
DEV float sigm(float x) { return rcp_f(1.f + __expf(-x)); }
DEV float tanh_f(float x) {
  float e = __expf(2.f * x);
  return __builtin_fmaf(-2.f, rcp_f(e + 1.f), 1.f);
}
// lanes 0-31 <- x0, lanes 32-63 <- x1's lanes 0-31 (one v_permlane32_swap_b32)
DEV float plsel(float x0, float x1) {
  u32x2 r = __builtin_amdgcn_permlane32_swap(
      __float_as_uint(x0), __float_as_uint(x1), false, false);
  return __uint_as_float(r[0]);
}

DEV s16x8 ldfrag(const unsigned short* p) {
  u32x4 v = *(const u32x4*)p;
  return __builtin_bit_cast(s16x8, v);
}
DEV f32x4 mfma16(s16x8 a, s16x8 b, f32x4 c) {
  return __builtin_amdgcn_mfma_f32_16x16x32_bf16(a, b, c, 0, 0, 0);
}

// ---------------- fused staging: 9x cvt + embed + padw (flattened grid) -------

struct StageArgs {
  const float* cs[9]; unsigned short* cd[9]; int cn[9];
  const int* idx; const float* emb; unsigned short* xhi; unsigned short* xlo;
  const float* lW; const float* rW; unsigned short* wpad;
  int bo[12];                      // per-seg block offsets; bo[11] = total
};

__global__ void k_stage(StageArgs sa) {
  int blk = blockIdx.x;
  int seg = 0;
  #pragma unroll
  for (int s2 = 1; s2 < 11; ++s2) seg = (blk >= sa.bo[s2]) ? s2 : seg;
  int i = (blk - sa.bo[seg]) * 256 + threadIdx.x;
  if (seg < 9) {
    if (i < sa.cn[seg]) sa.cd[seg][i] = f2b(sa.cs[seg][i]);
    return;
  }
  if (seg == 9) {
    if (i >= M * EP) return;
    int m = i / EP, e = i - m * EP;
    int r = sa.idx[m];
    float v = (e < E) ? sa.emb[(size_t)r * E + e] : 0.f;
    unsigned short hi = f2b(v);
    sa.xhi[i] = hi;
    sa.xlo[i] = f2b(v - b2f(hi));
    return;
  }
  if (i >= 4 * H3 * EP) return;
  int e = i % EP, n = (i / EP) % H3, uu = i / (EP * H3);
  const float* src = (uu < 2 ? sa.lW : sa.rW) + (size_t)((uu & 1) * H3 + n) * E;
  sa.wpad[i] = (e < E) ? f2b(src[e]) : (unsigned short)0;
}

// ---------------- generic GEMM: C = (Ahi+Alo) @ W^T (+bias), fp32 out ----------
// tr=1: write transposed C_t[n*M + m] (for j-streamed consumers).

struct GemmDesc {
  const unsigned short* Ahi; const unsigned short* Alo; const unsigned short* W;
  const float* bias; float* Cf; int N; int K; int tr;
};
struct GemmBatch { GemmDesc d[8]; };

DEV void gemm_body(const GemmDesc& g, int mb, int nb, int tid) {
  int lane = tid & 63, w = tid >> 6, quad = lane >> 4, l16 = lane & 15;
  int K = g.K;
  const unsigned short* Ahp = g.Ahi + (size_t)(mb + w * 16 + l16) * K + quad * 8;
  const unsigned short* Alp = g.Alo + (size_t)(mb + w * 16 + l16) * K + quad * 8;
  const unsigned short* Wp = g.W + (size_t)(nb + l16) * K + quad * 8;
  f32x4 acc[4];
  #pragma unroll
  for (int nt = 0; nt < 4; ++nt) acc[nt] = f32x4{0.f, 0.f, 0.f, 0.f};
  for (int k = 0; k < K; k += 32) {
    s16x8 ah = ldfrag(Ahp + k);
    s16x8 al = ldfrag(Alp + k);
    #pragma unroll
    for (int nt = 0; nt < 4; ++nt) {
      s16x8 b = ldfrag(Wp + (size_t)nt * 16 * K + k);
      acc[nt] = mfma16(ah, b, acc[nt]);
      acc[nt] = mfma16(al, b, acc[nt]);
    }
  }
  int mr0 = mb + w * 16 + quad * 4;
  #pragma unroll
  for (int nt = 0; nt < 4; ++nt) {
    int col = nb + nt * 16 + l16;
    float bv = g.bias ? g.bias[col] : 0.f;
    #pragma unroll
    for (int r = 0; r < 4; ++r) {
      if (g.tr)
        g.Cf[(size_t)col * M + (mr0 + r)] = acc[nt][r] + bv;
      else
        g.Cf[(size_t)(mr0 + r) * g.N + col] = acc[nt][r] + bv;
    }
  }
}

__global__ __launch_bounds__(256) void k_gemm(GemmBatch gb) {
  GemmDesc g = gb.d[blockIdx.z];
  int nb = blockIdx.y * 64;
  if (nb >= g.N) return;
  gemm_body(g, blockIdx.x * 64, nb, threadIdx.x);
}

// ---------------- GRU recurrence v9 (R18 store placement + incr pointers) -----

struct RecArgs {
  const unsigned short* whh[4];
  const float* pre[4];
  float* outf[4];
  unsigned short* outhi[4];
  unsigned short* outlo[4];
  unsigned short* agghi[4];      // null -> no agg copy
  unsigned short* agglo[4];
  const float* bhh[4];
  int colOff[4];
  int dir[4];
};

// One recurrence step. pr_/pz_/pn_ are this step's pre-activations (bh_r/bh_z
// pre-added); refreshed from pq_ (advanced 2 steps) for step s+2. Output
// pointers advance by ost/ast per step (no per-step address mul).
#define GRU_STEP(pr_, pz_, pn_, pq_, hcur_, hnxt_)                             \
  {                                                                            \
    float pr = pr_, pz = pz_, pn = pn_;                                        \
    pq_ += pst2;                                                               \
    pr_ = pq_[0] + bh_r; pz_ = pq_[128] + bh_z; pn_ = pq_[256];                \
    const unsigned short* hb_ = hcur_ + l16 * 136 + quad * 8;                  \
    s16x8 ah0 = ldfrag(hb_);                                                   \
    s16x8 ah1 = ldfrag(hb_ + 32);                                              \
    s16x8 ah2 = ldfrag(hb_ + 64);                                              \
    s16x8 ah3 = ldfrag(hb_ + 96);                                              \
    f32x4 z4 = f32x4{0.f, 0.f, 0.f, 0.f};                                      \
    f32x4 aR0 = mfma16(ah0, bq[0][0], z4);                                     \
    f32x4 aR1 = mfma16(ah2, bq[0][2], z4);                                     \
    aR0 = mfma16(ah1, bq[0][1], aR0);                                          \
    aR1 = mfma16(ah3, bq[0][3], aR1);                                          \
    f32x4 aZ0 = mfma16(ah0, bq[1][0], z4);                                     \
    f32x4 aZ1 = mfma16(ah2, bq[1][2], z4);                                     \
    aZ0 = mfma16(ah1, bq[1][1], aZ0);                                          \
    aZ1 = mfma16(ah3, bq[1][3], aZ1);                                          \
    float r0 = (aR0[0] + aR1[0]) + (aR0[1] + aR1[1]);                          \
    float r1v = (aR0[2] + aR1[2]) + (aR0[3] + aR1[3]);                         \
    float rg = sigm(pr + plsel(r0, r1v));                                      \
    f32x4 aN0 = mfma16(ah0, bq[2][0], z4);                                     \
    f32x4 aN1 = mfma16(ah2, bq[2][2], z4);                                     \
    aN0 = mfma16(ah1, bq[2][1], aN0);                                          \
    aN1 = mfma16(ah3, bq[2][3], aN1);                                          \
    float z0 = (aZ0[0] + aZ1[0]) + (aZ0[1] + aZ1[1]);                          \
    float z1 = (aZ0[2] + aZ1[2]) + (aZ0[3] + aZ1[3]);                          \
    float zg = sigm(pz + plsel(z0, z1));                                       \
    float n0 = (aN0[0] + aN1[0]) + (aN0[1] + aN1[1]);                          \
    float n1 = (aN0[2] + aN1[2]) + (aN0[3] + aN1[3]);                          \
    float ng = tanh_f(pn + rg * (plsel(n0, n1) + bh_n));                       \
    hf = __builtin_fmaf(zg, hf - ng, ng);                                      \
    unsigned hp32 = cvt_pk_bf16(hf, hf);                                       \
    float rem = hf - __uint_as_float(hp32 << 16);                              \
    unsigned lp32 = cvt_pk_bf16(rem, rem);                                     \
    unsigned short hi = (unsigned short)hp32;                                  \
    unsigned short lo = (unsigned short)lp32;                                  \
    hnxt_[(2 * b) * 136 + d] = hi;                                             \
    hnxt_[(2 * b + 1) * 136 + d] = lo;                                         \
    *outf_p = hf; *outhi_p = hi; *outlo_p = lo;                                \
    outf_p += ost; outhi_p += ost; outlo_p += ost;                             \
    if (agghi_p) { *agghi_p = hi; *agglo_p = lo; agghi_p += ast; agglo_p += ast; } \
    BAR_LGKM();                                                                \
  }

__global__ __launch_bounds__(512) void k_gru(RecArgs ra) {
  int u = blockIdx.x;
  __shared__ __align__(16) unsigned short hs[2][16 * 136];
  int tid = threadIdx.x, lane = tid & 63, w8 = tid >> 6;
  int quad = lane >> 4, l16 = lane & 15;
  for (int i = tid; i < 2 * 16 * 136; i += 512) ((unsigned short*)hs)[i] = 0;
  const unsigned short* whh = ra.whh[u];
  s16x8 bq[3][4];
  #pragma unroll
  for (int g = 0; g < 3; ++g) {
    int row = g * 128 + w8 * 16 + l16;
    #pragma unroll
    for (int kc = 0; kc < 4; ++kc)
      bq[g][kc] = ldfrag(whh + (size_t)row * H + kc * 32 + quad * 8);
  }
  const float* bhh = ra.bhh[u];
  const float* pre = ra.pre[u];
  int colOff = ra.colOff[u], dir = ra.dir[u];
  int b = ((quad & 1) << 1) | (quad >> 1);
  int d = w8 * 16 + l16;
  float bh_r = bhh[d], bh_z = bhh[d + 128], bh_n = bhh[d + 256];
  float hf = 0.f;
  int t0 = dir ? (T - 1) : 0;
  long pst = dir ? -(long)H3 : (long)H3;
  long pst2 = 2 * pst;
  long ost = dir ? -(long)H2 : (long)H2;
  long ast = dir ? -(long)H12 : (long)H12;
  size_t o0 = (size_t)(b * T + t0) * H2 + colOff + d;
  size_t a0 = (size_t)(b * T + t0) * H12 + colOff + d;
  float* outf_p = ra.outf[u] + o0;
  unsigned short* outhi_p = ra.outhi[u] + o0;
  unsigned short* outlo_p = ra.outlo[u] + o0;
  unsigned short* agghi_p = ra.agghi[u] ? ra.agghi[u] + a0 : nullptr;
  unsigned short* agglo_p = ra.agglo[u] ? ra.agglo[u] + a0 : nullptr;
  // depth-2 prefetch: even/odd register pairs. Final iterations overrun the
  // unit's pre slab by <=2 rows (3KB) — lands in adjacent ws regions, unused.
  const float* pqE = pre + (size_t)(b * T + t0) * H3 + d;
  const float* pqO = pqE + pst;
  float e_pr = pqE[0] + bh_r, e_pz = pqE[128] + bh_z, e_pn = pqE[256];
  float o_pr = pqO[0] + bh_r, o_pz = pqO[128] + bh_z, o_pn = pqO[256];
  __syncthreads();
  for (int s = 0; s < T; s += 2) {
    GRU_STEP(e_pr, e_pz, e_pn, pqE, hs[0], hs[1]);
    GRU_STEP(o_pr, o_pz, o_pn, pqO, hs[1], hs[0]);
  }
}

// ---------------- fused: projection GEMMs (y<6) + MFMA scores (y>=6) ----------
// gemm and scmm are independent (scmm reads only hl_hi/hr_hi) — one dispatch
// lets them co-execute instead of serializing on the stream.

struct ScMMArgs {
  const unsigned short* Xhi[2];
  const float* Rf; const float* Wt[2]; const float* vt[2];
  float* So[2]; float* So2[2];
};
struct FuseArgs { GemmDesc d[6]; ScMMArgs sm; };

__global__ __launch_bounds__(256, 2) void k_fuse(FuseArgs fa) {
  __shared__ __align__(16) unsigned short w_lds[64 * 256];   // 32KB (scmm path)
  int y = blockIdx.y;
  int tid = threadIdx.x;
  if (y < 6) {
    int xx = blockIdx.x;
    if (xx >= 64) return;
    GemmDesc g = fa.d[y];
    int nb = (xx >> 4) * 64;
    if (nb >= g.N) return;
    gemm_body(g, (xx & 15) * 64, nb, tid);
    return;
  }
  const ScMMArgs& a = fa.sm;
  int which = y - 6;
  int bi = blockIdx.x, b = bi >> 8;
  int type = which >> 1, khb = which & 1;
  const unsigned short* Xhi = a.Xhi[type];
  const float* W = a.Wt[type] + (size_t)khb * 64 * 256;
  const float* v = a.vt[type] + khb * 64;
  float* Sout = khb ? a.So2[type] : a.So[type];
  int lane = tid & 63, w = tid >> 6, quad = lane >> 4, l16 = lane & 15;
  int d4 = tid & 63, rhi = tid >> 6;
  float4 h4 = ((const float4*)(a.Rf + (size_t)bi * 256))[d4];
  #pragma unroll
  for (int it = 0; it < 16; ++it) {
    int kl = it * 4 + rhi;                            // local row 0..63
    float4 w4 = ((const float4*)(W + (size_t)kl * 256))[d4];
    unsigned lo32 = cvt_pk_bf16(w4.x * h4.x, w4.y * h4.y);
    unsigned hi32 = cvt_pk_bf16(w4.z * h4.z, w4.w * h4.w);
    unsigned long long pk = (unsigned long long)lo32 | ((unsigned long long)hi32 << 32);
    int gphys = ((d4 >> 1) + kl) & 31;
    *(unsigned long long*)(w_lds + (size_t)kl * 256 + gphys * 8 + (d4 & 1) * 4) = pk;
  }
  BAR_LGKM();
  f32x4 acc[4][4];
  #pragma unroll
  for (int jj = 0; jj < 4; ++jj)
    #pragma unroll
    for (int c = 0; c < 4; ++c) acc[jj][c] = f32x4{0.f, 0.f, 0.f, 0.f};
  const unsigned short* Xp0 =
      Xhi + (size_t)(b * 256 + w * 4 * 16 + l16) * 256 + quad * 8;
  #pragma unroll 2
  for (int kc = 0; kc < 8; ++kc) {
    s16x8 af[4];
    #pragma unroll
    for (int c = 0; c < 4; ++c) {
      int krow = c * 16 + l16;
      int gp = (kc * 4 + quad + krow) & 31;
      af[c] = ldfrag(w_lds + (size_t)krow * 256 + gp * 8);
    }
    s16x8 bf[4];
    #pragma unroll
    for (int jj = 0; jj < 4; ++jj)
      bf[jj] = ldfrag(Xp0 + (size_t)jj * 16 * 256 + kc * 32);
    #pragma unroll
    for (int jj = 0; jj < 4; ++jj)
      #pragma unroll
      for (int c = 0; c < 4; ++c)
        acc[jj][c] = mfma16(af[c], bf[jj], acc[jj][c]);
  }
  float vv[4][4];
  #pragma unroll
  for (int c = 0; c < 4; ++c)
    #pragma unroll
    for (int r = 0; r < 4; ++r) vv[c][r] = v[c * 16 + quad * 4 + r];
  #pragma unroll
  for (int jj = 0; jj < 4; ++jj) {
    float s = 0.f;
    #pragma unroll
    for (int c = 0; c < 4; ++c)
      #pragma unroll
      for (int r = 0; r < 4; ++r) s += tanh_f(acc[jj][c][r]) * vv[c][r];
    s += __shfl_xor(s, 16);
    s += __shfl_xor(s, 32);
    int jt = w * 4 + jj;
    if (lane < 16) Sout[(size_t)bi * 256 + jt * 16 + l16] = s;
  }
}

// ---------------- scores cmb path (grid 256, 4 i-rows/block) ------------------

struct ScCmbArgs {
  const float *Hc, *Rc, *Hm, *Rm, *HB, *hrf, *vcf, *vmf; float* S;
};

__global__ __launch_bounds__(256, 2) void k_sccmb(ScCmbArgs a) {
  int bi = blockIdx.x;
  int tid = threadIdx.x;
  __shared__ float rc_l[4 * 128];
  __shared__ float rm_l[4 * 128];
  __shared__ float hr_l[4 * 256];
  __shared__ float vc_l[128], vm_l[128];
  int b = bi >> 6, i0 = (bi & 63) << 2;       // 4 i-rows: gi0..gi0+3
  int gi0 = b * 256 + i0;
  {
    const float4* hr4 = (const float4*)(a.hrf + (size_t)gi0 * 256);
    ((float4*)hr_l)[tid] = hr4[tid];
    if (tid < 128) {
      const float4* rc4 = (const float4*)(a.Rc + (size_t)gi0 * 128);
      const float4* rm4 = (const float4*)(a.Rm + (size_t)gi0 * 128);
      ((float4*)rc_l)[tid] = rc4[tid];
      ((float4*)rm_l)[tid] = rm4[tid];
      vc_l[tid] = a.vcf[tid]; vm_l[tid] = a.vmf[tid];
    }
  }
  __syncthreads();
  int j = tid;
  size_t cb = (size_t)(b * 256 + j);
  float scq[4], smq[4], sbq[4];
  #pragma unroll
  for (int q = 0; q < 4; ++q) { scq[q] = 0.f; smq[q] = 0.f; sbq[q] = 0.f; }
  for (int k = 0; k < 128; ++k) {
    float hc = a.Hc[(size_t)k * M + cb];      // transposed: lane-consecutive
    float hm = a.Hm[(size_t)k * M + cb];
    float vck = vc_l[k], vmk = vm_l[k];
    #pragma unroll
    for (int q = 0; q < 4; ++q) {
      scq[q] += vck * tanh_f(hc + rc_l[q * 128 + k]);
      smq[q] += vmk * tanh_f(hm - rm_l[q * 128 + k]);
    }
  }
  for (int k = 0; k < 256; ++k) {
    float hb = a.HB[(size_t)k * M + cb];      // transposed
    #pragma unroll
    for (int q = 0; q < 4; ++q) sbq[q] += hb * hr_l[q * 256 + k];
  }
  #pragma unroll
  for (int q = 0; q < 4; ++q) {
    size_t o = (size_t)(gi0 + q) * 256 + j;
    a.S[(size_t)STY * 1 + o] = scq[q];
    a.S[(size_t)STY * 3 + o] = sbq[q];
    a.S[(size_t)STY * 4 + o] = smq[q];
  }
}

// ---------------- wsum with inline softmax (adds kh-half partials) ------------

__global__ __launch_bounds__(256) void k_wsum(const float* __restrict__ S,
    const float* __restrict__ S2,
    const float* __restrict__ hl_f, const float* __restrict__ hr_f,
    unsigned short* __restrict__ ahi, unsigned short* __restrict__ alo) {
  int it = blockIdx.x, type = blockIdx.y, b = blockIdx.z;
  __shared__ float p_l[8][256];
  __shared__ float red[4];
  int tid = threadIdx.x;
  for (int ii = 0; ii < 8; ++ii) {
    size_t idx = ((size_t)(b * 256 + it * 8 + ii)) * 256 + tid;
    float x = S[(size_t)type * STY + idx];
    if (type == 0) x += S2[idx];                        // pts partial (kh1)
    else if (type == 2) x += S2[(size_t)STY + idx];     // ptd partial (kh1)
    float m = x;
    for (int dl = 32; dl; dl >>= 1) m = fmaxf(m, __shfl_xor(m, dl));
    if ((tid & 63) == 0) red[tid >> 6] = m;
    __syncthreads();
    m = fmaxf(fmaxf(red[0], red[1]), fmaxf(red[2], red[3]));
    __syncthreads();
    float e = __expf(x - m);
    float sum = e;
    for (int dl = 32; dl; dl >>= 1) sum += __shfl_xor(sum, dl);
    if ((tid & 63) == 0) red[tid >> 6] = sum;
    __syncthreads();
    sum = red[0] + red[1] + red[2] + red[3];
    p_l[ii][tid] = e * rcp_f(sum);
    __syncthreads();
  }
  const float* src = (type == 0 ? hr_f : hl_f) + (size_t)b * 256 * 256;
  float acc[8] = {0.f, 0.f, 0.f, 0.f, 0.f, 0.f, 0.f, 0.f};
  for (int j = 0; j < 256; ++j) {
    float hv = src[(size_t)j * 256 + tid];
    #pragma unroll
    for (int ii = 0; ii < 8; ++ii) acc[ii] += p_l[ii][j] * hv;
  }
  int off = 256 * (1 + type);      // agg: [hr | pts | ptc | ptd | ptb | ptm]
  #pragma unroll
  for (int ii = 0; ii < 8; ++ii) {
    float vv = acc[ii];
    unsigned short hi = f2b(vv);
    size_t o = (size_t)(b * 256 + it * 8 + ii) * H12 + off + tid;
    ahi[o] = hi;
    alo[o] = f2b(vv - b2f(hi));
  }
}

// ---------------- fused tail ----------------

__global__ __launch_bounds__(256) void k_tail(const float* __restrict__ Hp,
    const float* __restrict__ hl_f, const float* __restrict__ vpf,
    const float* __restrict__ Wc2f, const float* __restrict__ Arc,
    const float* __restrict__ ar_f, const float* __restrict__ vcf,
    const float* __restrict__ Wpredf, float* __restrict__ out) {
  int b = blockIdx.x, tid = threadIdx.x;
  __shared__ float vl[128], wl[256], rvec[256], rlcl[128], red[4];
  if (tid < 128) vl[tid] = vpf[tid];
  __syncthreads();
  const float* hp = Hp + (size_t)(b * 256 + tid) * 128;
  float s = 0.f;
  for (int k = 0; k < 128; ++k) s += vl[k] * tanh_f(hp[k]);
  float m = s;
  for (int dl = 32; dl; dl >>= 1) m = fmaxf(m, __shfl_xor(m, dl));
  if ((tid & 63) == 0) red[tid >> 6] = m;
  __syncthreads();
  m = fmaxf(fmaxf(red[0], red[1]), fmaxf(red[2], red[3]));
  __syncthreads();
  float e = __expf(s - m);
  float sum = e;
  for (int dl = 32; dl; dl >>= 1) sum += __shfl_xor(sum, dl);
  if ((tid & 63) == 0) red[tid >> 6] = sum;
  __syncthreads();
  sum = red[0] + red[1] + red[2] + red[3];
  wl[tid] = e * rcp_f(sum);
  __syncthreads();
  float acc = 0.f;
  for (int t = 0; t < 256; ++t) acc += wl[t] * hl_f[(size_t)(b * 256 + t) * 256 + tid];
  rvec[tid] = acc;
  __syncthreads();
  if (tid < 128) {
    float a2 = 0.f;
    const float* wr = Wc2f + (size_t)tid * 256;
    for (int dk = 0; dk < 256; ++dk) a2 += rvec[dk] * wr[dk];
    rlcl[tid] = a2;
    vl[tid] = vcf[tid];
  }
  __syncthreads();
  const float* ap = Arc + (size_t)(b * 256 + tid) * 128;
  float s2 = 0.f;
  for (int k = 0; k < 128; ++k) s2 += vl[k] * (ap[k] + rlcl[k]);
  m = s2;
  for (int dl = 32; dl; dl >>= 1) m = fmaxf(m, __shfl_xor(m, dl));
  if ((tid & 63) == 0) red[tid >> 6] = m;
  __syncthreads();
  m = fmaxf(fmaxf(red[0], red[1]), fmaxf(red[2], red[3]));
  __syncthreads();
  float e2 = __expf(s2 - m);
  float sum2 = e2;
  for (int dl = 32; dl; dl >>= 1) sum2 += __shfl_xor(sum2, dl);
  if ((tid & 63) == 0) red[tid >> 6] = sum2;
  __syncthreads();
  sum2 = red[0] + red[1] + red[2] + red[3];
  wl[tid] = e2 * rcp_f(sum2);
  __syncthreads();
  float acc2 = 0.f;
  for (int t = 0; t < 256; ++t) acc2 += wl[t] * ar_f[(size_t)(b * 256 + t) * 256 + tid];
  rvec[tid] = acc2;
  __syncthreads();
  if (tid < 2) {
    float o = 0.f;
    const float* wp = Wpredf + (size_t)tid * 256;
    for (int dk = 0; dk < 256; ++dk) o += rvec[dk] * wp[dk];
    out[b * 2 + tid] = sigm(o);
  }
}

// ---------------- host ----------------

extern "C" void kernel_launch(void* const* d_in, const int* in_sizes, int n_in,
                              void* d_out, int out_size, void* d_ws, size_t ws_size,
                              hipStream_t stream) {
  (void)in_sizes; (void)n_in; (void)out_size; (void)ws_size;
  const int* inputs = (const int*)d_in[0];
  const float* embed = (const float*)d_in[1];
  const float* lWih = (const float*)d_in[2];
  const float* lWhh = (const float*)d_in[3];
  const float* lbih = (const float*)d_in[4];
  const float* lbhh = (const float*)d_in[5];
  const float* rWih = (const float*)d_in[6];
  const float* rWhh = (const float*)d_in[7];
  const float* rbih = (const float*)d_in[8];
  const float* rbhh = (const float*)d_in[9];
  const float* aWih = (const float*)d_in[10];
  const float* aWhh = (const float*)d_in[11];
  const float* abih = (const float*)d_in[12];
  const float* abhh = (const float*)d_in[13];
  const float* Wc1 = (const float*)d_in[14];
  const float* Wc2 = (const float*)d_in[15];
  const float* vc  = (const float*)d_in[16];
  const float* Wb  = (const float*)d_in[17];
  const float* Wd  = (const float*)d_in[18];
  const float* vd  = (const float*)d_in[19];
  const float* Wm  = (const float*)d_in[20];
  const float* vmv = (const float*)d_in[21];
  const float* Wsw = (const float*)d_in[22];
  const float* vsv = (const float*)d_in[23];
  const float* Wp  = (const float*)d_in[24];
  const float* vp  = (const float*)d_in[25];
  const float* Wpred = (const float*)d_in[26];

  char* ws = (char*)d_ws;
  size_t off = 0;
  auto alloc = [&](size_t bytes) -> void* {
    void* p = ws + off;
    off += (bytes + 255) & ~(size_t)255;
    return p;
  };
  unsigned short* xhi = (unsigned short*)alloc((size_t)M * EP * 2);
  unsigned short* xlo = (unsigned short*)alloc((size_t)M * EP * 2);
  unsigned short* wpad = (unsigned short*)alloc((size_t)4 * H3 * EP * 2);
  unsigned short* Whh_b = (unsigned short*)alloc((size_t)6 * H3 * H * 2);
  unsigned short* aWih_b = (unsigned short*)alloc((size_t)2 * H3 * H12 * 2);
  unsigned short* Wc1_b = (unsigned short*)alloc((size_t)H * H2 * 2);
  unsigned short* Wc2_b = (unsigned short*)alloc((size_t)H * H2 * 2);
  unsigned short* Wm_b  = (unsigned short*)alloc((size_t)H * H2 * 2);
  unsigned short* Wp_b  = (unsigned short*)alloc((size_t)H * H2 * 2);
  unsigned short* Wb_b  = (unsigned short*)alloc((size_t)H2 * H2 * 2);
  char* region1 = (char*)alloc((size_t)4 * M * H3 * 4);
  float* pre_lr = (float*)region1;
  float* S      = (float*)region1;
  float* pre_a  = (float*)region1;
  float* S2 = (float*)alloc((size_t)2 * STY * 4);   // kh1 partials: [pts | ptd]
  float* hl_f = (float*)alloc((size_t)M * H2 * 4);
  float* hr_f = (float*)alloc((size_t)M * H2 * 4);
  unsigned short* hl_hi = (unsigned short*)alloc((size_t)M * H2 * 2);
  unsigned short* hl_lo = (unsigned short*)alloc((size_t)M * H2 * 2);
  unsigned short* hr_hi = (unsigned short*)alloc((size_t)M * H2 * 2);
  unsigned short* hr_lo = (unsigned short*)alloc((size_t)M * H2 * 2);
  float* Hc = (float*)alloc((size_t)M * H * 4);     // transposed [H][M]
  float* Rc = (float*)alloc((size_t)M * H * 4);
  float* Hm = (float*)alloc((size_t)M * H * 4);     // transposed [H][M]
  float* Rm = (float*)alloc((size_t)M * H * 4);
  float* Hp = (float*)alloc((size_t)M * H * 4);
  float* HB = (float*)alloc((size_t)M * H2 * 4);    // transposed [H2][M]
  unsigned short* agg_hi = (unsigned short*)alloc((size_t)M * H12 * 2);
  unsigned short* agg_lo = (unsigned short*)alloc((size_t)M * H12 * 2);
  float* ar_f = (float*)alloc((size_t)M * H2 * 4);
  unsigned short* ar_hi = (unsigned short*)alloc((size_t)M * H2 * 2);
  unsigned short* ar_lo = (unsigned short*)alloc((size_t)M * H2 * 2);
  float* Arc = (float*)alloc((size_t)M * H * 4);

  // 1. staging (flattened grid)
  StageArgs sa{};
  sa.cs[0] = lWhh;  sa.cd[0] = Whh_b;                 sa.cn[0] = 2 * H3 * H;
  sa.cs[1] = rWhh;  sa.cd[1] = Whh_b + 2 * H3 * H;    sa.cn[1] = 2 * H3 * H;
  sa.cs[2] = aWhh;  sa.cd[2] = Whh_b + 4 * H3 * H;    sa.cn[2] = 2 * H3 * H;
  sa.cs[3] = aWih;  sa.cd[3] = aWih_b;                sa.cn[3] = 2 * H3 * H12;
  sa.cs[4] = Wc1;   sa.cd[4] = Wc1_b;                 sa.cn[4] = H * H2;
  sa.cs[5] = Wc2;   sa.cd[5] = Wc2_b;                 sa.cn[5] = H * H2;
  sa.cs[6] = Wm;    sa.cd[6] = Wm_b;                  sa.cn[6] = H * H2;
  sa.cs[7] = Wp;    sa.cd[7] = Wp_b;                  sa.cn[7] = H * H2;
  sa.cs[8] = Wb;    sa.cd[8] = Wb_b;                  sa.cn[8] = H2 * H2;
  sa.idx = inputs; sa.emb = embed; sa.xhi = xhi; sa.xlo = xlo;
  sa.lW = lWih; sa.rW = rWih; sa.wpad = wpad;
  {
    int acc0 = 0;
    sa.bo[0] = 0;
    for (int s = 0; s < 9; ++s) { acc0 += (sa.cn[s] + 255) / 256; sa.bo[s + 1] = acc0; }
    acc0 += (M * EP + 255) / 256;       sa.bo[10] = acc0;
    acc0 += (4 * H3 * EP + 255) / 256;  sa.bo[11] = acc0;
  }
  k_stage<<<dim3(sa.bo[11]), dim3(256), 0, stream>>>(sa);

  // 2. input projections for l/r GRUs
  GemmBatch ga{};
  const float* biases[4] = { lbih, lbih + H3, rbih, rbih + H3 };
  for (int u = 0; u < 4; ++u)
    ga.d[u] = GemmDesc{ xhi, xlo, wpad + (size_t)u * H3 * EP, biases[u],
                        pre_lr + (size_t)u * M * H3, H3, EP, 0 };
  k_gemm<<<dim3(16, 6, 4), dim3(256), 0, stream>>>(ga);

  // 3. l/r recurrences (writes fp32 + hi/lo + agg hr-copy); 1 unit per block
  RecArgs r1{};
  r1.whh[0] = Whh_b;               r1.whh[1] = Whh_b + H3 * H;
  r1.whh[2] = Whh_b + 2 * H3 * H;  r1.whh[3] = Whh_b + 3 * H3 * H;
  for (int u = 0; u < 4; ++u) r1.pre[u] = pre_lr + (size_t)u * M * H3;
  r1.outf[0] = r1.outf[1] = hl_f; r1.outf[2] = r1.outf[3] = hr_f;
  r1.outhi[0] = r1.outhi[1] = hl_hi; r1.outhi[2] = r1.outhi[3] = hr_hi;
  r1.outlo[0] = r1.outlo[1] = hl_lo; r1.outlo[2] = r1.outlo[3] = hr_lo;
  r1.agghi[0] = r1.agghi[1] = nullptr; r1.agghi[2] = r1.agghi[3] = agg_hi;
  r1.agglo[0] = r1.agglo[1] = nullptr; r1.agglo[2] = r1.agglo[3] = agg_lo;
  r1.bhh[0] = lbhh; r1.bhh[1] = lbhh + H3; r1.bhh[2] = rbhh; r1.bhh[3] = rbhh + H3;
  r1.colOff[0] = 0; r1.colOff[1] = H; r1.colOff[2] = 0; r1.colOff[3] = H;
  r1.dir[0] = 0; r1.dir[1] = 1; r1.dir[2] = 0; r1.dir[3] = 1;
  k_gru<<<dim3(4), dim3(512), 0, stream>>>(r1);

  // 4+5a. fused projection GEMMs + MFMA scores (independent; co-execute)
  FuseArgs fu{};
  fu.d[0] = GemmDesc{ hl_hi, hl_lo, Wc1_b, nullptr, Hc, H, H2, 1 };
  fu.d[1] = GemmDesc{ hr_hi, hr_lo, Wc2_b, nullptr, Rc, H, H2, 0 };
  fu.d[2] = GemmDesc{ hl_hi, hl_lo, Wm_b, nullptr, Hm, H, H2, 1 };
  fu.d[3] = GemmDesc{ hr_hi, hr_lo, Wm_b, nullptr, Rm, H, H2, 0 };
  fu.d[4] = GemmDesc{ hl_hi, hl_lo, Wb_b, nullptr, HB, H2, H2, 1 };
  fu.d[5] = GemmDesc{ hl_hi, hl_lo, Wp_b, nullptr, Hp, H, H2, 0 };
  fu.sm.Xhi[0] = hl_hi; fu.sm.Wt[0] = Wd;  fu.sm.vt[0] = vd;
  fu.sm.So[0] = S + (size_t)2 * STY;
  fu.sm.Xhi[1] = hr_hi; fu.sm.Wt[1] = Wsw; fu.sm.vt[1] = vsv;
  fu.sm.So[1] = S + (size_t)0 * STY;
  fu.sm.So2[0] = S2 + (size_t)STY;   // ptd kh1 partial
  fu.sm.So2[1] = S2;                 // pts kh1 partial
  fu.sm.Rf = hr_f;
  k_fuse<<<dim3(M, 10), dim3(256), 0, stream>>>(fu);

  // 5b. combined ptc/ptb/ptm scores (4 i-rows/block)
  ScCmbArgs scb{};
  scb.Hc = Hc; scb.Rc = Rc; scb.Hm = Hm; scb.Rm = Rm; scb.HB = HB;
  scb.hrf = hr_f; scb.vcf = vc; scb.vmf = vmv; scb.S = S;
  k_sccmb<<<dim3(256), dim3(256), 0, stream>>>(scb);

  // 6. softmax + weighted sums into agg
  k_wsum<<<dim3(32, 5, 4), dim3(256), 0, stream>>>(S, S2, hl_f, hr_f, agg_hi, agg_lo);

  // 7. agg GRU input projection
  GemmBatch gc{};
  gc.d[0] = GemmDesc{ agg_hi, agg_lo, aWih_b, abih, pre_a, H3, H12, 0 };
  gc.d[1] = GemmDesc{ agg_hi, agg_lo, aWih_b + (size_t)H3 * H12, abih + H3,
                      pre_a + (size_t)M * H3, H3, H12, 0 };
  k_gemm<<<dim3(16, 6, 2), dim3(256), 0, stream>>>(gc);

  // 8. agg recurrence (writes ar fp32 + hi/lo); 1 unit per block
  RecArgs r2{};
  r2.whh[0] = Whh_b + 4 * H3 * H; r2.whh[1] = Whh_b + 5 * H3 * H;
  r2.whh[2] = r2.whh[3] = Whh_b + 4 * H3 * H;
  r2.pre[0] = pre_a; r2.pre[1] = pre_a + (size_t)M * H3;
  r2.pre[2] = r2.pre[3] = pre_a;
  r2.outf[0] = r2.outf[1] = r2.outf[2] = r2.outf[3] = ar_f;
  r2.outhi[0] = r2.outhi[1] = r2.outhi[2] = r2.outhi[3] = ar_hi;
  r2.outlo[0] = r2.outlo[1] = r2.outlo[2] = r2.outlo[3] = ar_lo;
  for (int u = 0; u < 4; ++u) { r2.agghi[u] = nullptr; r2.agglo[u] = nullptr; }
  r2.bhh[0] = abhh; r2.bhh[1] = abhh + H3; r2.bhh[2] = r2.bhh[3] = abhh;
  r2.colOff[0] = 0; r2.colOff[1] = H; r2.colOff[2] = r2.colOff[3] = 0;
  r2.dir[0] = 0; r2.dir[1] = 1; r2.dir[2] = r2.dir[3] = 0;
  k_gru<<<dim3(2), dim3(512), 0, stream>>>(r2);

  // 9. Arc GEMM
  GemmBatch gd{};
  gd.d[0] = GemmDesc{ ar_hi, ar_lo, Wc1_b, nullptr, Arc, H, H2, 0 };
  k_gemm<<<dim3(16, 2, 1), dim3(256), 0, stream>>>(gd);

  // 10. fused tail
  k_tail<<<dim3(4), dim3(256), 0, stream>>>(Hp, hl_f, vp, Wc2, Arc, ar_f, vc, Wpred,
                                            (float*)d_out);
}

// Round 12
// 658.849 us; speedup vs baseline: 1.0602x; 1.0260x over previous
//
#include <hip/hip_runtime.h>

// MANNet forward, MI355X gfx950. Inputs fp32 (+int32 ids), output fp32.
// R21: scmm kh-halves merged. Each (bi,type) was TWO blocks (kh 0/1), each
// re-reading X[b] (512MB L2 total) and paying the full stage->barrier->compute
// ramp. Now ONE 512-thread block stages the full 128-row W⊙h (64KB LDS), reads
// X once (256MB total), accumulates acc[2][8] (64 VGPR accumulator-class — the
// kind R16 proved the compiler keeps), writes FINAL scores (S2 partials and
// wsum's partial-adds eliminated). Co-fused GEMMs do 2 m-tiles per 512-block.

#define DEV static __device__ __forceinline__
#define BAR_LGKM() __asm__ volatile("s_waitcnt lgkmcnt(0)\ns_barrier" ::: "memory")

typedef __attribute__((ext_vector_type(4))) float f32x4;
typedef __attribute__((ext_vector_type(8))) short s16x8;
typedef __attribute__((ext_vector_type(4))) unsigned int u32x4;
typedef __attribute__((ext_vector_type(2))) unsigned int u32x2;

constexpr int T = 256, E = 300, EP = 320, H = 128, H2 = 256, H3 = 384, H12 = 1536;
constexpr int M = 1024;            // B*T
constexpr int STY = 262144;        // 4*T*T elements per score type

DEV float b2f(unsigned short h) { return __uint_as_float(((unsigned)h) << 16); }
DEV unsigned short f2b(float f) {
  unsigned u = __float_as_uint(f);
  u += 0x7fff + ((u >> 16) & 1);            // RNE
  return (unsigned short)(u >> 16);
}
DEV unsigned cvt_pk_bf16(float lo, float hi) {   // dst = {bf16(lo), bf16(hi)} RNE
  unsigned r;
  __asm__("v_cvt_pk_bf16_f32 %0, %1, %2" : "=v"(r) : "v"(lo), "v"(hi));
  return r;
}
DEV float rcp_f(float x) {                       // v_rcp_f32: 1 ulp, 1 trans op
  float r;
  __asm__("v_rcp_f32 %0, %1" : "=v"(r) : "v"(x));
  return r;
}
DEV float sigm(float x) { return rcp_f(1.f + __expf(-x)); }
DEV float tanh_f(float x) {
  float e = __expf(2.f * x);
  return __builtin_fmaf(-2.f, rcp_f(e + 1.f), 1.f);
}
// lanes 0-31 <- x0, lanes 32-63 <- x1's lanes 0-31 (one v_permlane32_swap_b32)
DEV float plsel(float x0, float x1) {
  u32x2 r = __builtin_amdgcn_permlane32_swap(
      __float_as_uint(x0), __float_as_uint(x1), false, false);
  return __uint_as_float(r[0]);
}

DEV s16x8 ldfrag(const unsigned short* p) {
  u32x4 v = *(const u32x4*)p;
  return __builtin_bit_cast(s16x8, v);
}
DEV f32x4 mfma16(s16x8 a, s16x8 b, f32x4 c) {
  return __builtin_amdgcn_mfma_f32_16x16x32_bf16(a, b, c, 0, 0, 0);
}

// ---------------- fused staging: 9x cvt + embed + padw (flattened grid) -------

struct StageArgs {
  const float* cs[9]; unsigned short* cd[9]; int cn[9];
  const int* idx; const float* emb; unsigned short* xhi; unsigned short* xlo;
  const float* lW; const float* rW; unsigned short* wpad;
  int bo[12];                      // per-seg block offsets; bo[11] = total
};

__global__ void k_stage(StageArgs sa) {
  int blk = blockIdx.x;
  int seg = 0;
  #pragma unroll
  for (int s2 = 1; s2 < 11; ++s2) seg = (blk >= sa.bo[s2]) ? s2 : seg;
  int i = (blk - sa.bo[seg]) * 256 + threadIdx.x;
  if (seg < 9) {
    if (i < sa.cn[seg]) sa.cd[seg][i] = f2b(sa.cs[seg][i]);
    return;
  }
  if (seg == 9) {
    if (i >= M * EP) return;
    int m = i / EP, e = i - m * EP;
    int r = sa.idx[m];
    float v = (e < E) ? sa.emb[(size_t)r * E + e] : 0.f;
    unsigned short hi = f2b(v);
    sa.xhi[i] = hi;
    sa.xlo[i] = f2b(v - b2f(hi));
    return;
  }
  if (i >= 4 * H3 * EP) return;
  int e = i % EP, n = (i / EP) % H3, uu = i / (EP * H3);
  const float* src = (uu < 2 ? sa.lW : sa.rW) + (size_t)((uu & 1) * H3 + n) * E;
  sa.wpad[i] = (e < E) ? f2b(src[e]) : (unsigned short)0;
}

// ---------------- generic GEMM: C = (Ahi+Alo) @ W^T (+bias), fp32 out ----------
// tr=1: write transposed C_t[n*M + m] (for j-streamed consumers).

struct GemmDesc {
  const unsigned short* Ahi; const unsigned short* Alo; const unsigned short* W;
  const float* bias; float* Cf; int N; int K; int tr;
};
struct GemmBatch { GemmDesc d[8]; };

DEV void gemm_body(const GemmDesc& g, int mb, int nb, int tid) {
  int lane = tid & 63, w = tid >> 6, quad = lane >> 4, l16 = lane & 15;
  int K = g.K;
  const unsigned short* Ahp = g.Ahi + (size_t)(mb + w * 16 + l16) * K + quad * 8;
  const unsigned short* Alp = g.Alo + (size_t)(mb + w * 16 + l16) * K + quad * 8;
  const unsigned short* Wp = g.W + (size_t)(nb + l16) * K + quad * 8;
  f32x4 acc[4];
  #pragma unroll
  for (int nt = 0; nt < 4; ++nt) acc[nt] = f32x4{0.f, 0.f, 0.f, 0.f};
  for (int k = 0; k < K; k += 32) {
    s16x8 ah = ldfrag(Ahp + k);
    s16x8 al = ldfrag(Alp + k);
    #pragma unroll
    for (int nt = 0; nt < 4; ++nt) {
      s16x8 b = ldfrag(Wp + (size_t)nt * 16 * K + k);
      acc[nt] = mfma16(ah, b, acc[nt]);
      acc[nt] = mfma16(al, b, acc[nt]);
    }
  }
  int mr0 = mb + w * 16 + quad * 4;
  #pragma unroll
  for (int nt = 0; nt < 4; ++nt) {
    int col = nb + nt * 16 + l16;
    float bv = g.bias ? g.bias[col] : 0.f;
    #pragma unroll
    for (int r = 0; r < 4; ++r) {
      if (g.tr)
        g.Cf[(size_t)col * M + (mr0 + r)] = acc[nt][r] + bv;
      else
        g.Cf[(size_t)(mr0 + r) * g.N + col] = acc[nt][r] + bv;
    }
  }
}

__global__ __launch_bounds__(256) void k_gemm(GemmBatch gb) {
  GemmDesc g = gb.d[blockIdx.z];
  int nb = blockIdx.y * 64;
  if (nb >= g.N) return;
  gemm_body(g, blockIdx.x * 64, nb, threadIdx.x);
}

// ---------------- GRU recurrence v9 (R18 store placement + incr pointers) -----

struct RecArgs {
  const unsigned short* whh[4];
  const float* pre[4];
  float* outf[4];
  unsigned short* outhi[4];
  unsigned short* outlo[4];
  unsigned short* agghi[4];      // null -> no agg copy
  unsigned short* agglo[4];
  const float* bhh[4];
  int colOff[4];
  int dir[4];
};

#define GRU_STEP(pr_, pz_, pn_, pq_, hcur_, hnxt_)                             \
  {                                                                            \
    float pr = pr_, pz = pz_, pn = pn_;                                        \
    pq_ += pst2;                                                               \
    pr_ = pq_[0] + bh_r; pz_ = pq_[128] + bh_z; pn_ = pq_[256];                \
    const unsigned short* hb_ = hcur_ + l16 * 136 + quad * 8;                  \
    s16x8 ah0 = ldfrag(hb_);                                                   \
    s16x8 ah1 = ldfrag(hb_ + 32);                                              \
    s16x8 ah2 = ldfrag(hb_ + 64);                                              \
    s16x8 ah3 = ldfrag(hb_ + 96);                                              \
    f32x4 z4 = f32x4{0.f, 0.f, 0.f, 0.f};                                      \
    f32x4 aR0 = mfma16(ah0, bq[0][0], z4);                                     \
    f32x4 aR1 = mfma16(ah2, bq[0][2], z4);                                     \
    aR0 = mfma16(ah1, bq[0][1], aR0);                                          \
    aR1 = mfma16(ah3, bq[0][3], aR1);                                          \
    f32x4 aZ0 = mfma16(ah0, bq[1][0], z4);                                     \
    f32x4 aZ1 = mfma16(ah2, bq[1][2], z4);                                     \
    aZ0 = mfma16(ah1, bq[1][1], aZ0);                                          \
    aZ1 = mfma16(ah3, bq[1][3], aZ1);                                          \
    float r0 = (aR0[0] + aR1[0]) + (aR0[1] + aR1[1]);                          \
    float r1v = (aR0[2] + aR1[2]) + (aR0[3] + aR1[3]);                         \
    float rg = sigm(pr + plsel(r0, r1v));                                      \
    f32x4 aN0 = mfma16(ah0, bq[2][0], z4);                                     \
    f32x4 aN1 = mfma16(ah2, bq[2][2], z4);                                     \
    aN0 = mfma16(ah1, bq[2][1], aN0);                                          \
    aN1 = mfma16(ah3, bq[2][3], aN1);                                          \
    float z0 = (aZ0[0] + aZ1[0]) + (aZ0[1] + aZ1[1]);                          \
    float z1 = (aZ0[2] + aZ1[2]) + (aZ0[3] + aZ1[3]);                          \
    float zg = sigm(pz + plsel(z0, z1));                                       \
    float n0 = (aN0[0] + aN1[0]) + (aN0[1] + aN1[1]);                          \
    float n1 = (aN0[2] + aN1[2]) + (aN0[3] + aN1[3]);                          \
    float ng = tanh_f(pn + rg * (plsel(n0, n1) + bh_n));                       \
    hf = __builtin_fmaf(zg, hf - ng, ng);                                      \
    unsigned hp32 = cvt_pk_bf16(hf, hf);                                       \
    float rem = hf - __uint_as_float(hp32 << 16);                              \
    unsigned lp32 = cvt_pk_bf16(rem, rem);                                     \
    unsigned short hi = (unsigned short)hp32;                                  \
    unsigned short lo = (unsigned short)lp32;                                  \
    hnxt_[(2 * b) * 136 + d] = hi;                                             \
    hnxt_[(2 * b + 1) * 136 + d] = lo;                                         \
    *outf_p = hf; *outhi_p = hi; *outlo_p = lo;                                \
    outf_p += ost; outhi_p += ost; outlo_p += ost;                             \
    if (agghi_p) { *agghi_p = hi; *agglo_p = lo; agghi_p += ast; agglo_p += ast; } \
    BAR_LGKM();                                                                \
  }

__global__ __launch_bounds__(512) void k_gru(RecArgs ra) {
  int u = blockIdx.x;
  __shared__ __align__(16) unsigned short hs[2][16 * 136];
  int tid = threadIdx.x, lane = tid & 63, w8 = tid >> 6;
  int quad = lane >> 4, l16 = lane & 15;
  for (int i = tid; i < 2 * 16 * 136; i += 512) ((unsigned short*)hs)[i] = 0;
  const unsigned short* whh = ra.whh[u];
  s16x8 bq[3][4];
  #pragma unroll
  for (int g = 0; g < 3; ++g) {
    int row = g * 128 + w8 * 16 + l16;
    #pragma unroll
    for (int kc = 0; kc < 4; ++kc)
      bq[g][kc] = ldfrag(whh + (size_t)row * H + kc * 32 + quad * 8);
  }
  const float* bhh = ra.bhh[u];
  const float* pre = ra.pre[u];
  int colOff = ra.colOff[u], dir = ra.dir[u];
  int b = ((quad & 1) << 1) | (quad >> 1);
  int d = w8 * 16 + l16;
  float bh_r = bhh[d], bh_z = bhh[d + 128], bh_n = bhh[d + 256];
  float hf = 0.f;
  int t0 = dir ? (T - 1) : 0;
  long pst = dir ? -(long)H3 : (long)H3;
  long pst2 = 2 * pst;
  long ost = dir ? -(long)H2 : (long)H2;
  long ast = dir ? -(long)H12 : (long)H12;
  size_t o0 = (size_t)(b * T + t0) * H2 + colOff + d;
  size_t a0 = (size_t)(b * T + t0) * H12 + colOff + d;
  float* outf_p = ra.outf[u] + o0;
  unsigned short* outhi_p = ra.outhi[u] + o0;
  unsigned short* outlo_p = ra.outlo[u] + o0;
  unsigned short* agghi_p = ra.agghi[u] ? ra.agghi[u] + a0 : nullptr;
  unsigned short* agglo_p = ra.agglo[u] ? ra.agglo[u] + a0 : nullptr;
  const float* pqE = pre + (size_t)(b * T + t0) * H3 + d;
  const float* pqO = pqE + pst;
  float e_pr = pqE[0] + bh_r, e_pz = pqE[128] + bh_z, e_pn = pqE[256];
  float o_pr = pqO[0] + bh_r, o_pz = pqO[128] + bh_z, o_pn = pqO[256];
  __syncthreads();
  for (int s = 0; s < T; s += 2) {
    GRU_STEP(e_pr, e_pz, e_pn, pqE, hs[0], hs[1]);
    GRU_STEP(o_pr, o_pz, o_pn, pqO, hs[1], hs[0]);
  }
}

// ---------------- fused: projection GEMMs (y<6) + merged MFMA scores (y>=6) ---
// 512-thread blocks. y<6: 2 m-tiles per block (xx<32). y=6/7: one block per
// (bi,type) stages the FULL 128-row W⊙h into 64KB LDS, reads X[b] ONCE,
// acc[2][8] accumulators, writes FINAL scores (no kh partials).

struct ScMMArgs {
  const unsigned short* Xhi[2];
  const float* Rf; const float* Wt[2]; const float* vt[2];
  float* So[2];
};
struct FuseArgs { GemmDesc d[6]; ScMMArgs sm; };

__global__ __launch_bounds__(512, 2) void k_fuse(FuseArgs fa) {
  __shared__ __align__(16) unsigned short w_lds[128 * 256];   // 64KB
  int y = blockIdx.y;
  int tid = threadIdx.x;
  if (y < 6) {
    int xx = blockIdx.x;
    if (xx >= 32) return;
    GemmDesc g = fa.d[y];
    int nb = (xx >> 3) * 64;
    if (nb >= g.N) return;
    int mb = (xx & 7) * 128 + (tid >> 8) * 64;
    gemm_body(g, mb, nb, tid & 255);
    return;
  }
  const ScMMArgs& a = fa.sm;
  int type = y - 6;
  int bi = blockIdx.x, b = bi >> 8;
  const unsigned short* Xhi = a.Xhi[type];
  const float* W = a.Wt[type];
  const float* v = a.vt[type];
  float* Sout = a.So[type];
  int lane = tid & 63, w = tid >> 6, quad = lane >> 4, l16 = lane & 15;
  int d4 = tid & 63, rhi = tid >> 6;
  float4 h4 = ((const float4*)(a.Rf + (size_t)bi * 256))[d4];
  #pragma unroll
  for (int it = 0; it < 16; ++it) {
    int kl = it * 8 + rhi;                            // row 0..127
    float4 w4 = ((const float4*)(W + (size_t)kl * 256))[d4];
    unsigned lo32 = cvt_pk_bf16(w4.x * h4.x, w4.y * h4.y);
    unsigned hi32 = cvt_pk_bf16(w4.z * h4.z, w4.w * h4.w);
    unsigned long long pk = (unsigned long long)lo32 | ((unsigned long long)hi32 << 32);
    int gphys = ((d4 >> 1) + kl) & 31;
    *(unsigned long long*)(w_lds + (size_t)kl * 256 + gphys * 8 + (d4 & 1) * 4) = pk;
  }
  BAR_LGKM();
  f32x4 acc[2][8];
  #pragma unroll
  for (int jj = 0; jj < 2; ++jj)
    #pragma unroll
    for (int c = 0; c < 8; ++c) acc[jj][c] = f32x4{0.f, 0.f, 0.f, 0.f};
  const unsigned short* Xp0 =
      Xhi + (size_t)(b * 256 + w * 2 * 16 + l16) * 256 + quad * 8;
  #pragma unroll 2
  for (int kc = 0; kc < 8; ++kc) {
    s16x8 bf0 = ldfrag(Xp0 + kc * 32);
    s16x8 bf1 = ldfrag(Xp0 + (size_t)16 * 256 + kc * 32);
    #pragma unroll
    for (int c = 0; c < 8; ++c) {
      int krow = c * 16 + l16;
      int gp = (kc * 4 + quad + krow) & 31;
      s16x8 af = ldfrag(w_lds + (size_t)krow * 256 + gp * 8);
      acc[0][c] = mfma16(af, bf0, acc[0][c]);
      acc[1][c] = mfma16(af, bf1, acc[1][c]);
    }
  }
  #pragma unroll
  for (int jj = 0; jj < 2; ++jj) {
    float s = 0.f;
    #pragma unroll
    for (int c = 0; c < 8; ++c)
      #pragma unroll
      for (int r = 0; r < 4; ++r)
        s += tanh_f(acc[jj][c][r]) * v[c * 16 + quad * 4 + r];
    s += __shfl_xor(s, 16);
    s += __shfl_xor(s, 32);
    int jt = w * 2 + jj;
    if (lane < 16) Sout[(size_t)bi * 256 + jt * 16 + l16] = s;
  }
}

// ---------------- scores cmb path (grid 256, 4 i-rows/block) ------------------

struct ScCmbArgs {
  const float *Hc, *Rc, *Hm, *Rm, *HB, *hrf, *vcf, *vmf; float* S;
};

__global__ __launch_bounds__(256, 2) void k_sccmb(ScCmbArgs a) {
  int bi = blockIdx.x;
  int tid = threadIdx.x;
  __shared__ float rc_l[4 * 128];
  __shared__ float rm_l[4 * 128];
  __shared__ float hr_l[4 * 256];
  __shared__ float vc_l[128], vm_l[128];
  int b = bi >> 6, i0 = (bi & 63) << 2;       // 4 i-rows: gi0..gi0+3
  int gi0 = b * 256 + i0;
  {
    const float4* hr4 = (const float4*)(a.hrf + (size_t)gi0 * 256);
    ((float4*)hr_l)[tid] = hr4[tid];
    if (tid < 128) {
      const float4* rc4 = (const float4*)(a.Rc + (size_t)gi0 * 128);
      const float4* rm4 = (const float4*)(a.Rm + (size_t)gi0 * 128);
      ((float4*)rc_l)[tid] = rc4[tid];
      ((float4*)rm_l)[tid] = rm4[tid];
      vc_l[tid] = a.vcf[tid]; vm_l[tid] = a.vmf[tid];
    }
  }
  __syncthreads();
  int j = tid;
  size_t cb = (size_t)(b * 256 + j);
  float scq[4], smq[4], sbq[4];
  #pragma unroll
  for (int q = 0; q < 4; ++q) { scq[q] = 0.f; smq[q] = 0.f; sbq[q] = 0.f; }
  for (int k = 0; k < 128; ++k) {
    float hc = a.Hc[(size_t)k * M + cb];      // transposed: lane-consecutive
    float hm = a.Hm[(size_t)k * M + cb];
    float vck = vc_l[k], vmk = vm_l[k];
    #pragma unroll
    for (int q = 0; q < 4; ++q) {
      scq[q] += vck * tanh_f(hc + rc_l[q * 128 + k]);
      smq[q] += vmk * tanh_f(hm - rm_l[q * 128 + k]);
    }
  }
  for (int k = 0; k < 256; ++k) {
    float hb = a.HB[(size_t)k * M + cb];      // transposed
    #pragma unroll
    for (int q = 0; q < 4; ++q) sbq[q] += hb * hr_l[q * 256 + k];
  }
  #pragma unroll
  for (int q = 0; q < 4; ++q) {
    size_t o = (size_t)(gi0 + q) * 256 + j;
    a.S[(size_t)STY * 1 + o] = scq[q];
    a.S[(size_t)STY * 3 + o] = sbq[q];
    a.S[(size_t)STY * 4 + o] = smq[q];
  }
}

// ---------------- wsum with inline softmax ----------------

__global__ __launch_bounds__(256) void k_wsum(const float* __restrict__ S,
    const float* __restrict__ hl_f, const float* __restrict__ hr_f,
    unsigned short* __restrict__ ahi, unsigned short* __restrict__ alo) {
  int it = blockIdx.x, type = blockIdx.y, b = blockIdx.z;
  __shared__ float p_l[8][256];
  __shared__ float red[4];
  int tid = threadIdx.x;
  for (int ii = 0; ii < 8; ++ii) {
    size_t idx = ((size_t)(b * 256 + it * 8 + ii)) * 256 + tid;
    float x = S[(size_t)type * STY + idx];
    float m = x;
    for (int dl = 32; dl; dl >>= 1) m = fmaxf(m, __shfl_xor(m, dl));
    if ((tid & 63) == 0) red[tid >> 6] = m;
    __syncthreads();
    m = fmaxf(fmaxf(red[0], red[1]), fmaxf(red[2], red[3]));
    __syncthreads();
    float e = __expf(x - m);
    float sum = e;
    for (int dl = 32; dl; dl >>= 1) sum += __shfl_xor(sum, dl);
    if ((tid & 63) == 0) red[tid >> 6] = sum;
    __syncthreads();
    sum = red[0] + red[1] + red[2] + red[3];
    p_l[ii][tid] = e * rcp_f(sum);
    __syncthreads();
  }
  const float* src = (type == 0 ? hr_f : hl_f) + (size_t)b * 256 * 256;
  float acc[8] = {0.f, 0.f, 0.f, 0.f, 0.f, 0.f, 0.f, 0.f};
  for (int j = 0; j < 256; ++j) {
    float hv = src[(size_t)j * 256 + tid];
    #pragma unroll
    for (int ii = 0; ii < 8; ++ii) acc[ii] += p_l[ii][j] * hv;
  }
  int off = 256 * (1 + type);      // agg: [hr | pts | ptc | ptd | ptb | ptm]
  #pragma unroll
  for (int ii = 0; ii < 8; ++ii) {
    float vv = acc[ii];
    unsigned short hi = f2b(vv);
    size_t o = (size_t)(b * 256 + it * 8 + ii) * H12 + off + tid;
    ahi[o] = hi;
    alo[o] = f2b(vv - b2f(hi));
  }
}

// ---------------- fused tail ----------------

__global__ __launch_bounds__(256) void k_tail(const float* __restrict__ Hp,
    const float* __restrict__ hl_f, const float* __restrict__ vpf,
    const float* __restrict__ Wc2f, const float* __restrict__ Arc,
    const float* __restrict__ ar_f, const float* __restrict__ vcf,
    const float* __restrict__ Wpredf, float* __restrict__ out) {
  int b = blockIdx.x, tid = threadIdx.x;
  __shared__ float vl[128], wl[256], rvec[256], rlcl[128], red[4];
  if (tid < 128) vl[tid] = vpf[tid];
  __syncthreads();
  const float* hp = Hp + (size_t)(b * 256 + tid) * 128;
  float s = 0.f;
  for (int k = 0; k < 128; ++k) s += vl[k] * tanh_f(hp[k]);
  float m = s;
  for (int dl = 32; dl; dl >>= 1) m = fmaxf(m, __shfl_xor(m, dl));
  if ((tid & 63) == 0) red[tid >> 6] = m;
  __syncthreads();
  m = fmaxf(fmaxf(red[0], red[1]), fmaxf(red[2], red[3]));
  __syncthreads();
  float e = __expf(s - m);
  float sum = e;
  for (int dl = 32; dl; dl >>= 1) sum += __shfl_xor(sum, dl);
  if ((tid & 63) == 0) red[tid >> 6] = sum;
  __syncthreads();
  sum = red[0] + red[1] + red[2] + red[3];
  wl[tid] = e * rcp_f(sum);
  __syncthreads();
  float acc = 0.f;
  for (int t = 0; t < 256; ++t) acc += wl[t] * hl_f[(size_t)(b * 256 + t) * 256 + tid];
  rvec[tid] = acc;
  __syncthreads();
  if (tid < 128) {
    float a2 = 0.f;
    const float* wr = Wc2f + (size_t)tid * 256;
    for (int dk = 0; dk < 256; ++dk) a2 += rvec[dk] * wr[dk];
    rlcl[tid] = a2;
    vl[tid] = vcf[tid];
  }
  __syncthreads();
  const float* ap = Arc + (size_t)(b * 256 + tid) * 128;
  float s2 = 0.f;
  for (int k = 0; k < 128; ++k) s2 += vl[k] * (ap[k] + rlcl[k]);
  m = s2;
  for (int dl = 32; dl; dl >>= 1) m = fmaxf(m, __shfl_xor(m, dl));
  if ((tid & 63) == 0) red[tid >> 6] = m;
  __syncthreads();
  m = fmaxf(fmaxf(red[0], red[1]), fmaxf(red[2], red[3]));
  __syncthreads();
  float e2 = __expf(s2 - m);
  float sum2 = e2;
  for (int dl = 32; dl; dl >>= 1) sum2 += __shfl_xor(sum2, dl);
  if ((tid & 63) == 0) red[tid >> 6] = sum2;
  __syncthreads();
  sum2 = red[0] + red[1] + red[2] + red[3];
  wl[tid] = e2 * rcp_f(sum2);
  __syncthreads();
  float acc2 = 0.f;
  for (int t = 0; t < 256; ++t) acc2 += wl[t] * ar_f[(size_t)(b * 256 + t) * 256 + tid];
  rvec[tid] = acc2;
  __syncthreads();
  if (tid < 2) {
    float o = 0.f;
    const float* wp = Wpredf + (size_t)tid * 256;
    for (int dk = 0; dk < 256; ++dk) o += rvec[dk] * wp[dk];
    out[b * 2 + tid] = sigm(o);
  }
}

// ---------------- host ----------------

extern "C" void kernel_launch(void* const* d_in, const int* in_sizes, int n_in,
                              void* d_out, int out_size, void* d_ws, size_t ws_size,
                              hipStream_t stream) {
  (void)in_sizes; (void)n_in; (void)out_size; (void)ws_size;
  const int* inputs = (const int*)d_in[0];
  const float* embed = (const float*)d_in[1];
  const float* lWih = (const float*)d_in[2];
  const float* lWhh = (const float*)d_in[3];
  const float* lbih = (const float*)d_in[4];
  const float* lbhh = (const float*)d_in[5];
  const float* rWih = (const float*)d_in[6];
  const float* rWhh = (const float*)d_in[7];
  const float* rbih = (const float*)d_in[8];
  const float* rbhh = (const float*)d_in[9];
  const float* aWih = (const float*)d_in[10];
  const float* aWhh = (const float*)d_in[11];
  const float* abih = (const float*)d_in[12];
  const float* abhh = (const float*)d_in[13];
  const float* Wc1 = (const float*)d_in[14];
  const float* Wc2 = (const float*)d_in[15];
  const float* vc  = (const float*)d_in[16];
  const float* Wb  = (const float*)d_in[17];
  const float* Wd  = (const float*)d_in[18];
  const float* vd  = (const float*)d_in[19];
  const float* Wm  = (const float*)d_in[20];
  const float* vmv = (const float*)d_in[21];
  const float* Wsw = (const float*)d_in[22];
  const float* vsv = (const float*)d_in[23];
  const float* Wp  = (const float*)d_in[24];
  const float* vp  = (const float*)d_in[25];
  const float* Wpred = (const float*)d_in[26];

  char* ws = (char*)d_ws;
  size_t off = 0;
  auto alloc = [&](size_t bytes) -> void* {
    void* p = ws + off;
    off += (bytes + 255) & ~(size_t)255;
    return p;
  };
  unsigned short* xhi = (unsigned short*)alloc((size_t)M * EP * 2);
  unsigned short* xlo = (unsigned short*)alloc((size_t)M * EP * 2);
  unsigned short* wpad = (unsigned short*)alloc((size_t)4 * H3 * EP * 2);
  unsigned short* Whh_b = (unsigned short*)alloc((size_t)6 * H3 * H * 2);
  unsigned short* aWih_b = (unsigned short*)alloc((size_t)2 * H3 * H12 * 2);
  unsigned short* Wc1_b = (unsigned short*)alloc((size_t)H * H2 * 2);
  unsigned short* Wc2_b = (unsigned short*)alloc((size_t)H * H2 * 2);
  unsigned short* Wm_b  = (unsigned short*)alloc((size_t)H * H2 * 2);
  unsigned short* Wp_b  = (unsigned short*)alloc((size_t)H * H2 * 2);
  unsigned short* Wb_b  = (unsigned short*)alloc((size_t)H2 * H2 * 2);
  char* region1 = (char*)alloc((size_t)4 * M * H3 * 4);
  float* pre_lr = (float*)region1;
  float* S      = (float*)region1;
  float* pre_a  = (float*)region1;
  float* hl_f = (float*)alloc((size_t)M * H2 * 4);
  float* hr_f = (float*)alloc((size_t)M * H2 * 4);
  unsigned short* hl_hi = (unsigned short*)alloc((size_t)M * H2 * 2);
  unsigned short* hl_lo = (unsigned short*)alloc((size_t)M * H2 * 2);
  unsigned short* hr_hi = (unsigned short*)alloc((size_t)M * H2 * 2);
  unsigned short* hr_lo = (unsigned short*)alloc((size_t)M * H2 * 2);
  float* Hc = (float*)alloc((size_t)M * H * 4);     // transposed [H][M]
  float* Rc = (float*)alloc((size_t)M * H * 4);
  float* Hm = (float*)alloc((size_t)M * H * 4);     // transposed [H][M]
  float* Rm = (float*)alloc((size_t)M * H * 4);
  float* Hp = (float*)alloc((size_t)M * H * 4);
  float* HB = (float*)alloc((size_t)M * H2 * 4);    // transposed [H2][M]
  unsigned short* agg_hi = (unsigned short*)alloc((size_t)M * H12 * 2);
  unsigned short* agg_lo = (unsigned short*)alloc((size_t)M * H12 * 2);
  float* ar_f = (float*)alloc((size_t)M * H2 * 4);
  unsigned short* ar_hi = (unsigned short*)alloc((size_t)M * H2 * 2);
  unsigned short* ar_lo = (unsigned short*)alloc((size_t)M * H2 * 2);
  float* Arc = (float*)alloc((size_t)M * H * 4);

  // 1. staging (flattened grid)
  StageArgs sa{};
  sa.cs[0] = lWhh;  sa.cd[0] = Whh_b;                 sa.cn[0] = 2 * H3 * H;
  sa.cs[1] = rWhh;  sa.cd[1] = Whh_b + 2 * H3 * H;    sa.cn[1] = 2 * H3 * H;
  sa.cs[2] = aWhh;  sa.cd[2] = Whh_b + 4 * H3 * H;    sa.cn[2] = 2 * H3 * H;
  sa.cs[3] = aWih;  sa.cd[3] = aWih_b;                sa.cn[3] = 2 * H3 * H12;
  sa.cs[4] = Wc1;   sa.cd[4] = Wc1_b;                 sa.cn[4] = H * H2;
  sa.cs[5] = Wc2;   sa.cd[5] = Wc2_b;                 sa.cn[5] = H * H2;
  sa.cs[6] = Wm;    sa.cd[6] = Wm_b;                  sa.cn[6] = H * H2;
  sa.cs[7] = Wp;    sa.cd[7] = Wp_b;                  sa.cn[7] = H * H2;
  sa.cs[8] = Wb;    sa.cd[8] = Wb_b;                  sa.cn[8] = H2 * H2;
  sa.idx = inputs; sa.emb = embed; sa.xhi = xhi; sa.xlo = xlo;
  sa.lW = lWih; sa.rW = rWih; sa.wpad = wpad;
  {
    int acc0 = 0;
    sa.bo[0] = 0;
    for (int s = 0; s < 9; ++s) { acc0 += (sa.cn[s] + 255) / 256; sa.bo[s + 1] = acc0; }
    acc0 += (M * EP + 255) / 256;       sa.bo[10] = acc0;
    acc0 += (4 * H3 * EP + 255) / 256;  sa.bo[11] = acc0;
  }
  k_stage<<<dim3(sa.bo[11]), dim3(256), 0, stream>>>(sa);

  // 2. input projections for l/r GRUs
  GemmBatch ga{};
  const float* biases[4] = { lbih, lbih + H3, rbih, rbih + H3 };
  for (int u = 0; u < 4; ++u)
    ga.d[u] = GemmDesc{ xhi, xlo, wpad + (size_t)u * H3 * EP, biases[u],
                        pre_lr + (size_t)u * M * H3, H3, EP, 0 };
  k_gemm<<<dim3(16, 6, 4), dim3(256), 0, stream>>>(ga);

  // 3. l/r recurrences (writes fp32 + hi/lo + agg hr-copy); 1 unit per block
  RecArgs r1{};
  r1.whh[0] = Whh_b;               r1.whh[1] = Whh_b + H3 * H;
  r1.whh[2] = Whh_b + 2 * H3 * H;  r1.whh[3] = Whh_b + 3 * H3 * H;
  for (int u = 0; u < 4; ++u) r1.pre[u] = pre_lr + (size_t)u * M * H3;
  r1.outf[0] = r1.outf[1] = hl_f; r1.outf[2] = r1.outf[3] = hr_f;
  r1.outhi[0] = r1.outhi[1] = hl_hi; r1.outhi[2] = r1.outhi[3] = hr_hi;
  r1.outlo[0] = r1.outlo[1] = hl_lo; r1.outlo[2] = r1.outlo[3] = hr_lo;
  r1.agghi[0] = r1.agghi[1] = nullptr; r1.agghi[2] = r1.agghi[3] = agg_hi;
  r1.agglo[0] = r1.agglo[1] = nullptr; r1.agglo[2] = r1.agglo[3] = agg_lo;
  r1.bhh[0] = lbhh; r1.bhh[1] = lbhh + H3; r1.bhh[2] = rbhh; r1.bhh[3] = rbhh + H3;
  r1.colOff[0] = 0; r1.colOff[1] = H; r1.colOff[2] = 0; r1.colOff[3] = H;
  r1.dir[0] = 0; r1.dir[1] = 1; r1.dir[2] = 0; r1.dir[3] = 1;
  k_gru<<<dim3(4), dim3(512), 0, stream>>>(r1);

  // 4+5a. fused projection GEMMs + merged MFMA scores
  FuseArgs fu{};
  fu.d[0] = GemmDesc{ hl_hi, hl_lo, Wc1_b, nullptr, Hc, H, H2, 1 };
  fu.d[1] = GemmDesc{ hr_hi, hr_lo, Wc2_b, nullptr, Rc, H, H2, 0 };
  fu.d[2] = GemmDesc{ hl_hi, hl_lo, Wm_b, nullptr, Hm, H, H2, 1 };
  fu.d[3] = GemmDesc{ hr_hi, hr_lo, Wm_b, nullptr, Rm, H, H2, 0 };
  fu.d[4] = GemmDesc{ hl_hi, hl_lo, Wb_b, nullptr, HB, H2, H2, 1 };
  fu.d[5] = GemmDesc{ hl_hi, hl_lo, Wp_b, nullptr, Hp, H, H2, 0 };
  fu.sm.Xhi[0] = hl_hi; fu.sm.Wt[0] = Wd;  fu.sm.vt[0] = vd;
  fu.sm.So[0] = S + (size_t)2 * STY;      // ptd
  fu.sm.Xhi[1] = hr_hi; fu.sm.Wt[1] = Wsw; fu.sm.vt[1] = vsv;
  fu.sm.So[1] = S + (size_t)0 * STY;      // pts
  fu.sm.Rf = hr_f;
  k_fuse<<<dim3(M, 8), dim3(512), 0, stream>>>(fu);

  // 5b. combined ptc/ptb/ptm scores (4 i-rows/block)
  ScCmbArgs scb{};
  scb.Hc = Hc; scb.Rc = Rc; scb.Hm = Hm; scb.Rm = Rm; scb.HB = HB;
  scb.hrf = hr_f; scb.vcf = vc; scb.vmf = vmv; scb.S = S;
  k_sccmb<<<dim3(256), dim3(256), 0, stream>>>(scb);

  // 6. softmax + weighted sums into agg
  k_wsum<<<dim3(32, 5, 4), dim3(256), 0, stream>>>(S, hl_f, hr_f, agg_hi, agg_lo);

  // 7. agg GRU input projection
  GemmBatch gc{};
  gc.d[0] = GemmDesc{ agg_hi, agg_lo, aWih_b, abih, pre_a, H3, H12, 0 };
  gc.d[1] = GemmDesc{ agg_hi, agg_lo, aWih_b + (size_t)H3 * H12, abih + H3,
                      pre_a + (size_t)M * H3, H3, H12, 0 };
  k_gemm<<<dim3(16, 6, 2), dim3(256), 0, stream>>>(gc);

  // 8. agg recurrence (writes ar fp32 + hi/lo); 1 unit per block
  RecArgs r2{};
  r2.whh[0] = Whh_b + 4 * H3 * H; r2.whh[1] = Whh_b + 5 * H3 * H;
  r2.whh[2] = r2.whh[3] = Whh_b + 4 * H3 * H;
  r2.pre[0] = pre_a; r2.pre[1] = pre_a + (size_t)M * H3;
  r2.pre[2] = r2.pre[3] = pre_a;
  r2.outf[0] = r2.outf[1] = r2.outf[2] = r2.outf[3] = ar_f;
  r2.outhi[0] = r2.outhi[1] = r2.outhi[2] = r2.outhi[3] = ar_hi;
  r2.outlo[0] = r2.outlo[1] = r2.outlo[2] = r2.outlo[3] = ar_lo;
  for (int u = 0; u < 4; ++u) { r2.agghi[u] = nullptr; r2.agglo[u] = nullptr; }
  r2.bhh[0] = abhh; r2.bhh[1] = abhh + H3; r2.bhh[2] = r2.bhh[3] = abhh;
  r2.colOff[0] = 0; r2.colOff[1] = H; r2.colOff[2] = r2.colOff[3] = 0;
  r2.dir[0] = 0; r2.dir[1] = 1; r2.dir[2] = r2.dir[3] = 0;
  k_gru<<<dim3(2), dim3(512), 0, stream>>>(r2);

  // 9. Arc GEMM
  GemmBatch gd{};
  gd.d[0] = GemmDesc{ ar_hi, ar_lo, Wc1_b, nullptr, Arc, H, H2, 0 };
  k_gemm<<<dim3(16, 2, 1), dim3(256), 0, stream>>>(gd);

  // 10. fused tail
  k_tail<<<dim3(4), dim3(256), 0, stream>>>(Hp, hl_f, vp, Wc2, Arc, ar_f, vc, Wpred,
                                            (float*)d_out);
}

// Round 13
// 628.103 us; speedup vs baseline: 1.1121x; 1.0490x over previous
//
#include <hip/hip_runtime.h>

// MANNet forward, MI355X gfx950. Inputs fp32 (+int32 ids), output fp32.
// R22: dependency-clean overlap merges (bit-exact; no arithmetic changed).
// (1) Weight cvts not needed until k_fuse/gc (aWih,Wc1,Wc2,Wm,Wp,Wb) moved out
//     of k_stage into r1's dispatch as 2688 extra blocks — they run inside
//     r1's 125us idle shadow (4 gru blocks use <2% of the GPU).
// (2) wsum types 0/2 (read k_fuse's S slots, not sccmb's) merged into the
//     sccmb dispatch as 256 extra blocks; k_wsum keeps types {1,3,4}.
// (3) tail phase A (softmax(tanh(Hp)vp)@hl_f@Wc2 -> rlcl) depends only on
//     fuse/r1 outputs — runs as 4 extra blocks in r2's dispatch; k_tail keeps
//     only the ar-dependent half.

#define DEV static __device__ __forceinline__
#define BAR_LGKM() __asm__ volatile("s_waitcnt lgkmcnt(0)\ns_barrier" ::: "memory")

typedef __attribute__((ext_vector_type(4))) float f32x4;
typedef __attribute__((ext_vector_type(8))) short s16x8;
typedef __attribute__((ext_vector_type(4))) unsigned int u32x4;
typedef __attribute__((ext_vector_type(2))) unsigned int u32x2;

constexpr int T = 256, E = 300, EP = 320, H = 128, H2 = 256, H3 = 384, H12 = 1536;
constexpr int M = 1024;            // B*T
constexpr int STY = 262144;        // 4*T*T elements per score type

DEV float b2f(unsigned short h) { return __uint_as_float(((unsigned)h) << 16); }
DEV unsigned short f2b(float f) {
  unsigned u = __float_as_uint(f);
  u += 0x7fff + ((u >> 16) & 1);            // RNE
  return (unsigned short)(u >> 16);
}
DEV unsigned cvt_pk_bf16(float lo, float hi) {   // dst = {bf16(lo), bf16(hi)} RNE
  unsigned r;
  __asm__("v_cvt_pk_bf16_f32 %0, %1, %2" : "=v"(r) : "v"(lo), "v"(hi));
  return r;
}
DEV float rcp_f(float x) {                       // v_rcp_f32: 1 ulp, 1 trans op
  float r;
  __asm__("v_rcp_f32 %0, %1" : "=v"(r) : "v"(x));
  return r;
}
DEV float sigm(float x) { return rcp_f(1.f + __expf(-x)); }
DEV float tanh_f(float x) {
  float e = __expf(2.f * x);
  return __builtin_fmaf(-2.f, rcp_f(e + 1.f), 1.f);
}
// lanes 0-31 <- x0, lanes 32-63 <- x1's lanes 0-31 (one v_permlane32_swap_b32)
DEV float plsel(float x0, float x1) {
  u32x2 r = __builtin_amdgcn_permlane32_swap(
      __float_as_uint(x0), __float_as_uint(x1), false, false);
  return __uint_as_float(r[0]);
}

DEV s16x8 ldfrag(const unsigned short* p) {
  u32x4 v = *(const u32x4*)p;
  return __builtin_bit_cast(s16x8, v);
}
DEV f32x4 mfma16(s16x8 a, s16x8 b, f32x4 c) {
  return __builtin_amdgcn_mfma_f32_16x16x32_bf16(a, b, c, 0, 0, 0);
}

// ---------------- staging (slim): 3x Whh cvt + embed + padw ----------------

struct StageArgs {
  const float* cs[3]; unsigned short* cd[3]; int cn[3];
  const int* idx; const float* emb; unsigned short* xhi; unsigned short* xlo;
  const float* lW; const float* rW; unsigned short* wpad;
  int bo[6];                       // segs 0-2 cvt, 3 embed, 4 wpad; bo[5]=total
};

__global__ void k_stage(StageArgs sa) {
  int blk = blockIdx.x;
  int seg = 0;
  #pragma unroll
  for (int s2 = 1; s2 < 5; ++s2) seg = (blk >= sa.bo[s2]) ? s2 : seg;
  int i = (blk - sa.bo[seg]) * 256 + threadIdx.x;
  if (seg < 3) {
    if (i < sa.cn[seg]) sa.cd[seg][i] = f2b(sa.cs[seg][i]);
    return;
  }
  if (seg == 3) {
    if (i >= M * EP) return;
    int m = i / EP, e = i - m * EP;
    int r = sa.idx[m];
    float v = (e < E) ? sa.emb[(size_t)r * E + e] : 0.f;
    unsigned short hi = f2b(v);
    sa.xhi[i] = hi;
    sa.xlo[i] = f2b(v - b2f(hi));
    return;
  }
  if (i >= 4 * H3 * EP) return;
  int e = i % EP, n = (i / EP) % H3, uu = i / (EP * H3);
  const float* src = (uu < 2 ? sa.lW : sa.rW) + (size_t)((uu & 1) * H3 + n) * E;
  sa.wpad[i] = (e < E) ? f2b(src[e]) : (unsigned short)0;
}

// ---------------- generic GEMM: C = (Ahi+Alo) @ W^T (+bias), fp32 out ----------
// tr=1: write transposed C_t[n*M + m] (for j-streamed consumers).

struct GemmDesc {
  const unsigned short* Ahi; const unsigned short* Alo; const unsigned short* W;
  const float* bias; float* Cf; int N; int K; int tr;
};
struct GemmBatch { GemmDesc d[8]; };

DEV void gemm_body(const GemmDesc& g, int mb, int nb, int tid) {
  int lane = tid & 63, w = tid >> 6, quad = lane >> 4, l16 = lane & 15;
  int K = g.K;
  const unsigned short* Ahp = g.Ahi + (size_t)(mb + w * 16 + l16) * K + quad * 8;
  const unsigned short* Alp = g.Alo + (size_t)(mb + w * 16 + l16) * K + quad * 8;
  const unsigned short* Wp = g.W + (size_t)(nb + l16) * K + quad * 8;
  f32x4 acc[4];
  #pragma unroll
  for (int nt = 0; nt < 4; ++nt) acc[nt] = f32x4{0.f, 0.f, 0.f, 0.f};
  for (int k = 0; k < K; k += 32) {
    s16x8 ah = ldfrag(Ahp + k);
    s16x8 al = ldfrag(Alp + k);
    #pragma unroll
    for (int nt = 0; nt < 4; ++nt) {
      s16x8 b = ldfrag(Wp + (size_t)nt * 16 * K + k);
      acc[nt] = mfma16(ah, b, acc[nt]);
      acc[nt] = mfma16(al, b, acc[nt]);
    }
  }
  int mr0 = mb + w * 16 + quad * 4;
  #pragma unroll
  for (int nt = 0; nt < 4; ++nt) {
    int col = nb + nt * 16 + l16;
    float bv = g.bias ? g.bias[col] : 0.f;
    #pragma unroll
    for (int r = 0; r < 4; ++r) {
      if (g.tr)
        g.Cf[(size_t)col * M + (mr0 + r)] = acc[nt][r] + bv;
      else
        g.Cf[(size_t)(mr0 + r) * g.N + col] = acc[nt][r] + bv;
    }
  }
}

__global__ __launch_bounds__(256) void k_gemm(GemmBatch gb) {
  GemmDesc g = gb.d[blockIdx.z];
  int nb = blockIdx.y * 64;
  if (nb >= g.N) return;
  gemm_body(g, blockIdx.x * 64, nb, threadIdx.x);
}

// ---------------- GRU recurrence v10 + piggyback blocks ----------------
// blocks [0,nGru): GRU units. For r1 (rlcl==null): blocks >= nGru are weight
// cvt blocks (segs in ccs/ccd/ccn, offsets cbo). For r2 (rlcl!=null): blocks
// [nGru, nGru+4) run tail phase A (rlcl[b][128] = (softmax(tanh(Hp)vp)@hl)@Wc2).

struct RecArgs {
  const unsigned short* whh[4];
  const float* pre[4];
  float* outf[4];
  unsigned short* outhi[4];
  unsigned short* outlo[4];
  unsigned short* agghi[4];      // null -> no agg copy
  unsigned short* agglo[4];
  const float* bhh[4];
  int colOff[4];
  int dir[4];
  int nGru;
  const float* ccs[6]; unsigned short* ccd[6]; int ccn[6]; int cbo[7];
  const float *Hp, *hlf, *vpf, *Wc2f; float* rlcl;   // rlcl!=null -> tailA mode
};

#define GRU_STEP(pr_, pz_, pn_, pq_, hcur_, hnxt_)                             \
  {                                                                            \
    float pr = pr_, pz = pz_, pn = pn_;                                        \
    pq_ += pst2;                                                               \
    pr_ = pq_[0] + bh_r; pz_ = pq_[128] + bh_z; pn_ = pq_[256];                \
    const unsigned short* hb_ = hcur_ + l16 * 136 + quad * 8;                  \
    s16x8 ah0 = ldfrag(hb_);                                                   \
    s16x8 ah1 = ldfrag(hb_ + 32);                                              \
    s16x8 ah2 = ldfrag(hb_ + 64);                                              \
    s16x8 ah3 = ldfrag(hb_ + 96);                                              \
    f32x4 z4 = f32x4{0.f, 0.f, 0.f, 0.f};                                      \
    f32x4 aR0 = mfma16(ah0, bq[0][0], z4);                                     \
    f32x4 aR1 = mfma16(ah2, bq[0][2], z4);                                     \
    aR0 = mfma16(ah1, bq[0][1], aR0);                                          \
    aR1 = mfma16(ah3, bq[0][3], aR1);                                          \
    f32x4 aZ0 = mfma16(ah0, bq[1][0], z4);                                     \
    f32x4 aZ1 = mfma16(ah2, bq[1][2], z4);                                     \
    aZ0 = mfma16(ah1, bq[1][1], aZ0);                                          \
    aZ1 = mfma16(ah3, bq[1][3], aZ1);                                          \
    float r0 = (aR0[0] + aR1[0]) + (aR0[1] + aR1[1]);                          \
    float r1v = (aR0[2] + aR1[2]) + (aR0[3] + aR1[3]);                         \
    float rg = sigm(pr + plsel(r0, r1v));                                      \
    f32x4 aN0 = mfma16(ah0, bq[2][0], z4);                                     \
    f32x4 aN1 = mfma16(ah2, bq[2][2], z4);                                     \
    aN0 = mfma16(ah1, bq[2][1], aN0);                                          \
    aN1 = mfma16(ah3, bq[2][3], aN1);                                          \
    float z0 = (aZ0[0] + aZ1[0]) + (aZ0[1] + aZ1[1]);                          \
    float z1 = (aZ0[2] + aZ1[2]) + (aZ0[3] + aZ1[3]);                          \
    float zg = sigm(pz + plsel(z0, z1));                                       \
    float n0 = (aN0[0] + aN1[0]) + (aN0[1] + aN1[1]);                          \
    float n1 = (aN0[2] + aN1[2]) + (aN0[3] + aN1[3]);                          \
    float ng = tanh_f(pn + rg * (plsel(n0, n1) + bh_n));                       \
    hf = __builtin_fmaf(zg, hf - ng, ng);                                      \
    unsigned hp32 = cvt_pk_bf16(hf, hf);                                       \
    float rem = hf - __uint_as_float(hp32 << 16);                              \
    unsigned lp32 = cvt_pk_bf16(rem, rem);                                     \
    unsigned short hi = (unsigned short)hp32;                                  \
    unsigned short lo = (unsigned short)lp32;                                  \
    hnxt_[(2 * b) * 136 + d] = hi;                                             \
    hnxt_[(2 * b + 1) * 136 + d] = lo;                                         \
    *outf_p = hf; *outhi_p = hi; *outlo_p = lo;                                \
    outf_p += ost; outhi_p += ost; outlo_p += ost;                             \
    if (agghi_p) { *agghi_p = hi; *agglo_p = lo; agghi_p += ast; agglo_p += ast; } \
    BAR_LGKM();                                                                \
  }

__global__ __launch_bounds__(512) void k_gru(RecArgs ra) {
  int blk = blockIdx.x;
  int tid = threadIdx.x;
  if (blk >= ra.nGru) {
    if (ra.rlcl) {                         // ---- tail phase A (r2 piggyback)
      int b = blk - ra.nGru;
      __shared__ float vl[128], wl[256], rvec[256], red[4];
      if (tid < 128) vl[tid] = ra.vpf[tid];
      __syncthreads();
      float s = 0.f, e = 0.f;
      if (tid < 256) {
        const float* hp = ra.Hp + (size_t)(b * 256 + tid) * 128;
        for (int k = 0; k < 128; ++k) s += vl[k] * tanh_f(hp[k]);
        float m = s;
        for (int dl = 32; dl; dl >>= 1) m = fmaxf(m, __shfl_xor(m, dl));
        if ((tid & 63) == 0) red[tid >> 6] = m;
      }
      __syncthreads();
      float m = fmaxf(fmaxf(red[0], red[1]), fmaxf(red[2], red[3]));
      __syncthreads();
      if (tid < 256) {
        e = __expf(s - m);
        float sum = e;
        for (int dl = 32; dl; dl >>= 1) sum += __shfl_xor(sum, dl);
        if ((tid & 63) == 0) red[tid >> 6] = sum;
      }
      __syncthreads();
      float sum = red[0] + red[1] + red[2] + red[3];
      if (tid < 256) wl[tid] = e * rcp_f(sum);
      __syncthreads();
      if (tid < 256) {
        float acc = 0.f;
        for (int t = 0; t < 256; ++t)
          acc += wl[t] * ra.hlf[(size_t)(b * 256 + t) * 256 + tid];
        rvec[tid] = acc;
      }
      __syncthreads();
      if (tid < 128) {
        float a2 = 0.f;
        const float* wr = ra.Wc2f + (size_t)tid * 256;
        for (int dk = 0; dk < 256; ++dk) a2 += rvec[dk] * wr[dk];
        ra.rlcl[b * 128 + tid] = a2;
      }
      return;
    }
    // ---- weight cvt (r1 piggyback)
    int cb = blk - ra.nGru;
    int seg = 0;
    #pragma unroll
    for (int s2 = 1; s2 < 6; ++s2) seg = (cb >= ra.cbo[s2]) ? s2 : seg;
    int i = (cb - ra.cbo[seg]) * 512 + tid;
    if (i < ra.ccn[seg]) ra.ccd[seg][i] = f2b(ra.ccs[seg][i]);
    return;
  }
  int u = blk;
  __shared__ __align__(16) unsigned short hs[2][16 * 136];
  int lane = tid & 63, w8 = tid >> 6;
  int quad = lane >> 4, l16 = lane & 15;
  for (int i = tid; i < 2 * 16 * 136; i += 512) ((unsigned short*)hs)[i] = 0;
  const unsigned short* whh = ra.whh[u];
  s16x8 bq[3][4];
  #pragma unroll
  for (int g = 0; g < 3; ++g) {
    int row = g * 128 + w8 * 16 + l16;
    #pragma unroll
    for (int kc = 0; kc < 4; ++kc)
      bq[g][kc] = ldfrag(whh + (size_t)row * H + kc * 32 + quad * 8);
  }
  const float* bhh = ra.bhh[u];
  const float* pre = ra.pre[u];
  int colOff = ra.colOff[u], dir = ra.dir[u];
  int b = ((quad & 1) << 1) | (quad >> 1);
  int d = w8 * 16 + l16;
  float bh_r = bhh[d], bh_z = bhh[d + 128], bh_n = bhh[d + 256];
  float hf = 0.f;
  int t0 = dir ? (T - 1) : 0;
  long pst = dir ? -(long)H3 : (long)H3;
  long pst2 = 2 * pst;
  long ost = dir ? -(long)H2 : (long)H2;
  long ast = dir ? -(long)H12 : (long)H12;
  size_t o0 = (size_t)(b * T + t0) * H2 + colOff + d;
  size_t a0 = (size_t)(b * T + t0) * H12 + colOff + d;
  float* outf_p = ra.outf[u] + o0;
  unsigned short* outhi_p = ra.outhi[u] + o0;
  unsigned short* outlo_p = ra.outlo[u] + o0;
  unsigned short* agghi_p = ra.agghi[u] ? ra.agghi[u] + a0 : nullptr;
  unsigned short* agglo_p = ra.agglo[u] ? ra.agglo[u] + a0 : nullptr;
  const float* pqE = pre + (size_t)(b * T + t0) * H3 + d;
  const float* pqO = pqE + pst;
  float e_pr = pqE[0] + bh_r, e_pz = pqE[128] + bh_z, e_pn = pqE[256];
  float o_pr = pqO[0] + bh_r, o_pz = pqO[128] + bh_z, o_pn = pqO[256];
  __syncthreads();
  for (int s = 0; s < T; s += 2) {
    GRU_STEP(e_pr, e_pz, e_pn, pqE, hs[0], hs[1]);
    GRU_STEP(o_pr, o_pz, o_pn, pqO, hs[1], hs[0]);
  }
}

// ---------------- fused: projection GEMMs (y<6) + merged MFMA scores (y>=6) ---

struct ScMMArgs {
  const unsigned short* Xhi[2];
  const float* Rf; const float* Wt[2]; const float* vt[2];
  float* So[2];
};
struct FuseArgs { GemmDesc d[6]; ScMMArgs sm; };

__global__ __launch_bounds__(512, 2) void k_fuse(FuseArgs fa) {
  __shared__ __align__(16) unsigned short w_lds[128 * 256];   // 64KB
  int y = blockIdx.y;
  int tid = threadIdx.x;
  if (y < 6) {
    int xx = blockIdx.x;
    if (xx >= 32) return;
    GemmDesc g = fa.d[y];
    int nb = (xx >> 3) * 64;
    if (nb >= g.N) return;
    int mb = (xx & 7) * 128 + (tid >> 8) * 64;
    gemm_body(g, mb, nb, tid & 255);
    return;
  }
  const ScMMArgs& a = fa.sm;
  int type = y - 6;
  int bi = blockIdx.x, b = bi >> 8;
  const unsigned short* Xhi = a.Xhi[type];
  const float* W = a.Wt[type];
  const float* v = a.vt[type];
  float* Sout = a.So[type];
  int lane = tid & 63, w = tid >> 6, quad = lane >> 4, l16 = lane & 15;
  int d4 = tid & 63, rhi = tid >> 6;
  float4 h4 = ((const float4*)(a.Rf + (size_t)bi * 256))[d4];
  #pragma unroll
  for (int it = 0; it < 16; ++it) {
    int kl = it * 8 + rhi;                            // row 0..127
    float4 w4 = ((const float4*)(W + (size_t)kl * 256))[d4];
    unsigned lo32 = cvt_pk_bf16(w4.x * h4.x, w4.y * h4.y);
    unsigned hi32 = cvt_pk_bf16(w4.z * h4.z, w4.w * h4.w);
    unsigned long long pk = (unsigned long long)lo32 | ((unsigned long long)hi32 << 32);
    int gphys = ((d4 >> 1) + kl) & 31;
    *(unsigned long long*)(w_lds + (size_t)kl * 256 + gphys * 8 + (d4 & 1) * 4) = pk;
  }
  BAR_LGKM();
  f32x4 acc[2][8];
  #pragma unroll
  for (int jj = 0; jj < 2; ++jj)
    #pragma unroll
    for (int c = 0; c < 8; ++c) acc[jj][c] = f32x4{0.f, 0.f, 0.f, 0.f};
  const unsigned short* Xp0 =
      Xhi + (size_t)(b * 256 + w * 2 * 16 + l16) * 256 + quad * 8;
  #pragma unroll 2
  for (int kc = 0; kc < 8; ++kc) {
    s16x8 bf0 = ldfrag(Xp0 + kc * 32);
    s16x8 bf1 = ldfrag(Xp0 + (size_t)16 * 256 + kc * 32);
    #pragma unroll
    for (int c = 0; c < 8; ++c) {
      int krow = c * 16 + l16;
      int gp = (kc * 4 + quad + krow) & 31;
      s16x8 af = ldfrag(w_lds + (size_t)krow * 256 + gp * 8);
      acc[0][c] = mfma16(af, bf0, acc[0][c]);
      acc[1][c] = mfma16(af, bf1, acc[1][c]);
    }
  }
  #pragma unroll
  for (int jj = 0; jj < 2; ++jj) {
    float s = 0.f;
    #pragma unroll
    for (int c = 0; c < 8; ++c)
      #pragma unroll
      for (int r = 0; r < 4; ++r)
        s += tanh_f(acc[jj][c][r]) * v[c * 16 + quad * 4 + r];
    s += __shfl_xor(s, 16);
    s += __shfl_xor(s, 32);
    int jt = w * 2 + jj;
    if (lane < 16) Sout[(size_t)bi * 256 + jt * 16 + l16] = s;
  }
}

// ---------------- scores cmb (bi<256) + wsum types 0/2 (bi>=256) --------------

struct ScCmbArgs {
  const float *Hc, *Rc, *Hm, *Rm, *HB, *hrf, *vcf, *vmf; float* S;
  const float* hlf;
  unsigned short *ahi, *alo;
};

__global__ __launch_bounds__(256, 2) void k_sccmb(ScCmbArgs a) {
  int bi = blockIdx.x;
  int tid = threadIdx.x;
  if (bi >= 256) {                          // ---- wsum for pts(0)/ptd(2)
    int widx = bi - 256;
    int type = (widx >> 7) * 2;
    int rem = widx & 127;
    int it = rem >> 2, b = rem & 3;
    __shared__ float p_l[8][256];
    __shared__ float red[4];
    for (int ii = 0; ii < 8; ++ii) {
      size_t idx = ((size_t)(b * 256 + it * 8 + ii)) * 256 + tid;
      float x = a.S[(size_t)type * STY + idx];
      float m = x;
      for (int dl = 32; dl; dl >>= 1) m = fmaxf(m, __shfl_xor(m, dl));
      if ((tid & 63) == 0) red[tid >> 6] = m;
      __syncthreads();
      m = fmaxf(fmaxf(red[0], red[1]), fmaxf(red[2], red[3]));
      __syncthreads();
      float e = __expf(x - m);
      float sum = e;
      for (int dl = 32; dl; dl >>= 1) sum += __shfl_xor(sum, dl);
      if ((tid & 63) == 0) red[tid >> 6] = sum;
      __syncthreads();
      sum = red[0] + red[1] + red[2] + red[3];
      p_l[ii][tid] = e * rcp_f(sum);
      __syncthreads();
    }
    const float* src = (type == 0 ? a.hrf : a.hlf) + (size_t)b * 256 * 256;
    float acc[8] = {0.f, 0.f, 0.f, 0.f, 0.f, 0.f, 0.f, 0.f};
    for (int j = 0; j < 256; ++j) {
      float hv = src[(size_t)j * 256 + tid];
      #pragma unroll
      for (int ii = 0; ii < 8; ++ii) acc[ii] += p_l[ii][j] * hv;
    }
    int off = 256 * (1 + type);
    #pragma unroll
    for (int ii = 0; ii < 8; ++ii) {
      float vv = acc[ii];
      unsigned short hi = f2b(vv);
      size_t o = (size_t)(b * 256 + it * 8 + ii) * H12 + off + tid;
      a.ahi[o] = hi;
      a.alo[o] = f2b(vv - b2f(hi));
    }
    return;
  }
  __shared__ float rc_l[4 * 128];
  __shared__ float rm_l[4 * 128];
  __shared__ float hr_l[4 * 256];
  __shared__ float vc_l[128], vm_l[128];
  int b = bi >> 6, i0 = (bi & 63) << 2;       // 4 i-rows: gi0..gi0+3
  int gi0 = b * 256 + i0;
  {
    const float4* hr4 = (const float4*)(a.hrf + (size_t)gi0 * 256);
    ((float4*)hr_l)[tid] = hr4[tid];
    if (tid < 128) {
      const float4* rc4 = (const float4*)(a.Rc + (size_t)gi0 * 128);
      const float4* rm4 = (const float4*)(a.Rm + (size_t)gi0 * 128);
      ((float4*)rc_l)[tid] = rc4[tid];
      ((float4*)rm_l)[tid] = rm4[tid];
      vc_l[tid] = a.vcf[tid]; vm_l[tid] = a.vmf[tid];
    }
  }
  __syncthreads();
  int j = tid;
  size_t cb = (size_t)(b * 256 + j);
  float scq[4], smq[4], sbq[4];
  #pragma unroll
  for (int q = 0; q < 4; ++q) { scq[q] = 0.f; smq[q] = 0.f; sbq[q] = 0.f; }
  for (int k = 0; k < 128; ++k) {
    float hc = a.Hc[(size_t)k * M + cb];      // transposed: lane-consecutive
    float hm = a.Hm[(size_t)k * M + cb];
    float vck = vc_l[k], vmk = vm_l[k];
    #pragma unroll
    for (int q = 0; q < 4; ++q) {
      scq[q] += vck * tanh_f(hc + rc_l[q * 128 + k]);
      smq[q] += vmk * tanh_f(hm - rm_l[q * 128 + k]);
    }
  }
  for (int k = 0; k < 256; ++k) {
    float hb = a.HB[(size_t)k * M + cb];      // transposed
    #pragma unroll
    for (int q = 0; q < 4; ++q) sbq[q] += hb * hr_l[q * 256 + k];
  }
  #pragma unroll
  for (int q = 0; q < 4; ++q) {
    size_t o = (size_t)(gi0 + q) * 256 + j;
    a.S[(size_t)STY * 1 + o] = scq[q];
    a.S[(size_t)STY * 3 + o] = sbq[q];
    a.S[(size_t)STY * 4 + o] = smq[q];
  }
}

// ---------------- wsum types {1,3,4} ----------------

__global__ __launch_bounds__(256) void k_wsum(const float* __restrict__ S,
    const float* __restrict__ hl_f, const float* __restrict__ hr_f,
    unsigned short* __restrict__ ahi, unsigned short* __restrict__ alo) {
  int it = blockIdx.x, b = blockIdx.z;
  int y = blockIdx.y;
  int type = (y == 0) ? 1 : (y + 2);          // {1,3,4}
  __shared__ float p_l[8][256];
  __shared__ float red[4];
  int tid = threadIdx.x;
  for (int ii = 0; ii < 8; ++ii) {
    size_t idx = ((size_t)(b * 256 + it * 8 + ii)) * 256 + tid;
    float x = S[(size_t)type * STY + idx];
    float m = x;
    for (int dl = 32; dl; dl >>= 1) m = fmaxf(m, __shfl_xor(m, dl));
    if ((tid & 63) == 0) red[tid >> 6] = m;
    __syncthreads();
    m = fmaxf(fmaxf(red[0], red[1]), fmaxf(red[2], red[3]));
    __syncthreads();
    float e = __expf(x - m);
    float sum = e;
    for (int dl = 32; dl; dl >>= 1) sum += __shfl_xor(sum, dl);
    if ((tid & 63) == 0) red[tid >> 6] = sum;
    __syncthreads();
    sum = red[0] + red[1] + red[2] + red[3];
    p_l[ii][tid] = e * rcp_f(sum);
    __syncthreads();
  }
  const float* src = hl_f + (size_t)b * 256 * 256;   // types 1,3,4 all use hl
  float acc[8] = {0.f, 0.f, 0.f, 0.f, 0.f, 0.f, 0.f, 0.f};
  for (int j = 0; j < 256; ++j) {
    float hv = src[(size_t)j * 256 + tid];
    #pragma unroll
    for (int ii = 0; ii < 8; ++ii) acc[ii] += p_l[ii][j] * hv;
  }
  int off = 256 * (1 + type);      // agg: [hr | pts | ptc | ptd | ptb | ptm]
  #pragma unroll
  for (int ii = 0; ii < 8; ++ii) {
    float vv = acc[ii];
    unsigned short hi = f2b(vv);
    size_t o = (size_t)(b * 256 + it * 8 + ii) * H12 + off + tid;
    ahi[o] = hi;
    alo[o] = f2b(vv - b2f(hi));
  }
}

// ---------------- tail phase B (rlcl precomputed in r2 dispatch) --------------

__global__ __launch_bounds__(256) void k_tail(const float* __restrict__ rlcl,
    const float* __restrict__ Arc, const float* __restrict__ ar_f,
    const float* __restrict__ vcf, const float* __restrict__ Wpredf,
    float* __restrict__ out) {
  int b = blockIdx.x, tid = threadIdx.x;
  __shared__ float vl[128], wl[256], rvec[256], red[4];
  if (tid < 128) vl[tid] = vcf[tid];
  __syncthreads();
  const float* ap = Arc + (size_t)(b * 256 + tid) * 128;
  const float* rl = rlcl + b * 128;
  float s2 = 0.f;
  for (int k = 0; k < 128; ++k) s2 += vl[k] * (ap[k] + rl[k]);
  float m = s2;
  for (int dl = 32; dl; dl >>= 1) m = fmaxf(m, __shfl_xor(m, dl));
  if ((tid & 63) == 0) red[tid >> 6] = m;
  __syncthreads();
  m = fmaxf(fmaxf(red[0], red[1]), fmaxf(red[2], red[3]));
  __syncthreads();
  float e2 = __expf(s2 - m);
  float sum2 = e2;
  for (int dl = 32; dl; dl >>= 1) sum2 += __shfl_xor(sum2, dl);
  if ((tid & 63) == 0) red[tid >> 6] = sum2;
  __syncthreads();
  sum2 = red[0] + red[1] + red[2] + red[3];
  wl[tid] = e2 * rcp_f(sum2);
  __syncthreads();
  float acc2 = 0.f;
  for (int t = 0; t < 256; ++t) acc2 += wl[t] * ar_f[(size_t)(b * 256 + t) * 256 + tid];
  rvec[tid] = acc2;
  __syncthreads();
  if (tid < 2) {
    float o = 0.f;
    const float* wp = Wpredf + (size_t)tid * 256;
    for (int dk = 0; dk < 256; ++dk) o += rvec[dk] * wp[dk];
    out[b * 2 + tid] = sigm(o);
  }
}

// ---------------- host ----------------

extern "C" void kernel_launch(void* const* d_in, const int* in_sizes, int n_in,
                              void* d_out, int out_size, void* d_ws, size_t ws_size,
                              hipStream_t stream) {
  (void)in_sizes; (void)n_in; (void)out_size; (void)ws_size;
  const int* inputs = (const int*)d_in[0];
  const float* embed = (const float*)d_in[1];
  const float* lWih = (const float*)d_in[2];
  const float* lWhh = (const float*)d_in[3];
  const float* lbih = (const float*)d_in[4];
  const float* lbhh = (const float*)d_in[5];
  const float* rWih = (const float*)d_in[6];
  const float* rWhh = (const float*)d_in[7];
  const float* rbih = (const float*)d_in[8];
  const float* rbhh = (const float*)d_in[9];
  const float* aWih = (const float*)d_in[10];
  const float* aWhh = (const float*)d_in[11];
  const float* abih = (const float*)d_in[12];
  const float* abhh = (const float*)d_in[13];
  const float* Wc1 = (const float*)d_in[14];
  const float* Wc2 = (const float*)d_in[15];
  const float* vc  = (const float*)d_in[16];
  const float* Wb  = (const float*)d_in[17];
  const float* Wd  = (const float*)d_in[18];
  const float* vd  = (const float*)d_in[19];
  const float* Wm  = (const float*)d_in[20];
  const float* vmv = (const float*)d_in[21];
  const float* Wsw = (const float*)d_in[22];
  const float* vsv = (const float*)d_in[23];
  const float* Wp  = (const float*)d_in[24];
  const float* vp  = (const float*)d_in[25];
  const float* Wpred = (const float*)d_in[26];

  char* ws = (char*)d_ws;
  size_t off = 0;
  auto alloc = [&](size_t bytes) -> void* {
    void* p = ws + off;
    off += (bytes + 255) & ~(size_t)255;
    return p;
  };
  unsigned short* xhi = (unsigned short*)alloc((size_t)M * EP * 2);
  unsigned short* xlo = (unsigned short*)alloc((size_t)M * EP * 2);
  unsigned short* wpad = (unsigned short*)alloc((size_t)4 * H3 * EP * 2);
  unsigned short* Whh_b = (unsigned short*)alloc((size_t)6 * H3 * H * 2);
  unsigned short* aWih_b = (unsigned short*)alloc((size_t)2 * H3 * H12 * 2);
  unsigned short* Wc1_b = (unsigned short*)alloc((size_t)H * H2 * 2);
  unsigned short* Wc2_b = (unsigned short*)alloc((size_t)H * H2 * 2);
  unsigned short* Wm_b  = (unsigned short*)alloc((size_t)H * H2 * 2);
  unsigned short* Wp_b  = (unsigned short*)alloc((size_t)H * H2 * 2);
  unsigned short* Wb_b  = (unsigned short*)alloc((size_t)H2 * H2 * 2);
  char* region1 = (char*)alloc((size_t)4 * M * H3 * 4);
  float* pre_lr = (float*)region1;
  float* S      = (float*)region1;
  float* pre_a  = (float*)region1;
  float* hl_f = (float*)alloc((size_t)M * H2 * 4);
  float* hr_f = (float*)alloc((size_t)M * H2 * 4);
  unsigned short* hl_hi = (unsigned short*)alloc((size_t)M * H2 * 2);
  unsigned short* hl_lo = (unsigned short*)alloc((size_t)M * H2 * 2);
  unsigned short* hr_hi = (unsigned short*)alloc((size_t)M * H2 * 2);
  unsigned short* hr_lo = (unsigned short*)alloc((size_t)M * H2 * 2);
  float* Hc = (float*)alloc((size_t)M * H * 4);     // transposed [H][M]
  float* Rc = (float*)alloc((size_t)M * H * 4);
  float* Hm = (float*)alloc((size_t)M * H * 4);     // transposed [H][M]
  float* Rm = (float*)alloc((size_t)M * H * 4);
  float* Hp = (float*)alloc((size_t)M * H * 4);
  float* HB = (float*)alloc((size_t)M * H2 * 4);    // transposed [H2][M]
  unsigned short* agg_hi = (unsigned short*)alloc((size_t)M * H12 * 2);
  unsigned short* agg_lo = (unsigned short*)alloc((size_t)M * H12 * 2);
  float* ar_f = (float*)alloc((size_t)M * H2 * 4);
  unsigned short* ar_hi = (unsigned short*)alloc((size_t)M * H2 * 2);
  unsigned short* ar_lo = (unsigned short*)alloc((size_t)M * H2 * 2);
  float* Arc = (float*)alloc((size_t)M * H * 4);
  float* rlcl = (float*)alloc((size_t)4 * H * 4);

  // 1. staging (slim: Whh cvts + embed + wpad)
  StageArgs sa{};
  sa.cs[0] = lWhh;  sa.cd[0] = Whh_b;                 sa.cn[0] = 2 * H3 * H;
  sa.cs[1] = rWhh;  sa.cd[1] = Whh_b + 2 * H3 * H;    sa.cn[1] = 2 * H3 * H;
  sa.cs[2] = aWhh;  sa.cd[2] = Whh_b + 4 * H3 * H;    sa.cn[2] = 2 * H3 * H;
  sa.idx = inputs; sa.emb = embed; sa.xhi = xhi; sa.xlo = xlo;
  sa.lW = lWih; sa.rW = rWih; sa.wpad = wpad;
  {
    int acc0 = 0;
    sa.bo[0] = 0;
    for (int s = 0; s < 3; ++s) { acc0 += (sa.cn[s] + 255) / 256; sa.bo[s + 1] = acc0; }
    acc0 += (M * EP + 255) / 256;       sa.bo[4] = acc0;
    acc0 += (4 * H3 * EP + 255) / 256;  sa.bo[5] = acc0;
  }
  k_stage<<<dim3(sa.bo[5]), dim3(256), 0, stream>>>(sa);

  // 2. input projections for l/r GRUs
  GemmBatch ga{};
  const float* biases[4] = { lbih, lbih + H3, rbih, rbih + H3 };
  for (int u = 0; u < 4; ++u)
    ga.d[u] = GemmDesc{ xhi, xlo, wpad + (size_t)u * H3 * EP, biases[u],
                        pre_lr + (size_t)u * M * H3, H3, EP, 0 };
  k_gemm<<<dim3(16, 6, 4), dim3(256), 0, stream>>>(ga);

  // 3. l/r recurrences + piggybacked weight cvts (aWih, Wc1, Wc2, Wm, Wp, Wb)
  RecArgs r1{};
  r1.whh[0] = Whh_b;               r1.whh[1] = Whh_b + H3 * H;
  r1.whh[2] = Whh_b + 2 * H3 * H;  r1.whh[3] = Whh_b + 3 * H3 * H;
  for (int u = 0; u < 4; ++u) r1.pre[u] = pre_lr + (size_t)u * M * H3;
  r1.outf[0] = r1.outf[1] = hl_f; r1.outf[2] = r1.outf[3] = hr_f;
  r1.outhi[0] = r1.outhi[1] = hl_hi; r1.outhi[2] = r1.outhi[3] = hr_hi;
  r1.outlo[0] = r1.outlo[1] = hl_lo; r1.outlo[2] = r1.outlo[3] = hr_lo;
  r1.agghi[0] = r1.agghi[1] = nullptr; r1.agghi[2] = r1.agghi[3] = agg_hi;
  r1.agglo[0] = r1.agglo[1] = nullptr; r1.agglo[2] = r1.agglo[3] = agg_lo;
  r1.bhh[0] = lbhh; r1.bhh[1] = lbhh + H3; r1.bhh[2] = rbhh; r1.bhh[3] = rbhh + H3;
  r1.colOff[0] = 0; r1.colOff[1] = H; r1.colOff[2] = 0; r1.colOff[3] = H;
  r1.dir[0] = 0; r1.dir[1] = 1; r1.dir[2] = 0; r1.dir[3] = 1;
  r1.nGru = 4;
  r1.ccs[0] = aWih; r1.ccd[0] = aWih_b; r1.ccn[0] = 2 * H3 * H12;
  r1.ccs[1] = Wc1;  r1.ccd[1] = Wc1_b;  r1.ccn[1] = H * H2;
  r1.ccs[2] = Wc2;  r1.ccd[2] = Wc2_b;  r1.ccn[2] = H * H2;
  r1.ccs[3] = Wm;   r1.ccd[3] = Wm_b;   r1.ccn[3] = H * H2;
  r1.ccs[4] = Wp;   r1.ccd[4] = Wp_b;   r1.ccn[4] = H * H2;
  r1.ccs[5] = Wb;   r1.ccd[5] = Wb_b;   r1.ccn[5] = H2 * H2;
  int cvtBlocks;
  {
    int acc0 = 0;
    r1.cbo[0] = 0;
    for (int s = 0; s < 6; ++s) { acc0 += (r1.ccn[s] + 511) / 512; r1.cbo[s + 1] = acc0; }
    cvtBlocks = acc0;
  }
  r1.Hp = nullptr; r1.hlf = nullptr; r1.vpf = nullptr; r1.Wc2f = nullptr;
  r1.rlcl = nullptr;
  k_gru<<<dim3(4 + cvtBlocks), dim3(512), 0, stream>>>(r1);

  // 4+5a. fused projection GEMMs + merged MFMA scores
  FuseArgs fu{};
  fu.d[0] = GemmDesc{ hl_hi, hl_lo, Wc1_b, nullptr, Hc, H, H2, 1 };
  fu.d[1] = GemmDesc{ hr_hi, hr_lo, Wc2_b, nullptr, Rc, H, H2, 0 };
  fu.d[2] = GemmDesc{ hl_hi, hl_lo, Wm_b, nullptr, Hm, H, H2, 1 };
  fu.d[3] = GemmDesc{ hr_hi, hr_lo, Wm_b, nullptr, Rm, H, H2, 0 };
  fu.d[4] = GemmDesc{ hl_hi, hl_lo, Wb_b, nullptr, HB, H2, H2, 1 };
  fu.d[5] = GemmDesc{ hl_hi, hl_lo, Wp_b, nullptr, Hp, H, H2, 0 };
  fu.sm.Xhi[0] = hl_hi; fu.sm.Wt[0] = Wd;  fu.sm.vt[0] = vd;
  fu.sm.So[0] = S + (size_t)2 * STY;      // ptd
  fu.sm.Xhi[1] = hr_hi; fu.sm.Wt[1] = Wsw; fu.sm.vt[1] = vsv;
  fu.sm.So[1] = S + (size_t)0 * STY;      // pts
  fu.sm.Rf = hr_f;
  k_fuse<<<dim3(M, 8), dim3(512), 0, stream>>>(fu);

  // 5b. combined ptc/ptb/ptm scores + wsum for pts/ptd (fuse outputs)
  ScCmbArgs scb{};
  scb.Hc = Hc; scb.Rc = Rc; scb.Hm = Hm; scb.Rm = Rm; scb.HB = HB;
  scb.hrf = hr_f; scb.vcf = vc; scb.vmf = vmv; scb.S = S;
  scb.hlf = hl_f; scb.ahi = agg_hi; scb.alo = agg_lo;
  k_sccmb<<<dim3(512), dim3(256), 0, stream>>>(scb);

  // 6. softmax + weighted sums for types {1,3,4}
  k_wsum<<<dim3(32, 3, 4), dim3(256), 0, stream>>>(S, hl_f, hr_f, agg_hi, agg_lo);

  // 7. agg GRU input projection
  GemmBatch gc{};
  gc.d[0] = GemmDesc{ agg_hi, agg_lo, aWih_b, abih, pre_a, H3, H12, 0 };
  gc.d[1] = GemmDesc{ agg_hi, agg_lo, aWih_b + (size_t)H3 * H12, abih + H3,
                      pre_a + (size_t)M * H3, H3, H12, 0 };
  k_gemm<<<dim3(16, 6, 2), dim3(256), 0, stream>>>(gc);

  // 8. agg recurrence + piggybacked tail phase A
  RecArgs r2{};
  r2.whh[0] = Whh_b + 4 * H3 * H; r2.whh[1] = Whh_b + 5 * H3 * H;
  r2.whh[2] = r2.whh[3] = Whh_b + 4 * H3 * H;
  r2.pre[0] = pre_a; r2.pre[1] = pre_a + (size_t)M * H3;
  r2.pre[2] = r2.pre[3] = pre_a;
  r2.outf[0] = r2.outf[1] = r2.outf[2] = r2.outf[3] = ar_f;
  r2.outhi[0] = r2.outhi[1] = r2.outhi[2] = r2.outhi[3] = ar_hi;
  r2.outlo[0] = r2.outlo[1] = r2.outlo[2] = r2.outlo[3] = ar_lo;
  for (int u = 0; u < 4; ++u) { r2.agghi[u] = nullptr; r2.agglo[u] = nullptr; }
  r2.bhh[0] = abhh; r2.bhh[1] = abhh + H3; r2.bhh[2] = r2.bhh[3] = abhh;
  r2.colOff[0] = 0; r2.colOff[1] = H; r2.colOff[2] = r2.colOff[3] = 0;
  r2.dir[0] = 0; r2.dir[1] = 1; r2.dir[2] = r2.dir[3] = 0;
  r2.nGru = 2;
  for (int s = 0; s < 6; ++s) { r2.ccs[s] = nullptr; r2.ccd[s] = nullptr; r2.ccn[s] = 0; }
  for (int s = 0; s < 7; ++s) r2.cbo[s] = 0;
  r2.Hp = Hp; r2.hlf = hl_f; r2.vpf = vp; r2.Wc2f = Wc2; r2.rlcl = rlcl;
  k_gru<<<dim3(2 + 4), dim3(512), 0, stream>>>(r2);

  // 9. Arc GEMM
  GemmBatch gd{};
  gd.d[0] = GemmDesc{ ar_hi, ar_lo, Wc1_b, nullptr, Arc, H, H2, 0 };
  k_gemm<<<dim3(16, 2, 1), dim3(256), 0, stream>>>(gd);

  // 10. tail phase B
  k_tail<<<dim3(4), dim3(256), 0, stream>>>(rlcl, Arc, ar_f, vc, Wpred,
                                            (float*)d_out);
}

// Round 14
// 616.466 us; speedup vs baseline: 1.1331x; 1.0189x over previous
//
#include <hip/hip_runtime.h>

// MANNet forward, MI355X gfx950. Inputs fp32 (+int32 ids), output fp32.
// R23: Arc GEMM eliminated algebraically. Tail's s2_j = vc·(Wc1 ar_j + rlcl)
// = (Wc1^T vc)·ar_j + vc·rlcl. u = Wc1^T vc (256-vec) precomputed as one extra
// piggyback block in r2's idle shadow; k_tail dots u with ar_f directly.
// Deletes the gd dispatch + the Arc buffer round-trip. (Math-exact; fp32 order
// changes so absmax ~1e-6 instead of 0.0.)

#define DEV static __device__ __forceinline__
#define BAR_LGKM() __asm__ volatile("s_waitcnt lgkmcnt(0)\ns_barrier" ::: "memory")

typedef __attribute__((ext_vector_type(4))) float f32x4;
typedef __attribute__((ext_vector_type(8))) short s16x8;
typedef __attribute__((ext_vector_type(4))) unsigned int u32x4;
typedef __attribute__((ext_vector_type(2))) unsigned int u32x2;

constexpr int T = 256, E = 300, EP = 320, H = 128, H2 = 256, H3 = 384, H12 = 1536;
constexpr int M = 1024;            // B*T
constexpr int STY = 262144;        // 4*T*T elements per score type

DEV float b2f(unsigned short h) { return __uint_as_float(((unsigned)h) << 16); }
DEV unsigned short f2b(float f) {
  unsigned u = __float_as_uint(f);
  u += 0x7fff + ((u >> 16) & 1);            // RNE
  return (unsigned short)(u >> 16);
}
DEV unsigned cvt_pk_bf16(float lo, float hi) {   // dst = {bf16(lo), bf16(hi)} RNE
  unsigned r;
  __asm__("v_cvt_pk_bf16_f32 %0, %1, %2" : "=v"(r) : "v"(lo), "v"(hi));
  return r;
}
DEV float rcp_f(float x) {                       // v_rcp_f32: 1 ulp, 1 trans op
  float r;
  __asm__("v_rcp_f32 %0, %1" : "=v"(r) : "v"(x));
  return r;
}
DEV float sigm(float x) { return rcp_f(1.f + __expf(-x)); }
DEV float tanh_f(float x) {
  float e = __expf(2.f * x);
  return __builtin_fmaf(-2.f, rcp_f(e + 1.f), 1.f);
}
// lanes 0-31 <- x0, lanes 32-63 <- x1's lanes 0-31 (one v_permlane32_swap_b32)
DEV float plsel(float x0, float x1) {
  u32x2 r = __builtin_amdgcn_permlane32_swap(
      __float_as_uint(x0), __float_as_uint(x1), false, false);
  return __uint_as_float(r[0]);
}

DEV s16x8 ldfrag(const unsigned short* p) {
  u32x4 v = *(const u32x4*)p;
  return __builtin_bit_cast(s16x8, v);
}
DEV f32x4 mfma16(s16x8 a, s16x8 b, f32x4 c) {
  return __builtin_amdgcn_mfma_f32_16x16x32_bf16(a, b, c, 0, 0, 0);
}

// ---------------- staging (slim): 3x Whh cvt + embed + padw ----------------

struct StageArgs {
  const float* cs[3]; unsigned short* cd[3]; int cn[3];
  const int* idx; const float* emb; unsigned short* xhi; unsigned short* xlo;
  const float* lW; const float* rW; unsigned short* wpad;
  int bo[6];                       // segs 0-2 cvt, 3 embed, 4 wpad; bo[5]=total
};

__global__ void k_stage(StageArgs sa) {
  int blk = blockIdx.x;
  int seg = 0;
  #pragma unroll
  for (int s2 = 1; s2 < 5; ++s2) seg = (blk >= sa.bo[s2]) ? s2 : seg;
  int i = (blk - sa.bo[seg]) * 256 + threadIdx.x;
  if (seg < 3) {
    if (i < sa.cn[seg]) sa.cd[seg][i] = f2b(sa.cs[seg][i]);
    return;
  }
  if (seg == 3) {
    if (i >= M * EP) return;
    int m = i / EP, e = i - m * EP;
    int r = sa.idx[m];
    float v = (e < E) ? sa.emb[(size_t)r * E + e] : 0.f;
    unsigned short hi = f2b(v);
    sa.xhi[i] = hi;
    sa.xlo[i] = f2b(v - b2f(hi));
    return;
  }
  if (i >= 4 * H3 * EP) return;
  int e = i % EP, n = (i / EP) % H3, uu = i / (EP * H3);
  const float* src = (uu < 2 ? sa.lW : sa.rW) + (size_t)((uu & 1) * H3 + n) * E;
  sa.wpad[i] = (e < E) ? f2b(src[e]) : (unsigned short)0;
}

// ---------------- generic GEMM: C = (Ahi+Alo) @ W^T (+bias), fp32 out ----------
// tr=1: write transposed C_t[n*M + m] (for j-streamed consumers).

struct GemmDesc {
  const unsigned short* Ahi; const unsigned short* Alo; const unsigned short* W;
  const float* bias; float* Cf; int N; int K; int tr;
};
struct GemmBatch { GemmDesc d[8]; };

DEV void gemm_body(const GemmDesc& g, int mb, int nb, int tid) {
  int lane = tid & 63, w = tid >> 6, quad = lane >> 4, l16 = lane & 15;
  int K = g.K;
  const unsigned short* Ahp = g.Ahi + (size_t)(mb + w * 16 + l16) * K + quad * 8;
  const unsigned short* Alp = g.Alo + (size_t)(mb + w * 16 + l16) * K + quad * 8;
  const unsigned short* Wp = g.W + (size_t)(nb + l16) * K + quad * 8;
  f32x4 acc[4];
  #pragma unroll
  for (int nt = 0; nt < 4; ++nt) acc[nt] = f32x4{0.f, 0.f, 0.f, 0.f};
  for (int k = 0; k < K; k += 32) {
    s16x8 ah = ldfrag(Ahp + k);
    s16x8 al = ldfrag(Alp + k);
    #pragma unroll
    for (int nt = 0; nt < 4; ++nt) {
      s16x8 b = ldfrag(Wp + (size_t)nt * 16 * K + k);
      acc[nt] = mfma16(ah, b, acc[nt]);
      acc[nt] = mfma16(al, b, acc[nt]);
    }
  }
  int mr0 = mb + w * 16 + quad * 4;
  #pragma unroll
  for (int nt = 0; nt < 4; ++nt) {
    int col = nb + nt * 16 + l16;
    float bv = g.bias ? g.bias[col] : 0.f;
    #pragma unroll
    for (int r = 0; r < 4; ++r) {
      if (g.tr)
        g.Cf[(size_t)col * M + (mr0 + r)] = acc[nt][r] + bv;
      else
        g.Cf[(size_t)(mr0 + r) * g.N + col] = acc[nt][r] + bv;
    }
  }
}

__global__ __launch_bounds__(256) void k_gemm(GemmBatch gb) {
  GemmDesc g = gb.d[blockIdx.z];
  int nb = blockIdx.y * 64;
  if (nb >= g.N) return;
  gemm_body(g, blockIdx.x * 64, nb, threadIdx.x);
}

// ---------------- GRU recurrence v10 + piggyback blocks ----------------
// blocks [0,nGru): GRU units. r1 (rlcl==null): blocks >= nGru are weight cvts.
// r2 (rlcl!=null): blocks [nGru,nGru+4) tail phase A; block nGru+4 computes
// u = Wc1^T vc (256-vec) for the folded Arc elimination.

struct RecArgs {
  const unsigned short* whh[4];
  const float* pre[4];
  float* outf[4];
  unsigned short* outhi[4];
  unsigned short* outlo[4];
  unsigned short* agghi[4];      // null -> no agg copy
  unsigned short* agglo[4];
  const float* bhh[4];
  int colOff[4];
  int dir[4];
  int nGru;
  const float* ccs[6]; unsigned short* ccd[6]; int ccn[6]; int cbo[7];
  const float *Hp, *hlf, *vpf, *Wc2f; float* rlcl;   // rlcl!=null -> tailA mode
  const float* Wc1f; const float* vcf; float* uOut;  // u-compute block
};

#define GRU_STEP(pr_, pz_, pn_, pq_, hcur_, hnxt_)                             \
  {                                                                            \
    float pr = pr_, pz = pz_, pn = pn_;                                        \
    pq_ += pst2;                                                               \
    pr_ = pq_[0] + bh_r; pz_ = pq_[128] + bh_z; pn_ = pq_[256];                \
    const unsigned short* hb_ = hcur_ + l16 * 136 + quad * 8;                  \
    s16x8 ah0 = ldfrag(hb_);                                                   \
    s16x8 ah1 = ldfrag(hb_ + 32);                                              \
    s16x8 ah2 = ldfrag(hb_ + 64);                                              \
    s16x8 ah3 = ldfrag(hb_ + 96);                                              \
    f32x4 z4 = f32x4{0.f, 0.f, 0.f, 0.f};                                      \
    f32x4 aR0 = mfma16(ah0, bq[0][0], z4);                                     \
    f32x4 aR1 = mfma16(ah2, bq[0][2], z4);                                     \
    aR0 = mfma16(ah1, bq[0][1], aR0);                                          \
    aR1 = mfma16(ah3, bq[0][3], aR1);                                          \
    f32x4 aZ0 = mfma16(ah0, bq[1][0], z4);                                     \
    f32x4 aZ1 = mfma16(ah2, bq[1][2], z4);                                     \
    aZ0 = mfma16(ah1, bq[1][1], aZ0);                                          \
    aZ1 = mfma16(ah3, bq[1][3], aZ1);                                          \
    float r0 = (aR0[0] + aR1[0]) + (aR0[1] + aR1[1]);                          \
    float r1v = (aR0[2] + aR1[2]) + (aR0[3] + aR1[3]);                         \
    float rg = sigm(pr + plsel(r0, r1v));                                      \
    f32x4 aN0 = mfma16(ah0, bq[2][0], z4);                                     \
    f32x4 aN1 = mfma16(ah2, bq[2][2], z4);                                     \
    aN0 = mfma16(ah1, bq[2][1], aN0);                                          \
    aN1 = mfma16(ah3, bq[2][3], aN1);                                          \
    float z0 = (aZ0[0] + aZ1[0]) + (aZ0[1] + aZ1[1]);                          \
    float z1 = (aZ0[2] + aZ1[2]) + (aZ0[3] + aZ1[3]);                          \
    float zg = sigm(pz + plsel(z0, z1));                                       \
    float n0 = (aN0[0] + aN1[0]) + (aN0[1] + aN1[1]);                          \
    float n1 = (aN0[2] + aN1[2]) + (aN0[3] + aN1[3]);                          \
    float ng = tanh_f(pn + rg * (plsel(n0, n1) + bh_n));                       \
    hf = __builtin_fmaf(zg, hf - ng, ng);                                      \
    unsigned hp32 = cvt_pk_bf16(hf, hf);                                       \
    float rem = hf - __uint_as_float(hp32 << 16);                              \
    unsigned lp32 = cvt_pk_bf16(rem, rem);                                     \
    unsigned short hi = (unsigned short)hp32;                                  \
    unsigned short lo = (unsigned short)lp32;                                  \
    hnxt_[(2 * b) * 136 + d] = hi;                                             \
    hnxt_[(2 * b + 1) * 136 + d] = lo;                                         \
    *outf_p = hf; *outhi_p = hi; *outlo_p = lo;                                \
    outf_p += ost; outhi_p += ost; outlo_p += ost;                             \
    if (agghi_p) { *agghi_p = hi; *agglo_p = lo; agghi_p += ast; agglo_p += ast; } \
    BAR_LGKM();                                                                \
  }

__global__ __launch_bounds__(512) void k_gru(RecArgs ra) {
  int blk = blockIdx.x;
  int tid = threadIdx.x;
  if (blk >= ra.nGru) {
    if (ra.rlcl) {
      int b = blk - ra.nGru;
      if (b >= 4) {                        // ---- u = Wc1^T vc
        if (tid < 256) {
          float acc = 0.f;
          for (int h = 0; h < 128; ++h)
            acc += ra.vcf[h] * ra.Wc1f[(size_t)h * 256 + tid];
          ra.uOut[tid] = acc;
        }
        return;
      }
      // ---- tail phase A (r2 piggyback)
      __shared__ float vl[128], wl[256], rvec[256], red[4];
      if (tid < 128) vl[tid] = ra.vpf[tid];
      __syncthreads();
      float s = 0.f, e = 0.f;
      if (tid < 256) {
        const float* hp = ra.Hp + (size_t)(b * 256 + tid) * 128;
        for (int k = 0; k < 128; ++k) s += vl[k] * tanh_f(hp[k]);
        float m = s;
        for (int dl = 32; dl; dl >>= 1) m = fmaxf(m, __shfl_xor(m, dl));
        if ((tid & 63) == 0) red[tid >> 6] = m;
      }
      __syncthreads();
      float m = fmaxf(fmaxf(red[0], red[1]), fmaxf(red[2], red[3]));
      __syncthreads();
      if (tid < 256) {
        e = __expf(s - m);
        float sum = e;
        for (int dl = 32; dl; dl >>= 1) sum += __shfl_xor(sum, dl);
        if ((tid & 63) == 0) red[tid >> 6] = sum;
      }
      __syncthreads();
      float sum = red[0] + red[1] + red[2] + red[3];
      if (tid < 256) wl[tid] = e * rcp_f(sum);
      __syncthreads();
      if (tid < 256) {
        float acc = 0.f;
        for (int t = 0; t < 256; ++t)
          acc += wl[t] * ra.hlf[(size_t)(b * 256 + t) * 256 + tid];
        rvec[tid] = acc;
      }
      __syncthreads();
      if (tid < 128) {
        float a2 = 0.f;
        const float* wr = ra.Wc2f + (size_t)tid * 256;
        for (int dk = 0; dk < 256; ++dk) a2 += rvec[dk] * wr[dk];
        ra.rlcl[b * 128 + tid] = a2;
      }
      return;
    }
    // ---- weight cvt (r1 piggyback)
    int cb = blk - ra.nGru;
    int seg = 0;
    #pragma unroll
    for (int s2 = 1; s2 < 6; ++s2) seg = (cb >= ra.cbo[s2]) ? s2 : seg;
    int i = (cb - ra.cbo[seg]) * 512 + tid;
    if (i < ra.ccn[seg]) ra.ccd[seg][i] = f2b(ra.ccs[seg][i]);
    return;
  }
  int u = blk;
  __shared__ __align__(16) unsigned short hs[2][16 * 136];
  int lane = tid & 63, w8 = tid >> 6;
  int quad = lane >> 4, l16 = lane & 15;
  for (int i = tid; i < 2 * 16 * 136; i += 512) ((unsigned short*)hs)[i] = 0;
  const unsigned short* whh = ra.whh[u];
  s16x8 bq[3][4];
  #pragma unroll
  for (int g = 0; g < 3; ++g) {
    int row = g * 128 + w8 * 16 + l16;
    #pragma unroll
    for (int kc = 0; kc < 4; ++kc)
      bq[g][kc] = ldfrag(whh + (size_t)row * H + kc * 32 + quad * 8);
  }
  const float* bhh = ra.bhh[u];
  const float* pre = ra.pre[u];
  int colOff = ra.colOff[u], dir = ra.dir[u];
  int b = ((quad & 1) << 1) | (quad >> 1);
  int d = w8 * 16 + l16;
  float bh_r = bhh[d], bh_z = bhh[d + 128], bh_n = bhh[d + 256];
  float hf = 0.f;
  int t0 = dir ? (T - 1) : 0;
  long pst = dir ? -(long)H3 : (long)H3;
  long pst2 = 2 * pst;
  long ost = dir ? -(long)H2 : (long)H2;
  long ast = dir ? -(long)H12 : (long)H12;
  size_t o0 = (size_t)(b * T + t0) * H2 + colOff + d;
  size_t a0 = (size_t)(b * T + t0) * H12 + colOff + d;
  float* outf_p = ra.outf[u] + o0;
  unsigned short* outhi_p = ra.outhi[u] + o0;
  unsigned short* outlo_p = ra.outlo[u] + o0;
  unsigned short* agghi_p = ra.agghi[u] ? ra.agghi[u] + a0 : nullptr;
  unsigned short* agglo_p = ra.agglo[u] ? ra.agglo[u] + a0 : nullptr;
  const float* pqE = pre + (size_t)(b * T + t0) * H3 + d;
  const float* pqO = pqE + pst;
  float e_pr = pqE[0] + bh_r, e_pz = pqE[128] + bh_z, e_pn = pqE[256];
  float o_pr = pqO[0] + bh_r, o_pz = pqO[128] + bh_z, o_pn = pqO[256];
  __syncthreads();
  for (int s = 0; s < T; s += 2) {
    GRU_STEP(e_pr, e_pz, e_pn, pqE, hs[0], hs[1]);
    GRU_STEP(o_pr, o_pz, o_pn, pqO, hs[1], hs[0]);
  }
}

// ---------------- fused: projection GEMMs (y<6) + merged MFMA scores (y>=6) ---

struct ScMMArgs {
  const unsigned short* Xhi[2];
  const float* Rf; const float* Wt[2]; const float* vt[2];
  float* So[2];
};
struct FuseArgs { GemmDesc d[6]; ScMMArgs sm; };

__global__ __launch_bounds__(512, 2) void k_fuse(FuseArgs fa) {
  __shared__ __align__(16) unsigned short w_lds[128 * 256];   // 64KB
  int y = blockIdx.y;
  int tid = threadIdx.x;
  if (y < 6) {
    int xx = blockIdx.x;
    if (xx >= 32) return;
    GemmDesc g = fa.d[y];
    int nb = (xx >> 3) * 64;
    if (nb >= g.N) return;
    int mb = (xx & 7) * 128 + (tid >> 8) * 64;
    gemm_body(g, mb, nb, tid & 255);
    return;
  }
  const ScMMArgs& a = fa.sm;
  int type = y - 6;
  int bi = blockIdx.x, b = bi >> 8;
  const unsigned short* Xhi = a.Xhi[type];
  const float* W = a.Wt[type];
  const float* v = a.vt[type];
  float* Sout = a.So[type];
  int lane = tid & 63, w = tid >> 6, quad = lane >> 4, l16 = lane & 15;
  int d4 = tid & 63, rhi = tid >> 6;
  float4 h4 = ((const float4*)(a.Rf + (size_t)bi * 256))[d4];
  #pragma unroll
  for (int it = 0; it < 16; ++it) {
    int kl = it * 8 + rhi;                            // row 0..127
    float4 w4 = ((const float4*)(W + (size_t)kl * 256))[d4];
    unsigned lo32 = cvt_pk_bf16(w4.x * h4.x, w4.y * h4.y);
    unsigned hi32 = cvt_pk_bf16(w4.z * h4.z, w4.w * h4.w);
    unsigned long long pk = (unsigned long long)lo32 | ((unsigned long long)hi32 << 32);
    int gphys = ((d4 >> 1) + kl) & 31;
    *(unsigned long long*)(w_lds + (size_t)kl * 256 + gphys * 8 + (d4 & 1) * 4) = pk;
  }
  BAR_LGKM();
  f32x4 acc[2][8];
  #pragma unroll
  for (int jj = 0; jj < 2; ++jj)
    #pragma unroll
    for (int c = 0; c < 8; ++c) acc[jj][c] = f32x4{0.f, 0.f, 0.f, 0.f};
  const unsigned short* Xp0 =
      Xhi + (size_t)(b * 256 + w * 2 * 16 + l16) * 256 + quad * 8;
  #pragma unroll 2
  for (int kc = 0; kc < 8; ++kc) {
    s16x8 bf0 = ldfrag(Xp0 + kc * 32);
    s16x8 bf1 = ldfrag(Xp0 + (size_t)16 * 256 + kc * 32);
    #pragma unroll
    for (int c = 0; c < 8; ++c) {
      int krow = c * 16 + l16;
      int gp = (kc * 4 + quad + krow) & 31;
      s16x8 af = ldfrag(w_lds + (size_t)krow * 256 + gp * 8);
      acc[0][c] = mfma16(af, bf0, acc[0][c]);
      acc[1][c] = mfma16(af, bf1, acc[1][c]);
    }
  }
  #pragma unroll
  for (int jj = 0; jj < 2; ++jj) {
    float s = 0.f;
    #pragma unroll
    for (int c = 0; c < 8; ++c)
      #pragma unroll
      for (int r = 0; r < 4; ++r)
        s += tanh_f(acc[jj][c][r]) * v[c * 16 + quad * 4 + r];
    s += __shfl_xor(s, 16);
    s += __shfl_xor(s, 32);
    int jt = w * 2 + jj;
    if (lane < 16) Sout[(size_t)bi * 256 + jt * 16 + l16] = s;
  }
}

// ---------------- scores cmb (bi<256) + wsum types 0/2 (bi>=256) --------------

struct ScCmbArgs {
  const float *Hc, *Rc, *Hm, *Rm, *HB, *hrf, *vcf, *vmf; float* S;
  const float* hlf;
  unsigned short *ahi, *alo;
};

__global__ __launch_bounds__(256, 2) void k_sccmb(ScCmbArgs a) {
  int bi = blockIdx.x;
  int tid = threadIdx.x;
  if (bi >= 256) {                          // ---- wsum for pts(0)/ptd(2)
    int widx = bi - 256;
    int type = (widx >> 7) * 2;
    int rem = widx & 127;
    int it = rem >> 2, b = rem & 3;
    __shared__ float p_l[8][256];
    __shared__ float red[4];
    for (int ii = 0; ii < 8; ++ii) {
      size_t idx = ((size_t)(b * 256 + it * 8 + ii)) * 256 + tid;
      float x = a.S[(size_t)type * STY + idx];
      float m = x;
      for (int dl = 32; dl; dl >>= 1) m = fmaxf(m, __shfl_xor(m, dl));
      if ((tid & 63) == 0) red[tid >> 6] = m;
      __syncthreads();
      m = fmaxf(fmaxf(red[0], red[1]), fmaxf(red[2], red[3]));
      __syncthreads();
      float e = __expf(x - m);
      float sum = e;
      for (int dl = 32; dl; dl >>= 1) sum += __shfl_xor(sum, dl);
      if ((tid & 63) == 0) red[tid >> 6] = sum;
      __syncthreads();
      sum = red[0] + red[1] + red[2] + red[3];
      p_l[ii][tid] = e * rcp_f(sum);
      __syncthreads();
    }
    const float* src = (type == 0 ? a.hrf : a.hlf) + (size_t)b * 256 * 256;
    float acc[8] = {0.f, 0.f, 0.f, 0.f, 0.f, 0.f, 0.f, 0.f};
    for (int j = 0; j < 256; ++j) {
      float hv = src[(size_t)j * 256 + tid];
      #pragma unroll
      for (int ii = 0; ii < 8; ++ii) acc[ii] += p_l[ii][j] * hv;
    }
    int off = 256 * (1 + type);
    #pragma unroll
    for (int ii = 0; ii < 8; ++ii) {
      float vv = acc[ii];
      unsigned short hi = f2b(vv);
      size_t o = (size_t)(b * 256 + it * 8 + ii) * H12 + off + tid;
      a.ahi[o] = hi;
      a.alo[o] = f2b(vv - b2f(hi));
    }
    return;
  }
  __shared__ float rc_l[4 * 128];
  __shared__ float rm_l[4 * 128];
  __shared__ float hr_l[4 * 256];
  __shared__ float vc_l[128], vm_l[128];
  int b = bi >> 6, i0 = (bi & 63) << 2;       // 4 i-rows: gi0..gi0+3
  int gi0 = b * 256 + i0;
  {
    const float4* hr4 = (const float4*)(a.hrf + (size_t)gi0 * 256);
    ((float4*)hr_l)[tid] = hr4[tid];
    if (tid < 128) {
      const float4* rc4 = (const float4*)(a.Rc + (size_t)gi0 * 128);
      const float4* rm4 = (const float4*)(a.Rm + (size_t)gi0 * 128);
      ((float4*)rc_l)[tid] = rc4[tid];
      ((float4*)rm_l)[tid] = rm4[tid];
      vc_l[tid] = a.vcf[tid]; vm_l[tid] = a.vmf[tid];
    }
  }
  __syncthreads();
  int j = tid;
  size_t cb = (size_t)(b * 256 + j);
  float scq[4], smq[4], sbq[4];
  #pragma unroll
  for (int q = 0; q < 4; ++q) { scq[q] = 0.f; smq[q] = 0.f; sbq[q] = 0.f; }
  for (int k = 0; k < 128; ++k) {
    float hc = a.Hc[(size_t)k * M + cb];      // transposed: lane-consecutive
    float hm = a.Hm[(size_t)k * M + cb];
    float vck = vc_l[k], vmk = vm_l[k];
    #pragma unroll
    for (int q = 0; q < 4; ++q) {
      scq[q] += vck * tanh_f(hc + rc_l[q * 128 + k]);
      smq[q] += vmk * tanh_f(hm - rm_l[q * 128 + k]);
    }
  }
  for (int k = 0; k < 256; ++k) {
    float hb = a.HB[(size_t)k * M + cb];      // transposed
    #pragma unroll
    for (int q = 0; q < 4; ++q) sbq[q] += hb * hr_l[q * 256 + k];
  }
  #pragma unroll
  for (int q = 0; q < 4; ++q) {
    size_t o = (size_t)(gi0 + q) * 256 + j;
    a.S[(size_t)STY * 1 + o] = scq[q];
    a.S[(size_t)STY * 3 + o] = sbq[q];
    a.S[(size_t)STY * 4 + o] = smq[q];
  }
}

// ---------------- wsum types {1,3,4} ----------------

__global__ __launch_bounds__(256) void k_wsum(const float* __restrict__ S,
    const float* __restrict__ hl_f, const float* __restrict__ hr_f,
    unsigned short* __restrict__ ahi, unsigned short* __restrict__ alo) {
  int it = blockIdx.x, b = blockIdx.z;
  int y = blockIdx.y;
  int type = (y == 0) ? 1 : (y + 2);          // {1,3,4}
  __shared__ float p_l[8][256];
  __shared__ float red[4];
  int tid = threadIdx.x;
  for (int ii = 0; ii < 8; ++ii) {
    size_t idx = ((size_t)(b * 256 + it * 8 + ii)) * 256 + tid;
    float x = S[(size_t)type * STY + idx];
    float m = x;
    for (int dl = 32; dl; dl >>= 1) m = fmaxf(m, __shfl_xor(m, dl));
    if ((tid & 63) == 0) red[tid >> 6] = m;
    __syncthreads();
    m = fmaxf(fmaxf(red[0], red[1]), fmaxf(red[2], red[3]));
    __syncthreads();
    float e = __expf(x - m);
    float sum = e;
    for (int dl = 32; dl; dl >>= 1) sum += __shfl_xor(sum, dl);
    if ((tid & 63) == 0) red[tid >> 6] = sum;
    __syncthreads();
    sum = red[0] + red[1] + red[2] + red[3];
    p_l[ii][tid] = e * rcp_f(sum);
    __syncthreads();
  }
  const float* src = hl_f + (size_t)b * 256 * 256;   // types 1,3,4 all use hl
  float acc[8] = {0.f, 0.f, 0.f, 0.f, 0.f, 0.f, 0.f, 0.f};
  for (int j = 0; j < 256; ++j) {
    float hv = src[(size_t)j * 256 + tid];
    #pragma unroll
    for (int ii = 0; ii < 8; ++ii) acc[ii] += p_l[ii][j] * hv;
  }
  int off = 256 * (1 + type);      // agg: [hr | pts | ptc | ptd | ptb | ptm]
  #pragma unroll
  for (int ii = 0; ii < 8; ++ii) {
    float vv = acc[ii];
    unsigned short hi = f2b(vv);
    size_t o = (size_t)(b * 256 + it * 8 + ii) * H12 + off + tid;
    ahi[o] = hi;
    alo[o] = f2b(vv - b2f(hi));
  }
}

// ---------------- tail phase B (Arc folded: s2 = u·ar + vc·rlcl) --------------

__global__ __launch_bounds__(256) void k_tail(const float* __restrict__ u,
    const float* __restrict__ rlcl, const float* __restrict__ ar_f,
    const float* __restrict__ vcf, const float* __restrict__ Wpredf,
    float* __restrict__ out) {
  int b = blockIdx.x, tid = threadIdx.x;
  __shared__ float ul[256], wl[256], rvec[256], red[4], vc_l[128], rl_l[128];
  ul[tid] = u[tid];
  if (tid < 128) { vc_l[tid] = vcf[tid]; rl_l[tid] = rlcl[b * 128 + tid]; }
  __syncthreads();
  float c0 = 0.f;
  for (int h = 0; h < 128; ++h) c0 += vc_l[h] * rl_l[h];
  const float* ar = ar_f + (size_t)(b * 256 + tid) * 256;
  float s2 = c0;
  for (int k = 0; k < 256; ++k) s2 += ul[k] * ar[k];
  float m = s2;
  for (int dl = 32; dl; dl >>= 1) m = fmaxf(m, __shfl_xor(m, dl));
  if ((tid & 63) == 0) red[tid >> 6] = m;
  __syncthreads();
  m = fmaxf(fmaxf(red[0], red[1]), fmaxf(red[2], red[3]));
  __syncthreads();
  float e2 = __expf(s2 - m);
  float sum2 = e2;
  for (int dl = 32; dl; dl >>= 1) sum2 += __shfl_xor(sum2, dl);
  if ((tid & 63) == 0) red[tid >> 6] = sum2;
  __syncthreads();
  sum2 = red[0] + red[1] + red[2] + red[3];
  wl[tid] = e2 * rcp_f(sum2);
  __syncthreads();
  float acc2 = 0.f;
  for (int t = 0; t < 256; ++t) acc2 += wl[t] * ar_f[(size_t)(b * 256 + t) * 256 + tid];
  rvec[tid] = acc2;
  __syncthreads();
  if (tid < 2) {
    float o = 0.f;
    const float* wp = Wpredf + (size_t)tid * 256;
    for (int dk = 0; dk < 256; ++dk) o += rvec[dk] * wp[dk];
    out[b * 2 + tid] = sigm(o);
  }
}

// ---------------- host ----------------

extern "C" void kernel_launch(void* const* d_in, const int* in_sizes, int n_in,
                              void* d_out, int out_size, void* d_ws, size_t ws_size,
                              hipStream_t stream) {
  (void)in_sizes; (void)n_in; (void)out_size; (void)ws_size;
  const int* inputs = (const int*)d_in[0];
  const float* embed = (const float*)d_in[1];
  const float* lWih = (const float*)d_in[2];
  const float* lWhh = (const float*)d_in[3];
  const float* lbih = (const float*)d_in[4];
  const float* lbhh = (const float*)d_in[5];
  const float* rWih = (const float*)d_in[6];
  const float* rWhh = (const float*)d_in[7];
  const float* rbih = (const float*)d_in[8];
  const float* rbhh = (const float*)d_in[9];
  const float* aWih = (const float*)d_in[10];
  const float* aWhh = (const float*)d_in[11];
  const float* abih = (const float*)d_in[12];
  const float* abhh = (const float*)d_in[13];
  const float* Wc1 = (const float*)d_in[14];
  const float* Wc2 = (const float*)d_in[15];
  const float* vc  = (const float*)d_in[16];
  const float* Wb  = (const float*)d_in[17];
  const float* Wd  = (const float*)d_in[18];
  const float* vd  = (const float*)d_in[19];
  const float* Wm  = (const float*)d_in[20];
  const float* vmv = (const float*)d_in[21];
  const float* Wsw = (const float*)d_in[22];
  const float* vsv = (const float*)d_in[23];
  const float* Wp  = (const float*)d_in[24];
  const float* vp  = (const float*)d_in[25];
  const float* Wpred = (const float*)d_in[26];

  char* ws = (char*)d_ws;
  size_t off = 0;
  auto alloc = [&](size_t bytes) -> void* {
    void* p = ws + off;
    off += (bytes + 255) & ~(size_t)255;
    return p;
  };
  unsigned short* xhi = (unsigned short*)alloc((size_t)M * EP * 2);
  unsigned short* xlo = (unsigned short*)alloc((size_t)M * EP * 2);
  unsigned short* wpad = (unsigned short*)alloc((size_t)4 * H3 * EP * 2);
  unsigned short* Whh_b = (unsigned short*)alloc((size_t)6 * H3 * H * 2);
  unsigned short* aWih_b = (unsigned short*)alloc((size_t)2 * H3 * H12 * 2);
  unsigned short* Wc1_b = (unsigned short*)alloc((size_t)H * H2 * 2);
  unsigned short* Wc2_b = (unsigned short*)alloc((size_t)H * H2 * 2);
  unsigned short* Wm_b  = (unsigned short*)alloc((size_t)H * H2 * 2);
  unsigned short* Wp_b  = (unsigned short*)alloc((size_t)H * H2 * 2);
  unsigned short* Wb_b  = (unsigned short*)alloc((size_t)H2 * H2 * 2);
  char* region1 = (char*)alloc((size_t)4 * M * H3 * 4);
  float* pre_lr = (float*)region1;
  float* S      = (float*)region1;
  float* pre_a  = (float*)region1;
  float* hl_f = (float*)alloc((size_t)M * H2 * 4);
  float* hr_f = (float*)alloc((size_t)M * H2 * 4);
  unsigned short* hl_hi = (unsigned short*)alloc((size_t)M * H2 * 2);
  unsigned short* hl_lo = (unsigned short*)alloc((size_t)M * H2 * 2);
  unsigned short* hr_hi = (unsigned short*)alloc((size_t)M * H2 * 2);
  unsigned short* hr_lo = (unsigned short*)alloc((size_t)M * H2 * 2);
  float* Hc = (float*)alloc((size_t)M * H * 4);     // transposed [H][M]
  float* Rc = (float*)alloc((size_t)M * H * 4);
  float* Hm = (float*)alloc((size_t)M * H * 4);     // transposed [H][M]
  float* Rm = (float*)alloc((size_t)M * H * 4);
  float* Hp = (float*)alloc((size_t)M * H * 4);
  float* HB = (float*)alloc((size_t)M * H2 * 4);    // transposed [H2][M]
  unsigned short* agg_hi = (unsigned short*)alloc((size_t)M * H12 * 2);
  unsigned short* agg_lo = (unsigned short*)alloc((size_t)M * H12 * 2);
  float* ar_f = (float*)alloc((size_t)M * H2 * 4);
  unsigned short* ar_hi = (unsigned short*)alloc((size_t)M * H2 * 2);
  unsigned short* ar_lo = (unsigned short*)alloc((size_t)M * H2 * 2);
  float* rlcl = (float*)alloc((size_t)4 * H * 4);
  float* ubuf = (float*)alloc((size_t)H2 * 4);

  // 1. staging (slim: Whh cvts + embed + wpad)
  StageArgs sa{};
  sa.cs[0] = lWhh;  sa.cd[0] = Whh_b;                 sa.cn[0] = 2 * H3 * H;
  sa.cs[1] = rWhh;  sa.cd[1] = Whh_b + 2 * H3 * H;    sa.cn[1] = 2 * H3 * H;
  sa.cs[2] = aWhh;  sa.cd[2] = Whh_b + 4 * H3 * H;    sa.cn[2] = 2 * H3 * H;
  sa.idx = inputs; sa.emb = embed; sa.xhi = xhi; sa.xlo = xlo;
  sa.lW = lWih; sa.rW = rWih; sa.wpad = wpad;
  {
    int acc0 = 0;
    sa.bo[0] = 0;
    for (int s = 0; s < 3; ++s) { acc0 += (sa.cn[s] + 255) / 256; sa.bo[s + 1] = acc0; }
    acc0 += (M * EP + 255) / 256;       sa.bo[4] = acc0;
    acc0 += (4 * H3 * EP + 255) / 256;  sa.bo[5] = acc0;
  }
  k_stage<<<dim3(sa.bo[5]), dim3(256), 0, stream>>>(sa);

  // 2. input projections for l/r GRUs
  GemmBatch ga{};
  const float* biases[4] = { lbih, lbih + H3, rbih, rbih + H3 };
  for (int u = 0; u < 4; ++u)
    ga.d[u] = GemmDesc{ xhi, xlo, wpad + (size_t)u * H3 * EP, biases[u],
                        pre_lr + (size_t)u * M * H3, H3, EP, 0 };
  k_gemm<<<dim3(16, 6, 4), dim3(256), 0, stream>>>(ga);

  // 3. l/r recurrences + piggybacked weight cvts (aWih, Wc1, Wc2, Wm, Wp, Wb)
  RecArgs r1{};
  r1.whh[0] = Whh_b;               r1.whh[1] = Whh_b + H3 * H;
  r1.whh[2] = Whh_b + 2 * H3 * H;  r1.whh[3] = Whh_b + 3 * H3 * H;
  for (int u = 0; u < 4; ++u) r1.pre[u] = pre_lr + (size_t)u * M * H3;
  r1.outf[0] = r1.outf[1] = hl_f; r1.outf[2] = r1.outf[3] = hr_f;
  r1.outhi[0] = r1.outhi[1] = hl_hi; r1.outhi[2] = r1.outhi[3] = hr_hi;
  r1.outlo[0] = r1.outlo[1] = hl_lo; r1.outlo[2] = r1.outlo[3] = hr_lo;
  r1.agghi[0] = r1.agghi[1] = nullptr; r1.agghi[2] = r1.agghi[3] = agg_hi;
  r1.agglo[0] = r1.agglo[1] = nullptr; r1.agglo[2] = r1.agglo[3] = agg_lo;
  r1.bhh[0] = lbhh; r1.bhh[1] = lbhh + H3; r1.bhh[2] = rbhh; r1.bhh[3] = rbhh + H3;
  r1.colOff[0] = 0; r1.colOff[1] = H; r1.colOff[2] = 0; r1.colOff[3] = H;
  r1.dir[0] = 0; r1.dir[1] = 1; r1.dir[2] = 0; r1.dir[3] = 1;
  r1.nGru = 4;
  r1.ccs[0] = aWih; r1.ccd[0] = aWih_b; r1.ccn[0] = 2 * H3 * H12;
  r1.ccs[1] = Wc1;  r1.ccd[1] = Wc1_b;  r1.ccn[1] = H * H2;
  r1.ccs[2] = Wc2;  r1.ccd[2] = Wc2_b;  r1.ccn[2] = H * H2;
  r1.ccs[3] = Wm;   r1.ccd[3] = Wm_b;   r1.ccn[3] = H * H2;
  r1.ccs[4] = Wp;   r1.ccd[4] = Wp_b;   r1.ccn[4] = H * H2;
  r1.ccs[5] = Wb;   r1.ccd[5] = Wb_b;   r1.ccn[5] = H2 * H2;
  int cvtBlocks;
  {
    int acc0 = 0;
    r1.cbo[0] = 0;
    for (int s = 0; s < 6; ++s) { acc0 += (r1.ccn[s] + 511) / 512; r1.cbo[s + 1] = acc0; }
    cvtBlocks = acc0;
  }
  r1.Hp = nullptr; r1.hlf = nullptr; r1.vpf = nullptr; r1.Wc2f = nullptr;
  r1.rlcl = nullptr; r1.Wc1f = nullptr; r1.vcf = nullptr; r1.uOut = nullptr;
  k_gru<<<dim3(4 + cvtBlocks), dim3(512), 0, stream>>>(r1);

  // 4+5a. fused projection GEMMs + merged MFMA scores
  FuseArgs fu{};
  fu.d[0] = GemmDesc{ hl_hi, hl_lo, Wc1_b, nullptr, Hc, H, H2, 1 };
  fu.d[1] = GemmDesc{ hr_hi, hr_lo, Wc2_b, nullptr, Rc, H, H2, 0 };
  fu.d[2] = GemmDesc{ hl_hi, hl_lo, Wm_b, nullptr, Hm, H, H2, 1 };
  fu.d[3] = GemmDesc{ hr_hi, hr_lo, Wm_b, nullptr, Rm, H, H2, 0 };
  fu.d[4] = GemmDesc{ hl_hi, hl_lo, Wb_b, nullptr, HB, H2, H2, 1 };
  fu.d[5] = GemmDesc{ hl_hi, hl_lo, Wp_b, nullptr, Hp, H, H2, 0 };
  fu.sm.Xhi[0] = hl_hi; fu.sm.Wt[0] = Wd;  fu.sm.vt[0] = vd;
  fu.sm.So[0] = S + (size_t)2 * STY;      // ptd
  fu.sm.Xhi[1] = hr_hi; fu.sm.Wt[1] = Wsw; fu.sm.vt[1] = vsv;
  fu.sm.So[1] = S + (size_t)0 * STY;      // pts
  fu.sm.Rf = hr_f;
  k_fuse<<<dim3(M, 8), dim3(512), 0, stream>>>(fu);

  // 5b. combined ptc/ptb/ptm scores + wsum for pts/ptd (fuse outputs)
  ScCmbArgs scb{};
  scb.Hc = Hc; scb.Rc = Rc; scb.Hm = Hm; scb.Rm = Rm; scb.HB = HB;
  scb.hrf = hr_f; scb.vcf = vc; scb.vmf = vmv; scb.S = S;
  scb.hlf = hl_f; scb.ahi = agg_hi; scb.alo = agg_lo;
  k_sccmb<<<dim3(512), dim3(256), 0, stream>>>(scb);

  // 6. softmax + weighted sums for types {1,3,4}
  k_wsum<<<dim3(32, 3, 4), dim3(256), 0, stream>>>(S, hl_f, hr_f, agg_hi, agg_lo);

  // 7. agg GRU input projection
  GemmBatch gc{};
  gc.d[0] = GemmDesc{ agg_hi, agg_lo, aWih_b, abih, pre_a, H3, H12, 0 };
  gc.d[1] = GemmDesc{ agg_hi, agg_lo, aWih_b + (size_t)H3 * H12, abih + H3,
                      pre_a + (size_t)M * H3, H3, H12, 0 };
  k_gemm<<<dim3(16, 6, 2), dim3(256), 0, stream>>>(gc);

  // 8. agg recurrence + piggybacked tail phase A + u = Wc1^T vc
  RecArgs r2{};
  r2.whh[0] = Whh_b + 4 * H3 * H; r2.whh[1] = Whh_b + 5 * H3 * H;
  r2.whh[2] = r2.whh[3] = Whh_b + 4 * H3 * H;
  r2.pre[0] = pre_a; r2.pre[1] = pre_a + (size_t)M * H3;
  r2.pre[2] = r2.pre[3] = pre_a;
  r2.outf[0] = r2.outf[1] = r2.outf[2] = r2.outf[3] = ar_f;
  r2.outhi[0] = r2.outhi[1] = r2.outhi[2] = r2.outhi[3] = ar_hi;
  r2.outlo[0] = r2.outlo[1] = r2.outlo[2] = r2.outlo[3] = ar_lo;
  for (int u = 0; u < 4; ++u) { r2.agghi[u] = nullptr; r2.agglo[u] = nullptr; }
  r2.bhh[0] = abhh; r2.bhh[1] = abhh + H3; r2.bhh[2] = r2.bhh[3] = abhh;
  r2.colOff[0] = 0; r2.colOff[1] = H; r2.colOff[2] = r2.colOff[3] = 0;
  r2.dir[0] = 0; r2.dir[1] = 1; r2.dir[2] = r2.dir[3] = 0;
  r2.nGru = 2;
  for (int s = 0; s < 6; ++s) { r2.ccs[s] = nullptr; r2.ccd[s] = nullptr; r2.ccn[s] = 0; }
  for (int s = 0; s < 7; ++s) r2.cbo[s] = 0;
  r2.Hp = Hp; r2.hlf = hl_f; r2.vpf = vp; r2.Wc2f = Wc2; r2.rlcl = rlcl;
  r2.Wc1f = Wc1; r2.vcf = vc; r2.uOut = ubuf;
  k_gru<<<dim3(2 + 5), dim3(512), 0, stream>>>(r2);

  // 9. tail phase B (Arc GEMM eliminated)
  k_tail<<<dim3(4), dim3(256), 0, stream>>>(ubuf, rlcl, ar_f, vc, Wpred,
                                            (float*)d_out);
}

// Round 15
// 613.308 us; speedup vs baseline: 1.1389x; 1.0051x over previous
//
#include <hip/hip_runtime.h>

// MANNet forward, MI355X gfx950. Inputs fp32 (+int32 ids), output fp32.
// R24: K-split of the agg input projection (gc). agg's K=1536 cols become ready
// in waves: hr[0,256) after r1; pts/ptd [256,512)+[768,1024) after sccmb;
// ptc/ptb/ptm after wsum134. gc is split into partial-K accumulation passes:
// P1 (hr, +bias) rides k_fuse; P2 (pts/ptd) rides the wsum134 dispatch (y=3);
// P3 (rest, half the MACs) remains as gc. Sequential dispatches accumulate with
// plain += (no atomics). pre_a un-aliased from the S region (P1 writes it while
// S is still live). gemm_body gains {lda, ldw, K-extent, accum}.

#define DEV static __device__ __forceinline__
#define BAR_LGKM() __asm__ volatile("s_waitcnt lgkmcnt(0)\ns_barrier" ::: "memory")

typedef __attribute__((ext_vector_type(4))) float f32x4;
typedef __attribute__((ext_vector_type(8))) short s16x8;
typedef __attribute__((ext_vector_type(4))) unsigned int u32x4;
typedef __attribute__((ext_vector_type(2))) unsigned int u32x2;

constexpr int T = 256, E = 300, EP = 320, H = 128, H2 = 256, H3 = 384, H12 = 1536;
constexpr int M = 1024;            // B*T
constexpr int STY = 262144;        // 4*T*T elements per score type

DEV float b2f(unsigned short h) { return __uint_as_float(((unsigned)h) << 16); }
DEV unsigned short f2b(float f) {
  unsigned u = __float_as_uint(f);
  u += 0x7fff + ((u >> 16) & 1);            // RNE
  return (unsigned short)(u >> 16);
}
DEV unsigned cvt_pk_bf16(float lo, float hi) {   // dst = {bf16(lo), bf16(hi)} RNE
  unsigned r;
  __asm__("v_cvt_pk_bf16_f32 %0, %1, %2" : "=v"(r) : "v"(lo), "v"(hi));
  return r;
}
DEV float rcp_f(float x) {                       // v_rcp_f32: 1 ulp, 1 trans op
  float r;
  __asm__("v_rcp_f32 %0, %1" : "=v"(r) : "v"(x));
  return r;
}
DEV float sigm(float x) { return rcp_f(1.f + __expf(-x)); }
DEV float tanh_f(float x) {
  float e = __expf(2.f * x);
  return __builtin_fmaf(-2.f, rcp_f(e + 1.f), 1.f);
}
// lanes 0-31 <- x0, lanes 32-63 <- x1's lanes 0-31 (one v_permlane32_swap_b32)
DEV float plsel(float x0, float x1) {
  u32x2 r = __builtin_amdgcn_permlane32_swap(
      __float_as_uint(x0), __float_as_uint(x1), false, false);
  return __uint_as_float(r[0]);
}

DEV s16x8 ldfrag(const unsigned short* p) {
  u32x4 v = *(const u32x4*)p;
  return __builtin_bit_cast(s16x8, v);
}
DEV f32x4 mfma16(s16x8 a, s16x8 b, f32x4 c) {
  return __builtin_amdgcn_mfma_f32_16x16x32_bf16(a, b, c, 0, 0, 0);
}

// ---------------- staging (slim): 3x Whh cvt + embed + padw ----------------

struct StageArgs {
  const float* cs[3]; unsigned short* cd[3]; int cn[3];
  const int* idx; const float* emb; unsigned short* xhi; unsigned short* xlo;
  const float* lW; const float* rW; unsigned short* wpad;
  int bo[6];                       // segs 0-2 cvt, 3 embed, 4 wpad; bo[5]=total
};

__global__ void k_stage(StageArgs sa) {
  int blk = blockIdx.x;
  int seg = 0;
  #pragma unroll
  for (int s2 = 1; s2 < 5; ++s2) seg = (blk >= sa.bo[s2]) ? s2 : seg;
  int i = (blk - sa.bo[seg]) * 256 + threadIdx.x;
  if (seg < 3) {
    if (i < sa.cn[seg]) sa.cd[seg][i] = f2b(sa.cs[seg][i]);
    return;
  }
  if (seg == 3) {
    if (i >= M * EP) return;
    int m = i / EP, e = i - m * EP;
    int r = sa.idx[m];
    float v = (e < E) ? sa.emb[(size_t)r * E + e] : 0.f;
    unsigned short hi = f2b(v);
    sa.xhi[i] = hi;
    sa.xlo[i] = f2b(v - b2f(hi));
    return;
  }
  if (i >= 4 * H3 * EP) return;
  int e = i % EP, n = (i / EP) % H3, uu = i / (EP * H3);
  const float* src = (uu < 2 ? sa.lW : sa.rW) + (size_t)((uu & 1) * H3 + n) * E;
  sa.wpad[i] = (e < E) ? f2b(src[e]) : (unsigned short)0;
}

// ------- generic GEMM: C (+)= (Ahi+Alo) @ W^T (+bias), fp32 out --------------
// K = loop extent; lda/ldw = row strides (for partial-K passes); accum: C += .

struct GemmDesc {
  const unsigned short* Ahi; const unsigned short* Alo; const unsigned short* W;
  const float* bias; float* Cf; int N; int K; int lda; int ldw; int tr; int accum;
};
struct GemmBatch { GemmDesc d[8]; };

DEV void gemm_body(const GemmDesc& g, int mb, int nb, int tid) {
  int lane = tid & 63, w = tid >> 6, quad = lane >> 4, l16 = lane & 15;
  const unsigned short* Ahp = g.Ahi + (size_t)(mb + w * 16 + l16) * g.lda + quad * 8;
  const unsigned short* Alp = g.Alo + (size_t)(mb + w * 16 + l16) * g.lda + quad * 8;
  const unsigned short* Wp = g.W + (size_t)(nb + l16) * g.ldw + quad * 8;
  f32x4 acc[4];
  #pragma unroll
  for (int nt = 0; nt < 4; ++nt) acc[nt] = f32x4{0.f, 0.f, 0.f, 0.f};
  for (int k = 0; k < g.K; k += 32) {
    s16x8 ah = ldfrag(Ahp + k);
    s16x8 al = ldfrag(Alp + k);
    #pragma unroll
    for (int nt = 0; nt < 4; ++nt) {
      s16x8 b = ldfrag(Wp + (size_t)nt * 16 * g.ldw + k);
      acc[nt] = mfma16(ah, b, acc[nt]);
      acc[nt] = mfma16(al, b, acc[nt]);
    }
  }
  int mr0 = mb + w * 16 + quad * 4;
  #pragma unroll
  for (int nt = 0; nt < 4; ++nt) {
    int col = nb + nt * 16 + l16;
    if (g.accum) {
      #pragma unroll
      for (int r = 0; r < 4; ++r)
        g.Cf[(size_t)(mr0 + r) * g.N + col] += acc[nt][r];
    } else {
      float bv = g.bias ? g.bias[col] : 0.f;
      #pragma unroll
      for (int r = 0; r < 4; ++r) {
        if (g.tr)
          g.Cf[(size_t)col * M + (mr0 + r)] = acc[nt][r] + bv;
        else
          g.Cf[(size_t)(mr0 + r) * g.N + col] = acc[nt][r] + bv;
      }
    }
  }
}

__global__ __launch_bounds__(256) void k_gemm(GemmBatch gb) {
  GemmDesc g = gb.d[blockIdx.z];
  int nb = blockIdx.y * 64;
  if (nb >= g.N) return;
  gemm_body(g, blockIdx.x * 64, nb, threadIdx.x);
}

// ---------------- GRU recurrence v10 + piggyback blocks ----------------

struct RecArgs {
  const unsigned short* whh[4];
  const float* pre[4];
  float* outf[4];
  unsigned short* outhi[4];
  unsigned short* outlo[4];
  unsigned short* agghi[4];      // null -> no agg copy
  unsigned short* agglo[4];
  const float* bhh[4];
  int colOff[4];
  int dir[4];
  int nGru;
  const float* ccs[6]; unsigned short* ccd[6]; int ccn[6]; int cbo[7];
  const float *Hp, *hlf, *vpf, *Wc2f; float* rlcl;   // rlcl!=null -> tailA mode
  const float* Wc1f; const float* vcf; float* uOut;  // u-compute block
};

#define GRU_STEP(pr_, pz_, pn_, pq_, hcur_, hnxt_)                             \
  {                                                                            \
    float pr = pr_, pz = pz_, pn = pn_;                                        \
    pq_ += pst2;                                                               \
    pr_ = pq_[0] + bh_r; pz_ = pq_[128] + bh_z; pn_ = pq_[256];                \
    const unsigned short* hb_ = hcur_ + l16 * 136 + quad * 8;                  \
    s16x8 ah0 = ldfrag(hb_);                                                   \
    s16x8 ah1 = ldfrag(hb_ + 32);                                              \
    s16x8 ah2 = ldfrag(hb_ + 64);                                              \
    s16x8 ah3 = ldfrag(hb_ + 96);                                              \
    f32x4 z4 = f32x4{0.f, 0.f, 0.f, 0.f};                                      \
    f32x4 aR0 = mfma16(ah0, bq[0][0], z4);                                     \
    f32x4 aR1 = mfma16(ah2, bq[0][2], z4);                                     \
    aR0 = mfma16(ah1, bq[0][1], aR0);                                          \
    aR1 = mfma16(ah3, bq[0][3], aR1);                                          \
    f32x4 aZ0 = mfma16(ah0, bq[1][0], z4);                                     \
    f32x4 aZ1 = mfma16(ah2, bq[1][2], z4);                                     \
    aZ0 = mfma16(ah1, bq[1][1], aZ0);                                          \
    aZ1 = mfma16(ah3, bq[1][3], aZ1);                                          \
    float r0 = (aR0[0] + aR1[0]) + (aR0[1] + aR1[1]);                          \
    float r1v = (aR0[2] + aR1[2]) + (aR0[3] + aR1[3]);                         \
    float rg = sigm(pr + plsel(r0, r1v));                                      \
    f32x4 aN0 = mfma16(ah0, bq[2][0], z4);                                     \
    f32x4 aN1 = mfma16(ah2, bq[2][2], z4);                                     \
    aN0 = mfma16(ah1, bq[2][1], aN0);                                          \
    aN1 = mfma16(ah3, bq[2][3], aN1);                                          \
    float z0 = (aZ0[0] + aZ1[0]) + (aZ0[1] + aZ1[1]);                          \
    float z1 = (aZ0[2] + aZ1[2]) + (aZ0[3] + aZ1[3]);                          \
    float zg = sigm(pz + plsel(z0, z1));                                       \
    float n0 = (aN0[0] + aN1[0]) + (aN0[1] + aN1[1]);                          \
    float n1 = (aN0[2] + aN1[2]) + (aN0[3] + aN1[3]);                          \
    float ng = tanh_f(pn + rg * (plsel(n0, n1) + bh_n));                       \
    hf = __builtin_fmaf(zg, hf - ng, ng);                                      \
    unsigned hp32 = cvt_pk_bf16(hf, hf);                                       \
    float rem = hf - __uint_as_float(hp32 << 16);                              \
    unsigned lp32 = cvt_pk_bf16(rem, rem);                                     \
    unsigned short hi = (unsigned short)hp32;                                  \
    unsigned short lo = (unsigned short)lp32;                                  \
    hnxt_[(2 * b) * 136 + d] = hi;                                             \
    hnxt_[(2 * b + 1) * 136 + d] = lo;                                         \
    *outf_p = hf; *outhi_p = hi; *outlo_p = lo;                                \
    outf_p += ost; outhi_p += ost; outlo_p += ost;                             \
    if (agghi_p) { *agghi_p = hi; *agglo_p = lo; agghi_p += ast; agglo_p += ast; } \
    BAR_LGKM();                                                                \
  }

__global__ __launch_bounds__(512) void k_gru(RecArgs ra) {
  int blk = blockIdx.x;
  int tid = threadIdx.x;
  if (blk >= ra.nGru) {
    if (ra.rlcl) {
      int b = blk - ra.nGru;
      if (b >= 4) {                        // ---- u = Wc1^T vc
        if (tid < 256) {
          float acc = 0.f;
          for (int h = 0; h < 128; ++h)
            acc += ra.vcf[h] * ra.Wc1f[(size_t)h * 256 + tid];
          ra.uOut[tid] = acc;
        }
        return;
      }
      // ---- tail phase A (r2 piggyback)
      __shared__ float vl[128], wl[256], rvec[256], red[4];
      if (tid < 128) vl[tid] = ra.vpf[tid];
      __syncthreads();
      float s = 0.f, e = 0.f;
      if (tid < 256) {
        const float* hp = ra.Hp + (size_t)(b * 256 + tid) * 128;
        for (int k = 0; k < 128; ++k) s += vl[k] * tanh_f(hp[k]);
        float m = s;
        for (int dl = 32; dl; dl >>= 1) m = fmaxf(m, __shfl_xor(m, dl));
        if ((tid & 63) == 0) red[tid >> 6] = m;
      }
      __syncthreads();
      float m = fmaxf(fmaxf(red[0], red[1]), fmaxf(red[2], red[3]));
      __syncthreads();
      if (tid < 256) {
        e = __expf(s - m);
        float sum = e;
        for (int dl = 32; dl; dl >>= 1) sum += __shfl_xor(sum, dl);
        if ((tid & 63) == 0) red[tid >> 6] = sum;
      }
      __syncthreads();
      float sum = red[0] + red[1] + red[2] + red[3];
      if (tid < 256) wl[tid] = e * rcp_f(sum);
      __syncthreads();
      if (tid < 256) {
        float acc = 0.f;
        for (int t = 0; t < 256; ++t)
          acc += wl[t] * ra.hlf[(size_t)(b * 256 + t) * 256 + tid];
        rvec[tid] = acc;
      }
      __syncthreads();
      if (tid < 128) {
        float a2 = 0.f;
        const float* wr = ra.Wc2f + (size_t)tid * 256;
        for (int dk = 0; dk < 256; ++dk) a2 += rvec[dk] * wr[dk];
        ra.rlcl[b * 128 + tid] = a2;
      }
      return;
    }
    // ---- weight cvt (r1 piggyback)
    int cb = blk - ra.nGru;
    int seg = 0;
    #pragma unroll
    for (int s2 = 1; s2 < 6; ++s2) seg = (cb >= ra.cbo[s2]) ? s2 : seg;
    int i = (cb - ra.cbo[seg]) * 512 + tid;
    if (i < ra.ccn[seg]) ra.ccd[seg][i] = f2b(ra.ccs[seg][i]);
    return;
  }
  int u = blk;
  __shared__ __align__(16) unsigned short hs[2][16 * 136];
  int lane = tid & 63, w8 = tid >> 6;
  int quad = lane >> 4, l16 = lane & 15;
  for (int i = tid; i < 2 * 16 * 136; i += 512) ((unsigned short*)hs)[i] = 0;
  const unsigned short* whh = ra.whh[u];
  s16x8 bq[3][4];
  #pragma unroll
  for (int g = 0; g < 3; ++g) {
    int row = g * 128 + w8 * 16 + l16;
    #pragma unroll
    for (int kc = 0; kc < 4; ++kc)
      bq[g][kc] = ldfrag(whh + (size_t)row * H + kc * 32 + quad * 8);
  }
  const float* bhh = ra.bhh[u];
  const float* pre = ra.pre[u];
  int colOff = ra.colOff[u], dir = ra.dir[u];
  int b = ((quad & 1) << 1) | (quad >> 1);
  int d = w8 * 16 + l16;
  float bh_r = bhh[d], bh_z = bhh[d + 128], bh_n = bhh[d + 256];
  float hf = 0.f;
  int t0 = dir ? (T - 1) : 0;
  long pst = dir ? -(long)H3 : (long)H3;
  long pst2 = 2 * pst;
  long ost = dir ? -(long)H2 : (long)H2;
  long ast = dir ? -(long)H12 : (long)H12;
  size_t o0 = (size_t)(b * T + t0) * H2 + colOff + d;
  size_t a0 = (size_t)(b * T + t0) * H12 + colOff + d;
  float* outf_p = ra.outf[u] + o0;
  unsigned short* outhi_p = ra.outhi[u] + o0;
  unsigned short* outlo_p = ra.outlo[u] + o0;
  unsigned short* agghi_p = ra.agghi[u] ? ra.agghi[u] + a0 : nullptr;
  unsigned short* agglo_p = ra.agglo[u] ? ra.agglo[u] + a0 : nullptr;
  const float* pqE = pre + (size_t)(b * T + t0) * H3 + d;
  const float* pqO = pqE + pst;
  float e_pr = pqE[0] + bh_r, e_pz = pqE[128] + bh_z, e_pn = pqE[256];
  float o_pr = pqO[0] + bh_r, o_pz = pqO[128] + bh_z, o_pn = pqO[256];
  __syncthreads();
  for (int s = 0; s < T; s += 2) {
    GRU_STEP(e_pr, e_pz, e_pn, pqE, hs[0], hs[1]);
    GRU_STEP(o_pr, o_pz, o_pn, pqO, hs[1], hs[0]);
  }
}

// ---- fused: projection GEMMs (y<6) + merged MFMA scores (y=6,7) + P1 (y=8,9) -

struct ScMMArgs {
  const unsigned short* Xhi[2];
  const float* Rf; const float* Wt[2]; const float* vt[2];
  float* So[2];
};
struct FuseArgs { GemmDesc d[8]; ScMMArgs sm; };

__global__ __launch_bounds__(512, 2) void k_fuse(FuseArgs fa) {
  __shared__ __align__(16) unsigned short w_lds[128 * 256];   // 64KB
  int y = blockIdx.y;
  int tid = threadIdx.x;
  if (y < 6) {
    int xx = blockIdx.x;
    if (xx >= 32) return;
    GemmDesc g = fa.d[y];
    int nb = (xx >> 3) * 64;
    if (nb >= g.N) return;
    int mb = (xx & 7) * 128 + (tid >> 8) * 64;
    gemm_body(g, mb, nb, tid & 255);
    return;
  }
  if (y >= 8) {                             // ---- P1: agg hr-cols @ aWih (+bias)
    int xx = blockIdx.x;
    if (xx >= 48) return;
    GemmDesc g = fa.d[y - 2];               // d[6], d[7]
    int nb = (xx >> 3) * 64;                // 0..5 tiles (N=384)
    int mb = (xx & 7) * 128 + (tid >> 8) * 64;
    gemm_body(g, mb, nb, tid & 255);
    return;
  }
  const ScMMArgs& a = fa.sm;
  int type = y - 6;
  int bi = blockIdx.x, b = bi >> 8;
  const unsigned short* Xhi = a.Xhi[type];
  const float* W = a.Wt[type];
  const float* v = a.vt[type];
  float* Sout = a.So[type];
  int lane = tid & 63, w = tid >> 6, quad = lane >> 4, l16 = lane & 15;
  int d4 = tid & 63, rhi = tid >> 6;
  float4 h4 = ((const float4*)(a.Rf + (size_t)bi * 256))[d4];
  #pragma unroll
  for (int it = 0; it < 16; ++it) {
    int kl = it * 8 + rhi;                            // row 0..127
    float4 w4 = ((const float4*)(W + (size_t)kl * 256))[d4];
    unsigned lo32 = cvt_pk_bf16(w4.x * h4.x, w4.y * h4.y);
    unsigned hi32 = cvt_pk_bf16(w4.z * h4.z, w4.w * h4.w);
    unsigned long long pk = (unsigned long long)lo32 | ((unsigned long long)hi32 << 32);
    int gphys = ((d4 >> 1) + kl) & 31;
    *(unsigned long long*)(w_lds + (size_t)kl * 256 + gphys * 8 + (d4 & 1) * 4) = pk;
  }
  BAR_LGKM();
  f32x4 acc[2][8];
  #pragma unroll
  for (int jj = 0; jj < 2; ++jj)
    #pragma unroll
    for (int c = 0; c < 8; ++c) acc[jj][c] = f32x4{0.f, 0.f, 0.f, 0.f};
  const unsigned short* Xp0 =
      Xhi + (size_t)(b * 256 + w * 2 * 16 + l16) * 256 + quad * 8;
  #pragma unroll 2
  for (int kc = 0; kc < 8; ++kc) {
    s16x8 bf0 = ldfrag(Xp0 + kc * 32);
    s16x8 bf1 = ldfrag(Xp0 + (size_t)16 * 256 + kc * 32);
    #pragma unroll
    for (int c = 0; c < 8; ++c) {
      int krow = c * 16 + l16;
      int gp = (kc * 4 + quad + krow) & 31;
      s16x8 af = ldfrag(w_lds + (size_t)krow * 256 + gp * 8);
      acc[0][c] = mfma16(af, bf0, acc[0][c]);
      acc[1][c] = mfma16(af, bf1, acc[1][c]);
    }
  }
  #pragma unroll
  for (int jj = 0; jj < 2; ++jj) {
    float s = 0.f;
    #pragma unroll
    for (int c = 0; c < 8; ++c)
      #pragma unroll
      for (int r = 0; r < 4; ++r)
        s += tanh_f(acc[jj][c][r]) * v[c * 16 + quad * 4 + r];
    s += __shfl_xor(s, 16);
    s += __shfl_xor(s, 32);
    int jt = w * 2 + jj;
    if (lane < 16) Sout[(size_t)bi * 256 + jt * 16 + l16] = s;
  }
}

// ---------------- scores cmb (bi<256) + wsum types 0/2 (bi>=256) --------------

struct ScCmbArgs {
  const float *Hc, *Rc, *Hm, *Rm, *HB, *hrf, *vcf, *vmf; float* S;
  const float* hlf;
  unsigned short *ahi, *alo;
};

__global__ __launch_bounds__(256, 2) void k_sccmb(ScCmbArgs a) {
  int bi = blockIdx.x;
  int tid = threadIdx.x;
  if (bi >= 256) {                          // ---- wsum for pts(0)/ptd(2)
    int widx = bi - 256;
    int type = (widx >> 7) * 2;
    int rem = widx & 127;
    int it = rem >> 2, b = rem & 3;
    __shared__ float p_l[8][256];
    __shared__ float red[4];
    for (int ii = 0; ii < 8; ++ii) {
      size_t idx = ((size_t)(b * 256 + it * 8 + ii)) * 256 + tid;
      float x = a.S[(size_t)type * STY + idx];
      float m = x;
      for (int dl = 32; dl; dl >>= 1) m = fmaxf(m, __shfl_xor(m, dl));
      if ((tid & 63) == 0) red[tid >> 6] = m;
      __syncthreads();
      m = fmaxf(fmaxf(red[0], red[1]), fmaxf(red[2], red[3]));
      __syncthreads();
      float e = __expf(x - m);
      float sum = e;
      for (int dl = 32; dl; dl >>= 1) sum += __shfl_xor(sum, dl);
      if ((tid & 63) == 0) red[tid >> 6] = sum;
      __syncthreads();
      sum = red[0] + red[1] + red[2] + red[3];
      p_l[ii][tid] = e * rcp_f(sum);
      __syncthreads();
    }
    const float* src = (type == 0 ? a.hrf : a.hlf) + (size_t)b * 256 * 256;
    float acc[8] = {0.f, 0.f, 0.f, 0.f, 0.f, 0.f, 0.f, 0.f};
    for (int j = 0; j < 256; ++j) {
      float hv = src[(size_t)j * 256 + tid];
      #pragma unroll
      for (int ii = 0; ii < 8; ++ii) acc[ii] += p_l[ii][j] * hv;
    }
    int off = 256 * (1 + type);
    #pragma unroll
    for (int ii = 0; ii < 8; ++ii) {
      float vv = acc[ii];
      unsigned short hi = f2b(vv);
      size_t o = (size_t)(b * 256 + it * 8 + ii) * H12 + off + tid;
      a.ahi[o] = hi;
      a.alo[o] = f2b(vv - b2f(hi));
    }
    return;
  }
  __shared__ float rc_l[4 * 128];
  __shared__ float rm_l[4 * 128];
  __shared__ float hr_l[4 * 256];
  __shared__ float vc_l[128], vm_l[128];
  int b = bi >> 6, i0 = (bi & 63) << 2;       // 4 i-rows: gi0..gi0+3
  int gi0 = b * 256 + i0;
  {
    const float4* hr4 = (const float4*)(a.hrf + (size_t)gi0 * 256);
    ((float4*)hr_l)[tid] = hr4[tid];
    if (tid < 128) {
      const float4* rc4 = (const float4*)(a.Rc + (size_t)gi0 * 128);
      const float4* rm4 = (const float4*)(a.Rm + (size_t)gi0 * 128);
      ((float4*)rc_l)[tid] = rc4[tid];
      ((float4*)rm_l)[tid] = rm4[tid];
      vc_l[tid] = a.vcf[tid]; vm_l[tid] = a.vmf[tid];
    }
  }
  __syncthreads();
  int j = tid;
  size_t cb = (size_t)(b * 256 + j);
  float scq[4], smq[4], sbq[4];
  #pragma unroll
  for (int q = 0; q < 4; ++q) { scq[q] = 0.f; smq[q] = 0.f; sbq[q] = 0.f; }
  for (int k = 0; k < 128; ++k) {
    float hc = a.Hc[(size_t)k * M + cb];      // transposed: lane-consecutive
    float hm = a.Hm[(size_t)k * M + cb];
    float vck = vc_l[k], vmk = vm_l[k];
    #pragma unroll
    for (int q = 0; q < 4; ++q) {
      scq[q] += vck * tanh_f(hc + rc_l[q * 128 + k]);
      smq[q] += vmk * tanh_f(hm - rm_l[q * 128 + k]);
    }
  }
  for (int k = 0; k < 256; ++k) {
    float hb = a.HB[(size_t)k * M + cb];      // transposed
    #pragma unroll
    for (int q = 0; q < 4; ++q) sbq[q] += hb * hr_l[q * 256 + k];
  }
  #pragma unroll
  for (int q = 0; q < 4; ++q) {
    size_t o = (size_t)(gi0 + q) * 256 + j;
    a.S[(size_t)STY * 1 + o] = scq[q];
    a.S[(size_t)STY * 3 + o] = sbq[q];
    a.S[(size_t)STY * 4 + o] = smq[q];
  }
}

// ---------------- wsum types {1,3,4} (y<3) + P2 partial-K GEMM (y=3) ----------

__global__ __launch_bounds__(256) void k_wsum(const float* __restrict__ S,
    const float* __restrict__ hl_f, const float* __restrict__ hr_f,
    unsigned short* __restrict__ ahi, unsigned short* __restrict__ alo,
    const unsigned short* __restrict__ aW, float* __restrict__ preA) {
  int tid = threadIdx.x;
  if (blockIdx.y == 3) {                      // ---- P2: pts/ptd K-cols of gc
    int t3 = (blockIdx.z * 32 + blockIdx.x) * 3;
    for (int q = 0; q < 3; ++q) {
      int t = t3 + q;
      if (t >= 384) break;
      int unit = t / 192, rem = t % 192, seg = rem / 96, rem2 = rem % 96;
      int mtile = rem2 / 6, ntile = rem2 % 6;
      int k0 = seg ? 768 : 256;
      GemmDesc g{ ahi + k0, alo + k0,
                  aW + (size_t)unit * H3 * H12 + k0, nullptr,
                  preA + (size_t)unit * M * H3, H3, 256, H12, H12, 0, 1 };
      gemm_body(g, mtile * 64, ntile * 64, tid);
    }
    return;
  }
  int it = blockIdx.x, b = blockIdx.z;
  int y = blockIdx.y;
  int type = (y == 0) ? 1 : (y + 2);          // {1,3,4}
  __shared__ float p_l[8][256];
  __shared__ float red[4];
  for (int ii = 0; ii < 8; ++ii) {
    size_t idx = ((size_t)(b * 256 + it * 8 + ii)) * 256 + tid;
    float x = S[(size_t)type * STY + idx];
    float m = x;
    for (int dl = 32; dl; dl >>= 1) m = fmaxf(m, __shfl_xor(m, dl));
    if ((tid & 63) == 0) red[tid >> 6] = m;
    __syncthreads();
    m = fmaxf(fmaxf(red[0], red[1]), fmaxf(red[2], red[3]));
    __syncthreads();
    float e = __expf(x - m);
    float sum = e;
    for (int dl = 32; dl; dl >>= 1) sum += __shfl_xor(sum, dl);
    if ((tid & 63) == 0) red[tid >> 6] = sum;
    __syncthreads();
    sum = red[0] + red[1] + red[2] + red[3];
    p_l[ii][tid] = e * rcp_f(sum);
    __syncthreads();
  }
  const float* src = hl_f + (size_t)b * 256 * 256;   // types 1,3,4 all use hl
  float acc[8] = {0.f, 0.f, 0.f, 0.f, 0.f, 0.f, 0.f, 0.f};
  for (int j = 0; j < 256; ++j) {
    float hv = src[(size_t)j * 256 + tid];
    #pragma unroll
    for (int ii = 0; ii < 8; ++ii) acc[ii] += p_l[ii][j] * hv;
  }
  int off = 256 * (1 + type);      // agg: [hr | pts | ptc | ptd | ptb | ptm]
  #pragma unroll
  for (int ii = 0; ii < 8; ++ii) {
    float vv = acc[ii];
    unsigned short hi = f2b(vv);
    size_t o = (size_t)(b * 256 + it * 8 + ii) * H12 + off + tid;
    ahi[o] = hi;
    alo[o] = f2b(vv - b2f(hi));
  }
}

// ---------------- tail phase B (Arc folded: s2 = u·ar + vc·rlcl) --------------

__global__ __launch_bounds__(256) void k_tail(const float* __restrict__ u,
    const float* __restrict__ rlcl, const float* __restrict__ ar_f,
    const float* __restrict__ vcf, const float* __restrict__ Wpredf,
    float* __restrict__ out) {
  int b = blockIdx.x, tid = threadIdx.x;
  __shared__ float ul[256], wl[256], rvec[256], red[4], vc_l[128], rl_l[128];
  ul[tid] = u[tid];
  if (tid < 128) { vc_l[tid] = vcf[tid]; rl_l[tid] = rlcl[b * 128 + tid]; }
  __syncthreads();
  float c0 = 0.f;
  for (int h = 0; h < 128; ++h) c0 += vc_l[h] * rl_l[h];
  const float* ar = ar_f + (size_t)(b * 256 + tid) * 256;
  float s2 = c0;
  for (int k = 0; k < 256; ++k) s2 += ul[k] * ar[k];
  float m = s2;
  for (int dl = 32; dl; dl >>= 1) m = fmaxf(m, __shfl_xor(m, dl));
  if ((tid & 63) == 0) red[tid >> 6] = m;
  __syncthreads();
  m = fmaxf(fmaxf(red[0], red[1]), fmaxf(red[2], red[3]));
  __syncthreads();
  float e2 = __expf(s2 - m);
  float sum2 = e2;
  for (int dl = 32; dl; dl >>= 1) sum2 += __shfl_xor(sum2, dl);
  if ((tid & 63) == 0) red[tid >> 6] = sum2;
  __syncthreads();
  sum2 = red[0] + red[1] + red[2] + red[3];
  wl[tid] = e2 * rcp_f(sum2);
  __syncthreads();
  float acc2 = 0.f;
  for (int t = 0; t < 256; ++t) acc2 += wl[t] * ar_f[(size_t)(b * 256 + t) * 256 + tid];
  rvec[tid] = acc2;
  __syncthreads();
  if (tid < 2) {
    float o = 0.f;
    const float* wp = Wpredf + (size_t)tid * 256;
    for (int dk = 0; dk < 256; ++dk) o += rvec[dk] * wp[dk];
    out[b * 2 + tid] = sigm(o);
  }
}

// ---------------- host ----------------

extern "C" void kernel_launch(void* const* d_in, const int* in_sizes, int n_in,
                              void* d_out, int out_size, void* d_ws, size_t ws_size,
                              hipStream_t stream) {
  (void)in_sizes; (void)n_in; (void)out_size; (void)ws_size;
  const int* inputs = (const int*)d_in[0];
  const float* embed = (const float*)d_in[1];
  const float* lWih = (const float*)d_in[2];
  const float* lWhh = (const float*)d_in[3];
  const float* lbih = (const float*)d_in[4];
  const float* lbhh = (const float*)d_in[5];
  const float* rWih = (const float*)d_in[6];
  const float* rWhh = (const float*)d_in[7];
  const float* rbih = (const float*)d_in[8];
  const float* rbhh = (const float*)d_in[9];
  const float* aWih = (const float*)d_in[10];
  const float* aWhh = (const float*)d_in[11];
  const float* abih = (const float*)d_in[12];
  const float* abhh = (const float*)d_in[13];
  const float* Wc1 = (const float*)d_in[14];
  const float* Wc2 = (const float*)d_in[15];
  const float* vc  = (const float*)d_in[16];
  const float* Wb  = (const float*)d_in[17];
  const float* Wd  = (const float*)d_in[18];
  const float* vd  = (const float*)d_in[19];
  const float* Wm  = (const float*)d_in[20];
  const float* vmv = (const float*)d_in[21];
  const float* Wsw = (const float*)d_in[22];
  const float* vsv = (const float*)d_in[23];
  const float* Wp  = (const float*)d_in[24];
  const float* vp  = (const float*)d_in[25];
  const float* Wpred = (const float*)d_in[26];

  char* ws = (char*)d_ws;
  size_t off = 0;
  auto alloc = [&](size_t bytes) -> void* {
    void* p = ws + off;
    off += (bytes + 255) & ~(size_t)255;
    return p;
  };
  unsigned short* xhi = (unsigned short*)alloc((size_t)M * EP * 2);
  unsigned short* xlo = (unsigned short*)alloc((size_t)M * EP * 2);
  unsigned short* wpad = (unsigned short*)alloc((size_t)4 * H3 * EP * 2);
  unsigned short* Whh_b = (unsigned short*)alloc((size_t)6 * H3 * H * 2);
  unsigned short* aWih_b = (unsigned short*)alloc((size_t)2 * H3 * H12 * 2);
  unsigned short* Wc1_b = (unsigned short*)alloc((size_t)H * H2 * 2);
  unsigned short* Wc2_b = (unsigned short*)alloc((size_t)H * H2 * 2);
  unsigned short* Wm_b  = (unsigned short*)alloc((size_t)H * H2 * 2);
  unsigned short* Wp_b  = (unsigned short*)alloc((size_t)H * H2 * 2);
  unsigned short* Wb_b  = (unsigned short*)alloc((size_t)H2 * H2 * 2);
  char* region1 = (char*)alloc((size_t)4 * M * H3 * 4);
  float* pre_lr = (float*)region1;
  float* S      = (float*)region1;
  float* pre_a  = (float*)alloc((size_t)2 * M * H3 * 4);   // un-aliased from S
  float* hl_f = (float*)alloc((size_t)M * H2 * 4);
  float* hr_f = (float*)alloc((size_t)M * H2 * 4);
  unsigned short* hl_hi = (unsigned short*)alloc((size_t)M * H2 * 2);
  unsigned short* hl_lo = (unsigned short*)alloc((size_t)M * H2 * 2);
  unsigned short* hr_hi = (unsigned short*)alloc((size_t)M * H2 * 2);
  unsigned short* hr_lo = (unsigned short*)alloc((size_t)M * H2 * 2);
  float* Hc = (float*)alloc((size_t)M * H * 4);     // transposed [H][M]
  float* Rc = (float*)alloc((size_t)M * H * 4);
  float* Hm = (float*)alloc((size_t)M * H * 4);     // transposed [H][M]
  float* Rm = (float*)alloc((size_t)M * H * 4);
  float* Hp = (float*)alloc((size_t)M * H * 4);
  float* HB = (float*)alloc((size_t)M * H2 * 4);    // transposed [H2][M]
  unsigned short* agg_hi = (unsigned short*)alloc((size_t)M * H12 * 2);
  unsigned short* agg_lo = (unsigned short*)alloc((size_t)M * H12 * 2);
  float* ar_f = (float*)alloc((size_t)M * H2 * 4);
  unsigned short* ar_hi = (unsigned short*)alloc((size_t)M * H2 * 2);
  unsigned short* ar_lo = (unsigned short*)alloc((size_t)M * H2 * 2);
  float* rlcl = (float*)alloc((size_t)4 * H * 4);
  float* ubuf = (float*)alloc((size_t)H2 * 4);

  // 1. staging (slim: Whh cvts + embed + wpad)
  StageArgs sa{};
  sa.cs[0] = lWhh;  sa.cd[0] = Whh_b;                 sa.cn[0] = 2 * H3 * H;
  sa.cs[1] = rWhh;  sa.cd[1] = Whh_b + 2 * H3 * H;    sa.cn[1] = 2 * H3 * H;
  sa.cs[2] = aWhh;  sa.cd[2] = Whh_b + 4 * H3 * H;    sa.cn[2] = 2 * H3 * H;
  sa.idx = inputs; sa.emb = embed; sa.xhi = xhi; sa.xlo = xlo;
  sa.lW = lWih; sa.rW = rWih; sa.wpad = wpad;
  {
    int acc0 = 0;
    sa.bo[0] = 0;
    for (int s = 0; s < 3; ++s) { acc0 += (sa.cn[s] + 255) / 256; sa.bo[s + 1] = acc0; }
    acc0 += (M * EP + 255) / 256;       sa.bo[4] = acc0;
    acc0 += (4 * H3 * EP + 255) / 256;  sa.bo[5] = acc0;
  }
  k_stage<<<dim3(sa.bo[5]), dim3(256), 0, stream>>>(sa);

  // 2. input projections for l/r GRUs
  GemmBatch ga{};
  const float* biases[4] = { lbih, lbih + H3, rbih, rbih + H3 };
  for (int u = 0; u < 4; ++u)
    ga.d[u] = GemmDesc{ xhi, xlo, wpad + (size_t)u * H3 * EP, biases[u],
                        pre_lr + (size_t)u * M * H3, H3, EP, EP, EP, 0, 0 };
  k_gemm<<<dim3(16, 6, 4), dim3(256), 0, stream>>>(ga);

  // 3. l/r recurrences + piggybacked weight cvts (aWih, Wc1, Wc2, Wm, Wp, Wb)
  RecArgs r1{};
  r1.whh[0] = Whh_b;               r1.whh[1] = Whh_b + H3 * H;
  r1.whh[2] = Whh_b + 2 * H3 * H;  r1.whh[3] = Whh_b + 3 * H3 * H;
  for (int u = 0; u < 4; ++u) r1.pre[u] = pre_lr + (size_t)u * M * H3;
  r1.outf[0] = r1.outf[1] = hl_f; r1.outf[2] = r1.outf[3] = hr_f;
  r1.outhi[0] = r1.outhi[1] = hl_hi; r1.outhi[2] = r1.outhi[3] = hr_hi;
  r1.outlo[0] = r1.outlo[1] = hl_lo; r1.outlo[2] = r1.outlo[3] = hr_lo;
  r1.agghi[0] = r1.agghi[1] = nullptr; r1.agghi[2] = r1.agghi[3] = agg_hi;
  r1.agglo[0] = r1.agglo[1] = nullptr; r1.agglo[2] = r1.agglo[3] = agg_lo;
  r1.bhh[0] = lbhh; r1.bhh[1] = lbhh + H3; r1.bhh[2] = rbhh; r1.bhh[3] = rbhh + H3;
  r1.colOff[0] = 0; r1.colOff[1] = H; r1.colOff[2] = 0; r1.colOff[3] = H;
  r1.dir[0] = 0; r1.dir[1] = 1; r1.dir[2] = 0; r1.dir[3] = 1;
  r1.nGru = 4;
  r1.ccs[0] = aWih; r1.ccd[0] = aWih_b; r1.ccn[0] = 2 * H3 * H12;
  r1.ccs[1] = Wc1;  r1.ccd[1] = Wc1_b;  r1.ccn[1] = H * H2;
  r1.ccs[2] = Wc2;  r1.ccd[2] = Wc2_b;  r1.ccn[2] = H * H2;
  r1.ccs[3] = Wm;   r1.ccd[3] = Wm_b;   r1.ccn[3] = H * H2;
  r1.ccs[4] = Wp;   r1.ccd[4] = Wp_b;   r1.ccn[4] = H * H2;
  r1.ccs[5] = Wb;   r1.ccd[5] = Wb_b;   r1.ccn[5] = H2 * H2;
  int cvtBlocks;
  {
    int acc0 = 0;
    r1.cbo[0] = 0;
    for (int s = 0; s < 6; ++s) { acc0 += (r1.ccn[s] + 511) / 512; r1.cbo[s + 1] = acc0; }
    cvtBlocks = acc0;
  }
  r1.Hp = nullptr; r1.hlf = nullptr; r1.vpf = nullptr; r1.Wc2f = nullptr;
  r1.rlcl = nullptr; r1.Wc1f = nullptr; r1.vcf = nullptr; r1.uOut = nullptr;
  k_gru<<<dim3(4 + cvtBlocks), dim3(512), 0, stream>>>(r1);

  // 4+5a. fused projection GEMMs + merged MFMA scores + P1 (agg hr-cols)
  FuseArgs fu{};
  fu.d[0] = GemmDesc{ hl_hi, hl_lo, Wc1_b, nullptr, Hc, H, H2, H2, H2, 1, 0 };
  fu.d[1] = GemmDesc{ hr_hi, hr_lo, Wc2_b, nullptr, Rc, H, H2, H2, H2, 0, 0 };
  fu.d[2] = GemmDesc{ hl_hi, hl_lo, Wm_b, nullptr, Hm, H, H2, H2, H2, 1, 0 };
  fu.d[3] = GemmDesc{ hr_hi, hr_lo, Wm_b, nullptr, Rm, H, H2, H2, H2, 0, 0 };
  fu.d[4] = GemmDesc{ hl_hi, hl_lo, Wb_b, nullptr, HB, H2, H2, H2, H2, 1, 0 };
  fu.d[5] = GemmDesc{ hl_hi, hl_lo, Wp_b, nullptr, Hp, H, H2, H2, H2, 0, 0 };
  fu.d[6] = GemmDesc{ agg_hi, agg_lo, aWih_b, abih, pre_a,
                      H3, 256, H12, H12, 0, 0 };
  fu.d[7] = GemmDesc{ agg_hi, agg_lo, aWih_b + (size_t)H3 * H12, abih + H3,
                      pre_a + (size_t)M * H3, H3, 256, H12, H12, 0, 0 };
  fu.sm.Xhi[0] = hl_hi; fu.sm.Wt[0] = Wd;  fu.sm.vt[0] = vd;
  fu.sm.So[0] = S + (size_t)2 * STY;      // ptd
  fu.sm.Xhi[1] = hr_hi; fu.sm.Wt[1] = Wsw; fu.sm.vt[1] = vsv;
  fu.sm.So[1] = S + (size_t)0 * STY;      // pts
  fu.sm.Rf = hr_f;
  k_fuse<<<dim3(M, 10), dim3(512), 0, stream>>>(fu);

  // 5b. combined ptc/ptb/ptm scores + wsum for pts/ptd (fuse outputs)
  ScCmbArgs scb{};
  scb.Hc = Hc; scb.Rc = Rc; scb.Hm = Hm; scb.Rm = Rm; scb.HB = HB;
  scb.hrf = hr_f; scb.vcf = vc; scb.vmf = vmv; scb.S = S;
  scb.hlf = hl_f; scb.ahi = agg_hi; scb.alo = agg_lo;
  k_sccmb<<<dim3(512), dim3(256), 0, stream>>>(scb);

  // 6. wsum types {1,3,4} + P2 (pts/ptd K-cols of the agg projection)
  k_wsum<<<dim3(32, 4, 4), dim3(256), 0, stream>>>(S, hl_f, hr_f, agg_hi, agg_lo,
                                                   aWih_b, pre_a);

  // 7. P3: remaining agg projection K-cols (ptc + ptb/ptm), accumulate
  GemmBatch gc{};
  for (int u = 0; u < 2; ++u) {
    gc.d[2 * u + 0] = GemmDesc{ agg_hi + 512, agg_lo + 512,
                                aWih_b + (size_t)u * H3 * H12 + 512, nullptr,
                                pre_a + (size_t)u * M * H3, H3, 256, H12, H12, 0, 1 };
    gc.d[2 * u + 1] = GemmDesc{ agg_hi + 1024, agg_lo + 1024,
                                aWih_b + (size_t)u * H3 * H12 + 1024, nullptr,
                                pre_a + (size_t)u * M * H3, H3, 512, H12, H12, 0, 1 };
  }
  k_gemm<<<dim3(16, 6, 4), dim3(256), 0, stream>>>(gc);

  // 8. agg recurrence + piggybacked tail phase A + u = Wc1^T vc
  RecArgs r2{};
  r2.whh[0] = Whh_b + 4 * H3 * H; r2.whh[1] = Whh_b + 5 * H3 * H;
  r2.whh[2] = r2.whh[3] = Whh_b + 4 * H3 * H;
  r2.pre[0] = pre_a; r2.pre[1] = pre_a + (size_t)M * H3;
  r2.pre[2] = r2.pre[3] = pre_a;
  r2.outf[0] = r2.outf[1] = r2.outf[2] = r2.outf[3] = ar_f;
  r2.outhi[0] = r2.outhi[1] = r2.outhi[2] = r2.outhi[3] = ar_hi;
  r2.outlo[0] = r2.outlo[1] = r2.outlo[2] = r2.outlo[3] = ar_lo;
  for (int u = 0; u < 4; ++u) { r2.agghi[u] = nullptr; r2.agglo[u] = nullptr; }
  r2.bhh[0] = abhh; r2.bhh[1] = abhh + H3; r2.bhh[2] = r2.bhh[3] = abhh;
  r2.colOff[0] = 0; r2.colOff[1] = H; r2.colOff[2] = r2.colOff[3] = 0;
  r2.dir[0] = 0; r2.dir[1] = 1; r2.dir[2] = r2.dir[3] = 0;
  r2.nGru = 2;
  for (int s = 0; s < 6; ++s) { r2.ccs[s] = nullptr; r2.ccd[s] = nullptr; r2.ccn[s] = 0; }
  for (int s = 0; s < 7; ++s) r2.cbo[s] = 0;
  r2.Hp = Hp; r2.hlf = hl_f; r2.vpf = vp; r2.Wc2f = Wc2; r2.rlcl = rlcl;
  r2.Wc1f = Wc1; r2.vcf = vc; r2.uOut = ubuf;
  k_gru<<<dim3(2 + 5), dim3(512), 0, stream>>>(r2);

  // 9. tail phase B
  k_tail<<<dim3(4), dim3(256), 0, stream>>>(ubuf, rlcl, ar_f, vc, Wpred,
                                            (float*)d_out);
}